// Round 2
// baseline (2184.313 us; speedup 1.0000x reference)
//
#include <hip/hip_runtime.h>
#include <math.h>

#define Bq 4
#define Cc 256
#define Tt 2048
#define Kk 7
#define NTOP 10
#define CG 8
#define Ll 2

__device__ __forceinline__ float gelu_f(float v) {
  return 0.5f * v * (1.0f + erff(v * 0.70710678118654752440f));
}

// xT[b][t][c] = x[b][c][t]
__global__ void transpose_x(const float* __restrict__ x, float* __restrict__ xT) {
  __shared__ float tile[32][33];
  int b = blockIdx.z;
  int t0 = blockIdx.x * 32, c0 = blockIdx.y * 32;
  int tx = threadIdx.x, ty = threadIdx.y;
  const float* xb = x + (size_t)b * Cc * Tt;
  for (int r = ty; r < 32; r += 8)
    tile[r][tx] = xb[(size_t)(c0 + r) * Tt + t0 + tx];
  __syncthreads();
  float* xo = xT + (size_t)b * Tt * Cc;
  for (int r = ty; r < 32; r += 8)
    xo[(size_t)(t0 + r) * Cc + c0 + tx] = tile[tx][r];
}

// y[b,o,t] = act(bias[o] + sum_c W[o*wstride + woff + c] * x[b,c,t]); 16 o per thread
__global__ __launch_bounds__(256) void pw_conv16(
    const float* __restrict__ x, const float* __restrict__ W, int wstride, int woff,
    const float* __restrict__ bias, float* __restrict__ y, int do_gelu) {
  int t = blockIdx.x * 256 + threadIdx.x;
  int o0 = blockIdx.y * 16;
  int b = blockIdx.z;
  const float* xp = x + (size_t)b * Cc * Tt + t;
  const float* wp = W + (size_t)o0 * wstride + woff;
  float acc[16];
#pragma unroll
  for (int j = 0; j < 16; ++j) acc[j] = bias[o0 + j];
  for (int c = 0; c < Cc; ++c) {
    float xv = xp[(size_t)c * Tt];
#pragma unroll
    for (int j = 0; j < 16; ++j)
      acc[j] = fmaf(wp[(size_t)j * wstride + c], xv, acc[j]);
  }
#pragma unroll
  for (int j = 0; j < 16; ++j) {
    float v = acc[j];
    if (do_gelu) v = gelu_f(v);
    y[((size_t)b * Cc + o0 + j) * Tt + t] = v;
  }
}

// grouped conv1d k=5 pad=2
__global__ __launch_bounds__(256) void gconv1d(
    const float* __restrict__ h, const float* __restrict__ W, // [C][8][5]
    const float* __restrict__ bias, float* __restrict__ tout) {
  int t = blockIdx.x * 256 + threadIdx.x;
  int o = blockIdx.y, b = blockIdx.z;
  int g = o >> 3;
  const float* hp = h + ((size_t)b * Cc + g * CG) * Tt;
  const float* wp = W + (size_t)o * CG * 5;
  float acc = bias[o];
#pragma unroll
  for (int ci = 0; ci < CG; ++ci) {
#pragma unroll
    for (int dt = 0; dt < 5; ++dt) {
      int tt = t + dt - 2;
      if (tt >= 0 && tt < Tt)
        acc = fmaf(wp[ci * 5 + dt], hp[(size_t)ci * Tt + tt], acc);
    }
  }
  tout[((size_t)b * Cc + o) * Tt + t] = acc;
}

__global__ void sqnorm(const float* __restrict__ x, float* __restrict__ xx) {
  int t = blockIdx.x * 256 + threadIdx.x;
  int b = blockIdx.y;
  const float* xp = x + (size_t)b * Cc * Tt + t;
  float acc = 0.f;
  for (int c = 0; c < Cc; ++c) { float v = xp[(size_t)c * Tt]; acc = fmaf(v, v, acc); }
  xx[(size_t)b * Tt + t] = acc;
}

// pass 1: one wave per query m; 8 m per block. fp32 score(n) = 2*<x_m,x_n> - ||x_n||^2
// keeps a top-NTOP shortlist (margin over K=7 absorbs fp32 accumulation noise).
__global__ __launch_bounds__(512) void knn_topk(
    const float* __restrict__ x, const float* __restrict__ xx,
    int* __restrict__ idx10) {
  __shared__ float xm[8][Cc];
  int b = blockIdx.y;
  int m0 = blockIdx.x * 8;
  int tid = threadIdx.x;
  const float* xb = x + (size_t)b * Cc * Tt;
  for (int e = tid; e < 8 * Cc; e += 512) {
    int mi = e & 7, c = e >> 3;
    xm[mi][c] = xb[(size_t)c * Tt + m0 + mi];
  }
  __syncthreads();
  int w = tid >> 6, lane = tid & 63;
  int m = m0 + w;
  float s[NTOP]; int idl[NTOP];
#pragma unroll
  for (int j = 0; j < NTOP; ++j) { s[j] = -INFINITY; idl[j] = 0x7fffffff; }
  const float* xmw = xm[w];
  const float* xxb = xx + (size_t)b * Tt;
  for (int chunk = 0; chunk < Tt / 256; ++chunk) {
    int n0 = chunk * 256 + lane * 4;
    float dx = 0.f, dy = 0.f, dz = 0.f, dw_ = 0.f;
    for (int c = 0; c < Cc; c += 4) {
      float4 xv = *(const float4*)(xmw + c);
      const float* base = xb + (size_t)c * Tt + n0;
      float4 a0 = *(const float4*)(base);
      float4 a1 = *(const float4*)(base + Tt);
      float4 a2 = *(const float4*)(base + 2 * (size_t)Tt);
      float4 a3 = *(const float4*)(base + 3 * (size_t)Tt);
      dx = fmaf(xv.x, a0.x, dx); dy = fmaf(xv.x, a0.y, dy); dz = fmaf(xv.x, a0.z, dz); dw_ = fmaf(xv.x, a0.w, dw_);
      dx = fmaf(xv.y, a1.x, dx); dy = fmaf(xv.y, a1.y, dy); dz = fmaf(xv.y, a1.z, dz); dw_ = fmaf(xv.y, a1.w, dw_);
      dx = fmaf(xv.z, a2.x, dx); dy = fmaf(xv.z, a2.y, dy); dz = fmaf(xv.z, a2.z, dz); dw_ = fmaf(xv.z, a2.w, dw_);
      dx = fmaf(xv.w, a3.x, dx); dy = fmaf(xv.w, a3.y, dy); dz = fmaf(xv.w, a3.z, dz); dw_ = fmaf(xv.w, a3.w, dw_);
    }
    float dots[4] = {dx, dy, dz, dw_};
#pragma unroll
    for (int q = 0; q < 4; ++q) {
      int n = n0 + q;
      float sc = 2.0f * dots[q] - xxb[n];
      if (sc > s[NTOP - 1]) {
        s[NTOP - 1] = sc; idl[NTOP - 1] = n;
#pragma unroll
        for (int j = NTOP - 1; j > 0; --j) {
          if (s[j] > s[j - 1]) {
            float ts = s[j]; s[j] = s[j - 1]; s[j - 1] = ts;
            int ti = idl[j]; idl[j] = idl[j - 1]; idl[j - 1] = ti;
          }
        }
      }
    }
  }
  // merge sorted per-lane lists: NTOP rounds of (score desc, idx asc) argmax
  int ptr = 0;
  for (int r = 0; r < NTOP; ++r) {
    float cs = (ptr < NTOP) ? s[ptr] : -INFINITY;
    int cid = (ptr < NTOP) ? idl[ptr] : 0x7fffffff;
    float bs = cs; int bi = cid;
#pragma unroll
    for (int off = 1; off < 64; off <<= 1) {
      float os = __shfl_xor(bs, off);
      int oi = __shfl_xor(bi, off);
      if (os > bs || (os == bs && oi < bi)) { bs = os; bi = oi; }
    }
    if (cid == bi) ptr++;  // ids unique across lanes -> exactly one owner
    if (lane == 0) idx10[((size_t)b * Tt + m) * NTOP + r] = bi;
  }
}

// pass 2: fp64 rescore of the NTOP shortlist, emit exact top-7 (score desc, idx asc)
__global__ __launch_bounds__(64) void knn_rescore(
    const float* __restrict__ xT, const int* __restrict__ idx10,
    int* __restrict__ idxout) {
  int t = blockIdx.x;
  int b = blockIdx.y;
  int lane = threadIdx.x;
  const float* xTb = xT + (size_t)b * Tt * Cc;
  const float* xm = xTb + (size_t)t * Cc;
  double sc = -1e300;
  int cid = 0x7fffffff;
  if (lane < NTOP) {
    int j = idx10[((size_t)b * Tt + t) * NTOP + lane];
    const float* xn = xTb + (size_t)j * Cc;
    double dot = 0.0, nn = 0.0;
    for (int c = 0; c < Cc; c += 4) {
      float4 a = *(const float4*)(xm + c);
      float4 v = *(const float4*)(xn + c);
      dot += (double)a.x * v.x + (double)a.y * v.y + (double)a.z * v.z + (double)a.w * v.w;
      nn  += (double)v.x * v.x + (double)v.y * v.y + (double)v.z * v.z + (double)v.w * v.w;
    }
    sc = 2.0 * dot - nn;
    cid = j;
  }
  for (int r = 0; r < Kk; ++r) {
    double bs = sc; int bi = cid;
#pragma unroll
    for (int off = 1; off < 64; off <<= 1) {
      double os = __shfl_xor(bs, off);
      int oi = __shfl_xor(bi, off);
      if (os > bs || (os == bs && oi < bi)) { bs = os; bi = oi; }
    }
    if (cid == bi) { sc = -1e300; cid = 0x7fffffff; }  // consume winner
    if (lane == 0) idxout[((size_t)b * Tt + t) * Kk + r] = bi;
  }
}

// wT[c][o] = W[o][c] for c < 256 (neighbor half of dw1)
__global__ void transpose_w(const float* __restrict__ W, float* __restrict__ wT) {
  int c = blockIdx.x; int o = threadIdx.x;
  wT[(size_t)c * Cc + o] = W[(size_t)o * (2 * Cc) + c];
}

// g1[b,o,t,k] = gelu(ctr[b,o,t] + sum_c wT[c][o] * xT[b][idx[b,t,k]][c])
__global__ __launch_bounds__(256) void graph_pw(
    const float* __restrict__ xT, const int* __restrict__ idx,
    const float* __restrict__ wT, const float* __restrict__ ctr,
    float* __restrict__ g1) {
  __shared__ float nb[Cc][8];  // [c][k], padded to 8
  __shared__ int jid[Kk];
  int t = blockIdx.x;
  int b = blockIdx.y;
  int tid = threadIdx.x;
  if (tid < Kk) jid[tid] = idx[((size_t)b * Tt + t) * Kk + tid];
  __syncthreads();
  const float* xTb = xT + (size_t)b * Tt * Cc;
#pragma unroll
  for (int k = 0; k < Kk; ++k)
    nb[tid][k] = xTb[(size_t)jid[k] * Cc + tid];   // coalesced per k
  __syncthreads();
  int o = tid;
  float acc[Kk];
#pragma unroll
  for (int k = 0; k < Kk; ++k) acc[k] = 0.f;
  for (int c = 0; c < Cc; ++c) {
    float wv = wT[(size_t)c * Cc + o];             // coalesced across lanes
#pragma unroll
    for (int k = 0; k < Kk; ++k) acc[k] = fmaf(wv, nb[c][k], acc[k]);  // LDS broadcast
  }
  float cv = ctr[((size_t)b * Cc + o) * Tt + t];
  float* gp = g1 + (((size_t)b * Cc + o) * Tt + t) * (size_t)Kk;
#pragma unroll
  for (int k = 0; k < Kk; ++k) gp[k] = gelu_f(acc[k] + cv);
}

// grouped 5x5 conv over (T,K) pad 2 + bias, max over k, + tout + identity
__global__ __launch_bounds__(256) void gconv2d_max(
    const float* __restrict__ g1, const float* __restrict__ W, // [C][8][5][5]
    const float* __restrict__ bias, const float* __restrict__ tout,
    const float* __restrict__ xin, float* __restrict__ xout) {
  int t = blockIdx.x * 256 + threadIdx.x;
  int o = blockIdx.y;
  int b = blockIdx.z;
  int g = o >> 3;
  const float* wp = W + (size_t)o * CG * 25;
  float acc[Kk];
  float bv = bias[o];
#pragma unroll
  for (int k = 0; k < Kk; ++k) acc[k] = bv;
  for (int ci = 0; ci < CG; ++ci) {
    const float* gp = g1 + ((size_t)b * Cc + g * CG + ci) * Tt * (size_t)Kk;
    const float* wc = wp + ci * 25;
#pragma unroll
    for (int dt = 0; dt < 5; ++dt) {
      int tt = t + dt - 2;
      if (tt < 0 || tt >= Tt) continue;
      const float* gr = gp + (size_t)tt * Kk;
      float r[Kk];
#pragma unroll
      for (int k = 0; k < Kk; ++k) r[k] = gr[k];
#pragma unroll
      for (int dk = 0; dk < 5; ++dk) {
        float wv = wc[dt * 5 + dk];
#pragma unroll
        for (int k = 0; k < Kk; ++k) {
          int kk = k + dk - 2;
          if (kk >= 0 && kk < Kk) acc[k] = fmaf(wv, r[kk], acc[k]);
        }
      }
    }
  }
  float m = acc[0];
#pragma unroll
  for (int k = 1; k < Kk; ++k) m = fmaxf(m, acc[k]);
  size_t off = ((size_t)b * Cc + o) * Tt + t;
  xout[off] = tout[off] + m + xin[off];
}

extern "C" void kernel_launch(void* const* d_in, const int* in_sizes, int n_in,
                              void* d_out, int out_size, void* d_ws, size_t ws_size,
                              hipStream_t stream) {
  const float* x0  = (const float*)d_in[0];
  const float* tw1 = (const float*)d_in[1];
  const float* tb1 = (const float*)d_in[2];
  const float* tw2 = (const float*)d_in[3];
  const float* tb2 = (const float*)d_in[4];
  const float* dw1 = (const float*)d_in[5];
  const float* db1 = (const float*)d_in[6];
  const float* dw2 = (const float*)d_in[7];
  const float* db2 = (const float*)d_in[8];
  float* out = (float*)d_out;

  float* ws = (float*)d_ws;
  const size_t NCT = (size_t)Bq * Cc * Tt;
  float* x1   = ws;                 // layer-1 output          [B,C,T]
  float* hbuf = x1 + NCT;           // h, then ctr             [B,C,T]
  float* tbuf = hbuf + NCT;         // tout                    [B,C,T]
  float* xT   = tbuf + NCT;         // transposed x            [B,T,C]
  float* g1   = xT + NCT;           // graph branch activ.     [B,C,T,K]
  float* wT   = g1 + NCT * Kk;      // transposed nb weights   [C,C]
  float* xx   = wT + (size_t)Cc * Cc;    // squared norms      [B,T]
  int* idxb   = (int*)(xx + (size_t)Bq * Tt);   // knn top-7    [B,T,K]
  int* idx10  = idxb + (size_t)Bq * Tt * Kk;    // shortlist    [B,T,NTOP]

  for (int i = 0; i < Ll; ++i) {
    const float* xin = (i == 0) ? x0 : x1;
    float* xout = (i == Ll - 1) ? out : x1;

    transpose_x<<<dim3(Tt/32, Cc/32, Bq), dim3(32, 8), 0, stream>>>(xin, xT);
    pw_conv16<<<dim3(Tt/256, Cc/16, Bq), 256, 0, stream>>>(
        xin, tw1 + (size_t)i * Cc * Cc, Cc, 0, tb1 + (size_t)i * Cc, hbuf, 1);
    gconv1d<<<dim3(Tt/256, Cc, Bq), 256, 0, stream>>>(
        hbuf, tw2 + (size_t)i * Cc * CG * 5, tb2 + (size_t)i * Cc, tbuf);
    sqnorm<<<dim3(Tt/256, Bq), 256, 0, stream>>>(xin, xx);
    knn_topk<<<dim3(Tt/8, Bq), 512, 0, stream>>>(xin, xx, idx10);
    knn_rescore<<<dim3(Tt, Bq), 64, 0, stream>>>(xT, idx10, idxb);
    // center half of dw1 (input channels 256..511), bias folded in here
    pw_conv16<<<dim3(Tt/256, Cc/16, Bq), 256, 0, stream>>>(
        xin, dw1 + (size_t)i * Cc * 2 * Cc, 2 * Cc, Cc, db1 + (size_t)i * Cc, hbuf, 0);
    transpose_w<<<dim3(Cc), 256, 0, stream>>>(dw1 + (size_t)i * Cc * 2 * Cc, wT);
    graph_pw<<<dim3(Tt, Bq), 256, 0, stream>>>(xT, idxb, wT, hbuf, g1);
    gconv2d_max<<<dim3(Tt/256, Cc, Bq), 256, 0, stream>>>(
        g1, dw2 + (size_t)i * Cc * CG * 25, db2 + (size_t)i * Cc, tbuf, xin, xout);
  }
}

// Round 3
// 1456.537 us; speedup vs baseline: 1.4997x; 1.4997x over previous
//
#include <hip/hip_runtime.h>
#include <math.h>

#define Bq 4
#define Cc 256
#define Tt 2048
#define Kk 7
#define NTOP 10
#define CG 8
#define Ll 2

#define TM 32     // queries per block
#define TN 256    // neighbor tile
#define NT (Tt / TN)   // 8 N-tiles
#define APAD 264  // 256+8 ushort (16B-aligned rows, 2-way-free banks)
#define BPAD 56   // 32+24 ushort
#define SPAD 264  // strip cols (float)

typedef __attribute__((ext_vector_type(8))) short short8;
typedef __attribute__((ext_vector_type(4))) float floatx4;

__device__ __forceinline__ float gelu_f(float v) {
  return 0.5f * v * (1.0f + erff(v * 0.70710678118654752440f));
}

__device__ __forceinline__ unsigned short bf16_rne(float v) {
  unsigned int u = __float_as_uint(v);
  return (unsigned short)((u + 0x7fffu + ((u >> 16) & 1u)) >> 16);
}

// xT[b][t][c] = x[b][c][t]
__global__ void transpose_x(const float* __restrict__ x, float* __restrict__ xT) {
  __shared__ float tile[32][33];
  int b = blockIdx.z;
  int t0 = blockIdx.x * 32, c0 = blockIdx.y * 32;
  int tx = threadIdx.x, ty = threadIdx.y;
  const float* xb = x + (size_t)b * Cc * Tt;
  for (int r = ty; r < 32; r += 8)
    tile[r][tx] = xb[(size_t)(c0 + r) * Tt + t0 + tx];
  __syncthreads();
  float* xo = xT + (size_t)b * Tt * Cc;
  for (int r = ty; r < 32; r += 8)
    xo[(size_t)(t0 + r) * Cc + c0 + tx] = tile[tx][r];
}

// split xT into bf16 hi/lo pair (x ~= hi + lo)
__global__ __launch_bounds__(256) void cvt_split(
    const float* __restrict__ xT, unsigned short* __restrict__ xh,
    unsigned short* __restrict__ xl) {
  int i = (blockIdx.x * 256 + threadIdx.x) * 4;
  float4 v = *(const float4*)(xT + i);
  ushort4 h, l;
  float f;
  h.x = bf16_rne(v.x); f = v.x - __uint_as_float((unsigned int)h.x << 16); l.x = bf16_rne(f);
  h.y = bf16_rne(v.y); f = v.y - __uint_as_float((unsigned int)h.y << 16); l.y = bf16_rne(f);
  h.z = bf16_rne(v.z); f = v.z - __uint_as_float((unsigned int)h.z << 16); l.z = bf16_rne(f);
  h.w = bf16_rne(v.w); f = v.w - __uint_as_float((unsigned int)h.w << 16); l.w = bf16_rne(f);
  *(ushort4*)(xh + i) = h;
  *(ushort4*)(xl + i) = l;
}

// y[b,o,t] = act(bias[o] + sum_c W[o*wstride + woff + c] * x[b,c,t]); 16 o per thread
__global__ __launch_bounds__(256) void pw_conv16(
    const float* __restrict__ x, const float* __restrict__ W, int wstride, int woff,
    const float* __restrict__ bias, float* __restrict__ y, int do_gelu) {
  int t = blockIdx.x * 256 + threadIdx.x;
  int o0 = blockIdx.y * 16;
  int b = blockIdx.z;
  const float* xp = x + (size_t)b * Cc * Tt + t;
  const float* wp = W + (size_t)o0 * wstride + woff;
  float acc[16];
#pragma unroll
  for (int j = 0; j < 16; ++j) acc[j] = bias[o0 + j];
  for (int c = 0; c < Cc; ++c) {
    float xv = xp[(size_t)c * Tt];
#pragma unroll
    for (int j = 0; j < 16; ++j)
      acc[j] = fmaf(wp[(size_t)j * wstride + c], xv, acc[j]);
  }
#pragma unroll
  for (int j = 0; j < 16; ++j) {
    float v = acc[j];
    if (do_gelu) v = gelu_f(v);
    y[((size_t)b * Cc + o0 + j) * Tt + t] = v;
  }
}

// grouped conv1d k=5 pad=2
__global__ __launch_bounds__(256) void gconv1d(
    const float* __restrict__ h, const float* __restrict__ W, // [C][8][5]
    const float* __restrict__ bias, float* __restrict__ tout) {
  int t = blockIdx.x * 256 + threadIdx.x;
  int o = blockIdx.y, b = blockIdx.z;
  int g = o >> 3;
  const float* hp = h + ((size_t)b * Cc + g * CG) * Tt;
  const float* wp = W + (size_t)o * CG * 5;
  float acc = bias[o];
#pragma unroll
  for (int ci = 0; ci < CG; ++ci) {
#pragma unroll
    for (int dt = 0; dt < 5; ++dt) {
      int tt = t + dt - 2;
      if (tt >= 0 && tt < Tt)
        acc = fmaf(wp[ci * 5 + dt], hp[(size_t)ci * Tt + tt], acc);
    }
  }
  tout[((size_t)b * Cc + o) * Tt + t] = acc;
}

__global__ void sqnorm(const float* __restrict__ x, float* __restrict__ xx) {
  int t = blockIdx.x * 256 + threadIdx.x;
  int b = blockIdx.y;
  const float* xp = x + (size_t)b * Cc * Tt + t;
  float acc = 0.f;
  for (int c = 0; c < Cc; ++c) { float v = xp[(size_t)c * Tt]; acc = fmaf(v, v, acc); }
  xx[(size_t)b * Tt + t] = acc;
}

// MFMA pairwise scores + fused top-10. score(n) = 2*dot(x_m,x_n) - ||x_n||^2
// split-bf16: dot = hh + hl + lh (ll dropped, ~1e-3 worst-case score error).
__global__ __launch_bounds__(512, 1) void knn_mfma(
    const unsigned short* __restrict__ xh, const unsigned short* __restrict__ xl,
    const float* __restrict__ xx, int* __restrict__ idx10) {
  __shared__ __align__(16) unsigned short Ah[TM][APAD], Al[TM][APAD];
  __shared__ __align__(16) unsigned short Bh[TN][BPAD], Bl[TN][BPAD];
  __shared__ __align__(16) float strip[TM][SPAD];

  int bid = blockIdx.x;
  int batch = (bid & 7) >> 1;                    // XCD pair per batch (L2 locality)
  int mtile = ((bid >> 3) << 1) | (bid & 1);     // 0..63
  int m0 = mtile * TM;
  int tid = threadIdx.x;
  int w = tid >> 6, lane = tid & 63;
  int quad = lane >> 4, l15 = lane & 15;

  const unsigned short* xhb = xh + (size_t)batch * Tt * Cc;
  const unsigned short* xlb = xl + (size_t)batch * Tt * Cc;
  const float* xxb = xx + (size_t)batch * Tt;

  // stage A (32 rows x 256 k, hi+lo) once
#pragma unroll
  for (int k = 0; k < 4; ++k) {
    int e = tid + 512 * k;              // 0..2047
    int mat = e >> 10, ee = e & 1023;
    int row = ee >> 5, c8 = (ee & 31) * 8;
    const unsigned short* src = (mat ? xlb : xhb) + (size_t)(m0 + row) * Cc + c8;
    unsigned short* dst = (mat ? &Al[row][c8] : &Ah[row][c8]);
    *(uint4*)dst = *(const uint4*)src;
  }

  float s[NTOP]; int idl[NTOP];
#pragma unroll
  for (int j = 0; j < NTOP; ++j) { s[j] = -INFINITY; idl[j] = 0x7fffffff; }

  for (int nt = 0; nt < NT; ++nt) {
    int n0 = nt * TN;
    floatx4 acc00 = {0.f,0.f,0.f,0.f}, acc01 = acc00, acc10 = acc00, acc11 = acc00;
    for (int ks = 0; ks < 8; ++ks) {
      int kc = ks * 32;
      __syncthreads();                  // prior Bh/Bl reads (and nt-1 strip reads) done
      // stage B (256 rows x 32 k, hi+lo)
#pragma unroll
      for (int k = 0; k < 4; ++k) {
        int e = tid + 512 * k;          // 0..2047
        int mat = e >> 10, ee = e & 1023;
        int row = ee >> 2, c8 = (ee & 3) * 8;
        const unsigned short* src = (mat ? xlb : xhb) + (size_t)(n0 + row) * Cc + kc + c8;
        unsigned short* dst = (mat ? &Bl[row][c8] : &Bh[row][c8]);
        *(uint4*)dst = *(const uint4*)src;
      }
      __syncthreads();
      int ka = kc + quad * 8;
      short8 ah0 = *(const short8*)&Ah[l15][ka];
      short8 ah1 = *(const short8*)&Ah[16 + l15][ka];
      short8 al0 = *(const short8*)&Al[l15][ka];
      short8 al1 = *(const short8*)&Al[16 + l15][ka];
      int br0 = w * 32 + l15, br1 = br0 + 16, kb = quad * 8;
      short8 bh0 = *(const short8*)&Bh[br0][kb];
      short8 bh1 = *(const short8*)&Bh[br1][kb];
      short8 bl0 = *(const short8*)&Bl[br0][kb];
      short8 bl1 = *(const short8*)&Bl[br1][kb];
      acc00 = __builtin_amdgcn_mfma_f32_16x16x32_bf16(ah0, bh0, acc00, 0, 0, 0);
      acc00 = __builtin_amdgcn_mfma_f32_16x16x32_bf16(ah0, bl0, acc00, 0, 0, 0);
      acc00 = __builtin_amdgcn_mfma_f32_16x16x32_bf16(al0, bh0, acc00, 0, 0, 0);
      acc01 = __builtin_amdgcn_mfma_f32_16x16x32_bf16(ah0, bh1, acc01, 0, 0, 0);
      acc01 = __builtin_amdgcn_mfma_f32_16x16x32_bf16(ah0, bl1, acc01, 0, 0, 0);
      acc01 = __builtin_amdgcn_mfma_f32_16x16x32_bf16(al0, bh1, acc01, 0, 0, 0);
      acc10 = __builtin_amdgcn_mfma_f32_16x16x32_bf16(ah1, bh0, acc10, 0, 0, 0);
      acc10 = __builtin_amdgcn_mfma_f32_16x16x32_bf16(ah1, bl0, acc10, 0, 0, 0);
      acc10 = __builtin_amdgcn_mfma_f32_16x16x32_bf16(al1, bh0, acc10, 0, 0, 0);
      acc11 = __builtin_amdgcn_mfma_f32_16x16x32_bf16(ah1, bh1, acc11, 0, 0, 0);
      acc11 = __builtin_amdgcn_mfma_f32_16x16x32_bf16(ah1, bl1, acc11, 0, 0, 0);
      acc11 = __builtin_amdgcn_mfma_f32_16x16x32_bf16(al1, bh1, acc11, 0, 0, 0);
    }
    // write score strip: C layout col=lane&15, row=quad*4+reg
    int col0 = w * 32 + l15, col1 = col0 + 16;
    int r0 = quad * 4;
#pragma unroll
    for (int r = 0; r < 4; ++r) {
      strip[r0 + r][col0] = acc00[r];
      strip[r0 + r][col1] = acc01[r];
      strip[16 + r0 + r][col0] = acc10[r];
      strip[16 + r0 + r][col1] = acc11[r];
    }
    __syncthreads();
    // fused top-10 insertion: 16 threads per row, 16 cols each
    int row = tid >> 4, j16 = tid & 15;
#pragma unroll
    for (int q = 0; q < 4; ++q) {
      int c0 = j16 * 16 + q * 4;
      float4 sv = *(const float4*)&strip[row][c0];
      float4 xv = *(const float4*)&xxb[n0 + c0];
      float cand[4] = {fmaf(2.f, sv.x, -xv.x), fmaf(2.f, sv.y, -xv.y),
                       fmaf(2.f, sv.z, -xv.z), fmaf(2.f, sv.w, -xv.w)};
#pragma unroll
      for (int e = 0; e < 4; ++e) {
        float sc = cand[e];
        if (sc > s[NTOP - 1]) {
          int n = n0 + c0 + e;
          s[NTOP - 1] = sc; idl[NTOP - 1] = n;
#pragma unroll
          for (int j = NTOP - 1; j > 0; --j) {
            if (s[j] > s[j - 1]) {
              float ts = s[j]; s[j] = s[j - 1]; s[j - 1] = ts;
              int ti = idl[j]; idl[j] = idl[j - 1]; idl[j - 1] = ti;
            }
          }
        }
      }
    }
  }
  // merge the 16 per-thread lists of each row (lanes tid&15) via shfl
  int row = tid >> 4, j16 = tid & 15;
  int m = m0 + row;
  int ptr = 0;
  for (int r = 0; r < NTOP; ++r) {
    float cs = (ptr < NTOP) ? s[ptr] : -INFINITY;
    int cid = (ptr < NTOP) ? idl[ptr] : 0x7fffffff;
    float bs = cs; int bi = cid;
#pragma unroll
    for (int off = 1; off < 16; off <<= 1) {
      float os = __shfl_xor(bs, off);
      int oi = __shfl_xor(bi, off);
      if (os > bs || (os == bs && oi < bi)) { bs = os; bi = oi; }
    }
    if (cid == bi) ptr++;   // cols disjoint -> unique owner
    if (j16 == 0) idx10[((size_t)batch * Tt + m) * NTOP + r] = bi;
  }
}

// fp64 rescore of the NTOP shortlist, emit exact top-7 (score desc, idx asc)
__global__ __launch_bounds__(64) void knn_rescore(
    const float* __restrict__ xT, const int* __restrict__ idx10,
    int* __restrict__ idxout) {
  int t = blockIdx.x;
  int b = blockIdx.y;
  int lane = threadIdx.x;
  const float* xTb = xT + (size_t)b * Tt * Cc;
  const float* xm = xTb + (size_t)t * Cc;
  double sc = -1e300;
  int cid = 0x7fffffff;
  if (lane < NTOP) {
    int j = idx10[((size_t)b * Tt + t) * NTOP + lane];
    const float* xn = xTb + (size_t)j * Cc;
    double dot = 0.0, nn = 0.0;
    for (int c = 0; c < Cc; c += 4) {
      float4 a = *(const float4*)(xm + c);
      float4 v = *(const float4*)(xn + c);
      dot += (double)a.x * v.x + (double)a.y * v.y + (double)a.z * v.z + (double)a.w * v.w;
      nn  += (double)v.x * v.x + (double)v.y * v.y + (double)v.z * v.z + (double)v.w * v.w;
    }
    sc = 2.0 * dot - nn;
    cid = j;
  }
  for (int r = 0; r < Kk; ++r) {
    double bs = sc; int bi = cid;
#pragma unroll
    for (int off = 1; off < 64; off <<= 1) {
      double os = __shfl_xor(bs, off);
      int oi = __shfl_xor(bi, off);
      if (os > bs || (os == bs && oi < bi)) { bs = os; bi = oi; }
    }
    if (cid == bi) { sc = -1e300; cid = 0x7fffffff; }
    if (lane == 0) idxout[((size_t)b * Tt + t) * Kk + r] = bi;
  }
}

// wT[c][o] = W[o][c] for c < 256 (neighbor half of dw1)
__global__ void transpose_w(const float* __restrict__ W, float* __restrict__ wT) {
  int c = blockIdx.x; int o = threadIdx.x;
  wT[(size_t)c * Cc + o] = W[(size_t)o * (2 * Cc) + c];
}

// g1[b,o,t,k] = gelu(ctr[b,o,t] + sum_c wT[c][o] * xT[b][idx[b,t,k]][c])
__global__ __launch_bounds__(256) void graph_pw(
    const float* __restrict__ xT, const int* __restrict__ idx,
    const float* __restrict__ wT, const float* __restrict__ ctr,
    float* __restrict__ g1) {
  __shared__ float nb[Cc][8];
  __shared__ int jid[Kk];
  int t = blockIdx.x;
  int b = blockIdx.y;
  int tid = threadIdx.x;
  if (tid < Kk) jid[tid] = idx[((size_t)b * Tt + t) * Kk + tid];
  __syncthreads();
  const float* xTb = xT + (size_t)b * Tt * Cc;
#pragma unroll
  for (int k = 0; k < Kk; ++k)
    nb[tid][k] = xTb[(size_t)jid[k] * Cc + tid];
  __syncthreads();
  int o = tid;
  float acc[Kk];
#pragma unroll
  for (int k = 0; k < Kk; ++k) acc[k] = 0.f;
  for (int c = 0; c < Cc; ++c) {
    float wv = wT[(size_t)c * Cc + o];
#pragma unroll
    for (int k = 0; k < Kk; ++k) acc[k] = fmaf(wv, nb[c][k], acc[k]);
  }
  float cv = ctr[((size_t)b * Cc + o) * Tt + t];
  float* gp = g1 + (((size_t)b * Cc + o) * Tt + t) * (size_t)Kk;
#pragma unroll
  for (int k = 0; k < Kk; ++k) gp[k] = gelu_f(acc[k] + cv);
}

// grouped 5x5 conv over (T,K) pad 2 + bias, max over k, + tout + identity
__global__ __launch_bounds__(256) void gconv2d_max(
    const float* __restrict__ g1, const float* __restrict__ W,
    const float* __restrict__ bias, const float* __restrict__ tout,
    const float* __restrict__ xin, float* __restrict__ xout) {
  int t = blockIdx.x * 256 + threadIdx.x;
  int o = blockIdx.y;
  int b = blockIdx.z;
  int g = o >> 3;
  const float* wp = W + (size_t)o * CG * 25;
  float acc[Kk];
  float bv = bias[o];
#pragma unroll
  for (int k = 0; k < Kk; ++k) acc[k] = bv;
  for (int ci = 0; ci < CG; ++ci) {
    const float* gp = g1 + ((size_t)b * Cc + g * CG + ci) * Tt * (size_t)Kk;
    const float* wc = wp + ci * 25;
#pragma unroll
    for (int dt = 0; dt < 5; ++dt) {
      int tt = t + dt - 2;
      if (tt < 0 || tt >= Tt) continue;
      const float* gr = gp + (size_t)tt * Kk;
      float r[Kk];
#pragma unroll
      for (int k = 0; k < Kk; ++k) r[k] = gr[k];
#pragma unroll
      for (int dk = 0; dk < 5; ++dk) {
        float wv = wc[dt * 5 + dk];
#pragma unroll
        for (int k = 0; k < Kk; ++k) {
          int kk = k + dk - 2;
          if (kk >= 0 && kk < Kk) acc[k] = fmaf(wv, r[kk], acc[k]);
        }
      }
    }
  }
  float m = acc[0];
#pragma unroll
  for (int k = 1; k < Kk; ++k) m = fmaxf(m, acc[k]);
  size_t off = ((size_t)b * Cc + o) * Tt + t;
  xout[off] = tout[off] + m + xin[off];
}

extern "C" void kernel_launch(void* const* d_in, const int* in_sizes, int n_in,
                              void* d_out, int out_size, void* d_ws, size_t ws_size,
                              hipStream_t stream) {
  const float* x0  = (const float*)d_in[0];
  const float* tw1 = (const float*)d_in[1];
  const float* tb1 = (const float*)d_in[2];
  const float* tw2 = (const float*)d_in[3];
  const float* tb2 = (const float*)d_in[4];
  const float* dw1 = (const float*)d_in[5];
  const float* db1 = (const float*)d_in[6];
  const float* dw2 = (const float*)d_in[7];
  const float* db2 = (const float*)d_in[8];
  float* out = (float*)d_out;

  float* ws = (float*)d_ws;
  const size_t NCT = (size_t)Bq * Cc * Tt;
  float* x1   = ws;                 // layer-1 output          [B,C,T]
  float* hbuf = x1 + NCT;           // h, then ctr             [B,C,T]
  float* tbuf = hbuf + NCT;         // tout                    [B,C,T]
  float* xT   = tbuf + NCT;         // transposed x            [B,T,C]
  float* g1   = xT + NCT;           // graph branch activ.     [B,C,T,K]
  float* wT   = g1 + NCT * Kk;      // transposed nb weights   [C,C]
  float* xx   = wT + (size_t)Cc * Cc;    // squared norms      [B,T]
  int* idxb   = (int*)(xx + (size_t)Bq * Tt);   // knn top-7    [B,T,K]
  int* idx10  = idxb + (size_t)Bq * Tt * Kk;    // shortlist    [B,T,NTOP]
  // bf16 hi/lo split aliases g1 (dead until graph_pw writes it)
  unsigned short* xh = (unsigned short*)g1;
  unsigned short* xl = xh + NCT;

  for (int i = 0; i < Ll; ++i) {
    const float* xin = (i == 0) ? x0 : x1;
    float* xout = (i == Ll - 1) ? out : x1;

    transpose_x<<<dim3(Tt/32, Cc/32, Bq), dim3(32, 8), 0, stream>>>(xin, xT);
    cvt_split<<<dim3(NCT/1024), 256, 0, stream>>>(xT, xh, xl);
    pw_conv16<<<dim3(Tt/256, Cc/16, Bq), 256, 0, stream>>>(
        xin, tw1 + (size_t)i * Cc * Cc, Cc, 0, tb1 + (size_t)i * Cc, hbuf, 1);
    gconv1d<<<dim3(Tt/256, Cc, Bq), 256, 0, stream>>>(
        hbuf, tw2 + (size_t)i * Cc * CG * 5, tb2 + (size_t)i * Cc, tbuf);
    sqnorm<<<dim3(Tt/256, Bq), 256, 0, stream>>>(xin, xx);
    knn_mfma<<<dim3(256), 512, 0, stream>>>(xh, xl, xx, idx10);
    knn_rescore<<<dim3(Tt, Bq), 64, 0, stream>>>(xT, idx10, idxb);
    pw_conv16<<<dim3(Tt/256, Cc/16, Bq), 256, 0, stream>>>(
        xin, dw1 + (size_t)i * Cc * 2 * Cc, 2 * Cc, Cc, db1 + (size_t)i * Cc, hbuf, 0);
    transpose_w<<<dim3(Cc), 256, 0, stream>>>(dw1 + (size_t)i * Cc * 2 * Cc, wT);
    graph_pw<<<dim3(Tt, Bq), 256, 0, stream>>>(xT, idxb, wT, hbuf, g1);
    gconv2d_max<<<dim3(Tt/256, Cc, Bq), 256, 0, stream>>>(
        g1, dw2 + (size_t)i * Cc * CG * 25, db2 + (size_t)i * Cc, tbuf, xin, xout);
  }
}

// Round 4
// 1120.848 us; speedup vs baseline: 1.9488x; 1.2995x over previous
//
#include <hip/hip_runtime.h>
#include <math.h>

#define Bq 4
#define Cc 256
#define Tt 2048
#define Kk 7
#define NTOP 10
#define CG 8
#define Ll 2

typedef __attribute__((ext_vector_type(8))) short short8;
typedef __attribute__((ext_vector_type(4))) float floatx4;

__device__ __forceinline__ float gelu_f(float v) {
  return 0.5f * v * (1.0f + erff(v * 0.70710678118654752440f));
}

__device__ __forceinline__ unsigned short bf16_rne(float v) {
  unsigned int u = __float_as_uint(v);
  return (unsigned short)((u + 0x7fffu + ((u >> 16) & 1u)) >> 16);
}

// xT[b][t][c] = x[b][c][t]
__global__ void transpose_x(const float* __restrict__ x, float* __restrict__ xT) {
  __shared__ float tile[32][33];
  int b = blockIdx.z;
  int t0 = blockIdx.x * 32, c0 = blockIdx.y * 32;
  int tx = threadIdx.x, ty = threadIdx.y;
  const float* xb = x + (size_t)b * Cc * Tt;
  for (int r = ty; r < 32; r += 8)
    tile[r][tx] = xb[(size_t)(c0 + r) * Tt + t0 + tx];
  __syncthreads();
  float* xo = xT + (size_t)b * Tt * Cc;
  for (int r = ty; r < 32; r += 8)
    xo[(size_t)(t0 + r) * Cc + c0 + tx] = tile[tx][r];
}

// split xT into bf16 hi/lo pair (x ~= hi + lo)
__global__ __launch_bounds__(256) void cvt_split(
    const float* __restrict__ xT, unsigned short* __restrict__ xh,
    unsigned short* __restrict__ xl) {
  int i = (blockIdx.x * 256 + threadIdx.x) * 4;
  float4 v = *(const float4*)(xT + i);
  ushort4 h, l;
  float f;
  h.x = bf16_rne(v.x); f = v.x - __uint_as_float((unsigned int)h.x << 16); l.x = bf16_rne(f);
  h.y = bf16_rne(v.y); f = v.y - __uint_as_float((unsigned int)h.y << 16); l.y = bf16_rne(f);
  h.z = bf16_rne(v.z); f = v.z - __uint_as_float((unsigned int)h.z << 16); l.z = bf16_rne(f);
  h.w = bf16_rne(v.w); f = v.w - __uint_as_float((unsigned int)h.w << 16); l.w = bf16_rne(f);
  *(ushort4*)(xh + i) = h;
  *(ushort4*)(xl + i) = l;
}

// y[b,o,t] = act((bias? bias[o]:0) + sum_c W[o*wstride + woff + c] * x[b,c,t])
__global__ __launch_bounds__(256) void pw_conv16(
    const float* __restrict__ x, const float* __restrict__ W, int wstride, int woff,
    const float* __restrict__ bias, float* __restrict__ y, int do_gelu) {
  int t = blockIdx.x * 256 + threadIdx.x;
  int o0 = blockIdx.y * 16;
  int b = blockIdx.z;
  const float* xp = x + (size_t)b * Cc * Tt + t;
  const float* wp = W + (size_t)o0 * wstride + woff;
  float acc[16];
#pragma unroll
  for (int j = 0; j < 16; ++j) acc[j] = bias ? bias[o0 + j] : 0.f;
  for (int c = 0; c < Cc; ++c) {
    float xv = xp[(size_t)c * Tt];
#pragma unroll
    for (int j = 0; j < 16; ++j)
      acc[j] = fmaf(wp[(size_t)j * wstride + c], xv, acc[j]);
  }
#pragma unroll
  for (int j = 0; j < 16; ++j) {
    float v = acc[j];
    if (do_gelu) v = gelu_f(v);
    y[((size_t)b * Cc + o0 + j) * Tt + t] = v;
  }
}

// grouped conv1d k=5 pad=2
__global__ __launch_bounds__(256) void gconv1d(
    const float* __restrict__ h, const float* __restrict__ W, // [C][8][5]
    const float* __restrict__ bias, float* __restrict__ tout) {
  int t = blockIdx.x * 256 + threadIdx.x;
  int o = blockIdx.y, b = blockIdx.z;
  int g = o >> 3;
  const float* hp = h + ((size_t)b * Cc + g * CG) * Tt;
  const float* wp = W + (size_t)o * CG * 5;
  float acc = bias[o];
#pragma unroll
  for (int ci = 0; ci < CG; ++ci) {
#pragma unroll
    for (int dt = 0; dt < 5; ++dt) {
      int tt = t + dt - 2;
      if (tt >= 0 && tt < Tt)
        acc = fmaf(wp[ci * 5 + dt], hp[(size_t)ci * Tt + tt], acc);
    }
  }
  tout[((size_t)b * Cc + o) * Tt + t] = acc;
}

__global__ void sqnorm(const float* __restrict__ x, float* __restrict__ xx) {
  int t = blockIdx.x * 256 + threadIdx.x;
  int b = blockIdx.y;
  const float* xp = x + (size_t)b * Cc * Tt + t;
  float acc = 0.f;
  for (int c = 0; c < Cc; ++c) { float v = xp[(size_t)c * Tt]; acc = fmaf(v, v, acc); }
  xx[(size_t)b * Tt + t] = acc;
}

// one-batch score GEMM: S[m][n] = 2*dot(x_m,x_n) - xx[n], split-bf16 (hh+hl+lh).
// 128x128 tile, 256 threads = 4 waves, each wave 64x64 (4x4 16x16 frags).
__global__ __launch_bounds__(256) void score_gemm(
    const unsigned short* __restrict__ xh, const unsigned short* __restrict__ xl,
    const float* __restrict__ xx, float* __restrict__ S) {
  __shared__ __align__(16) unsigned short Ah[128][40], Al[128][40];
  __shared__ __align__(16) unsigned short Bh[128][40], Bl[128][40];
  int m0 = blockIdx.y * 128, n0 = blockIdx.x * 128;
  int tid = threadIdx.x;
  int w = tid >> 6, lane = tid & 63, quad = lane >> 4, l15 = lane & 15;
  int wm = (w >> 1) * 64, wn = (w & 1) * 64;
  floatx4 acc[4][4];
#pragma unroll
  for (int i = 0; i < 4; ++i)
#pragma unroll
    for (int j = 0; j < 4; ++j) acc[i][j] = (floatx4){0.f, 0.f, 0.f, 0.f};

  int sr = tid >> 1;                 // staging row 0..127
  int sq = (tid & 1) * 2;            // uint4 index 0/2
  for (int kc = 0; kc < Cc; kc += 32) {
    __syncthreads();                 // prior-iteration frag reads done
    {
      const unsigned short* am = xh + (size_t)(m0 + sr) * Cc + kc + sq * 8;
      *(uint4*)&Ah[sr][sq * 8] = *(const uint4*)am;
      *(uint4*)&Ah[sr][sq * 8 + 8] = *(const uint4*)(am + 8);
      const unsigned short* al = xl + (size_t)(m0 + sr) * Cc + kc + sq * 8;
      *(uint4*)&Al[sr][sq * 8] = *(const uint4*)al;
      *(uint4*)&Al[sr][sq * 8 + 8] = *(const uint4*)(al + 8);
      const unsigned short* bm = xh + (size_t)(n0 + sr) * Cc + kc + sq * 8;
      *(uint4*)&Bh[sr][sq * 8] = *(const uint4*)bm;
      *(uint4*)&Bh[sr][sq * 8 + 8] = *(const uint4*)(bm + 8);
      const unsigned short* bl = xl + (size_t)(n0 + sr) * Cc + kc + sq * 8;
      *(uint4*)&Bl[sr][sq * 8] = *(const uint4*)bl;
      *(uint4*)&Bl[sr][sq * 8 + 8] = *(const uint4*)(bl + 8);
    }
    __syncthreads();
    int ka = quad * 8;
    short8 a_h[4], a_l[4], b_h[4], b_l[4];
#pragma unroll
    for (int f = 0; f < 4; ++f) {
      a_h[f] = *(const short8*)&Ah[wm + f * 16 + l15][ka];
      a_l[f] = *(const short8*)&Al[wm + f * 16 + l15][ka];
      b_h[f] = *(const short8*)&Bh[wn + f * 16 + l15][ka];
      b_l[f] = *(const short8*)&Bl[wn + f * 16 + l15][ka];
    }
#pragma unroll
    for (int fm = 0; fm < 4; ++fm)
#pragma unroll
      for (int fn = 0; fn < 4; ++fn) {
        acc[fm][fn] = __builtin_amdgcn_mfma_f32_16x16x32_bf16(a_h[fm], b_h[fn], acc[fm][fn], 0, 0, 0);
        acc[fm][fn] = __builtin_amdgcn_mfma_f32_16x16x32_bf16(a_h[fm], b_l[fn], acc[fm][fn], 0, 0, 0);
        acc[fm][fn] = __builtin_amdgcn_mfma_f32_16x16x32_bf16(a_l[fm], b_h[fn], acc[fm][fn], 0, 0, 0);
      }
  }
  // epilogue: C layout col=lane&15 (n), row=quad*4+reg (m)
#pragma unroll
  for (int fn = 0; fn < 4; ++fn) {
    int n = n0 + wn + fn * 16 + l15;
    float xv = xx[n];
#pragma unroll
    for (int fm = 0; fm < 4; ++fm) {
      int m = m0 + wm + fm * 16 + quad * 4;
#pragma unroll
      for (int r = 0; r < 4; ++r)
        S[(size_t)(m + r) * Tt + n] = fmaf(2.f, acc[fm][fn][r], -xv);
    }
  }
}

// top-10 scan over one batch's S rows; wave per row, 8 rows per block
__global__ __launch_bounds__(512) void topk_scan(
    const float* __restrict__ S, int* __restrict__ idx10) {
  int m = blockIdx.x * 8 + (threadIdx.x >> 6);
  int lane = threadIdx.x & 63;
  const float* row = S + (size_t)m * Tt;
  float s[NTOP]; int idl[NTOP];
#pragma unroll
  for (int j = 0; j < NTOP; ++j) { s[j] = -INFINITY; idl[j] = 0x7fffffff; }
  for (int c0 = lane * 4; c0 < Tt; c0 += 256) {
    float4 v = *(const float4*)(row + c0);
    float cand[4] = {v.x, v.y, v.z, v.w};
#pragma unroll
    for (int e = 0; e < 4; ++e) {
      float sc = cand[e];
      if (sc > s[NTOP - 1]) {
        s[NTOP - 1] = sc; idl[NTOP - 1] = c0 + e;
#pragma unroll
        for (int j = NTOP - 1; j > 0; --j) {
          if (s[j] > s[j - 1]) {
            float ts = s[j]; s[j] = s[j - 1]; s[j - 1] = ts;
            int ti = idl[j]; idl[j] = idl[j - 1]; idl[j - 1] = ti;
          }
        }
      }
    }
  }
  int ptr = 0;
  for (int r = 0; r < NTOP; ++r) {
    float cs = (ptr < NTOP) ? s[ptr] : -INFINITY;
    int cid = (ptr < NTOP) ? idl[ptr] : 0x7fffffff;
    float bs = cs; int bi = cid;
#pragma unroll
    for (int off = 1; off < 64; off <<= 1) {
      float os = __shfl_xor(bs, off);
      int oi = __shfl_xor(bi, off);
      if (os > bs || (os == bs && oi < bi)) { bs = os; bi = oi; }
    }
    if (cid == bi) ptr++;
    if (lane == 0) idx10[(size_t)m * NTOP + r] = bi;
  }
}

// fp64 rescore of the NTOP shortlist, emit exact top-7 (score desc, idx asc)
__global__ __launch_bounds__(64) void knn_rescore(
    const float* __restrict__ xT, const int* __restrict__ idx10,
    int* __restrict__ idxout) {
  int t = blockIdx.x;
  int b = blockIdx.y;
  int lane = threadIdx.x;
  const float* xTb = xT + (size_t)b * Tt * Cc;
  const float* xm = xTb + (size_t)t * Cc;
  double sc = -1e300;
  int cid = 0x7fffffff;
  if (lane < NTOP) {
    int j = idx10[((size_t)b * Tt + t) * NTOP + lane];
    const float* xn = xTb + (size_t)j * Cc;
    double dot = 0.0, nn = 0.0;
    for (int c = 0; c < Cc; c += 4) {
      float4 a = *(const float4*)(xm + c);
      float4 v = *(const float4*)(xn + c);
      dot += (double)a.x * v.x + (double)a.y * v.y + (double)a.z * v.z + (double)a.w * v.w;
      nn  += (double)v.x * v.x + (double)v.y * v.y + (double)v.z * v.z + (double)v.w * v.w;
    }
    sc = 2.0 * dot - nn;
    cid = j;
  }
  for (int r = 0; r < Kk; ++r) {
    double bs = sc; int bi = cid;
#pragma unroll
    for (int off = 1; off < 64; off <<= 1) {
      double os = __shfl_xor(bs, off);
      int oi = __shfl_xor(bi, off);
      if (os > bs || (os == bs && oi < bi)) { bs = os; bi = oi; }
    }
    if (cid == bi) { sc = -1e300; cid = 0x7fffffff; }
    if (lane == 0) idxout[((size_t)b * Tt + t) * Kk + r] = bi;
  }
}

// g1[b][o][k][t] = gelu(ctr[b,o,t] + nbr[b,o,idx[b,t,k]])
__global__ __launch_bounds__(256) void g1_gather(
    const float* __restrict__ ctr, const float* __restrict__ nbr,
    const int* __restrict__ idx, float* __restrict__ g1) {
  int t = blockIdx.x * 256 + threadIdx.x;
  int o = blockIdx.y;
  int b = blockIdx.z;
  const float* nbrow = nbr + ((size_t)b * Cc + o) * Tt;
  float cv = ctr[((size_t)b * Cc + o) * Tt + t];
  const int* ip = idx + ((size_t)b * Tt + t) * Kk;
  float* gp = g1 + ((size_t)b * Cc + o) * Kk * Tt + t;
#pragma unroll
  for (int k = 0; k < Kk; ++k) {
    int j = ip[k];
    gp[(size_t)k * Tt] = gelu_f(cv + nbrow[j]);
  }
}

// grouped 5x5 conv over (K,T) pad 2 + bias, max over k, + tout + identity.
// g1 layout [b][o][k][t] -> all loads lane-coalesced.
__global__ __launch_bounds__(256) void gconv2d_max(
    const float* __restrict__ g1, const float* __restrict__ W, // [C][8][5][5]
    const float* __restrict__ bias, const float* __restrict__ tout,
    const float* __restrict__ xin, float* __restrict__ xout) {
  int t = blockIdx.x * 256 + threadIdx.x;
  int o = blockIdx.y;
  int b = blockIdx.z;
  int g = o >> 3;
  const float* wp = W + (size_t)o * CG * 25;
  float acc[Kk];
  float bv = bias[o];
#pragma unroll
  for (int k = 0; k < Kk; ++k) acc[k] = bv;
  for (int ci = 0; ci < CG; ++ci) {
    const float* gp = g1 + ((size_t)b * Cc + g * CG + ci) * Kk * Tt;
    float r[Kk][5];
#pragma unroll
    for (int k = 0; k < Kk; ++k) {
#pragma unroll
      for (int dt = 0; dt < 5; ++dt) {
        int tt = t + dt - 2;
        r[k][dt] = (tt >= 0 && tt < Tt) ? gp[(size_t)k * Tt + tt] : 0.f;
      }
    }
    const float* wc = wp + ci * 25;
#pragma unroll
    for (int dt = 0; dt < 5; ++dt) {
#pragma unroll
      for (int dk = 0; dk < 5; ++dk) {
        float wv = wc[dt * 5 + dk];
#pragma unroll
        for (int k = 0; k < Kk; ++k) {
          int kin = k + dk - 2;
          if (kin >= 0 && kin < Kk) acc[k] = fmaf(wv, r[kin][dt], acc[k]);
        }
      }
    }
  }
  float m = acc[0];
#pragma unroll
  for (int k = 1; k < Kk; ++k) m = fmaxf(m, acc[k]);
  size_t off = ((size_t)b * Cc + o) * Tt + t;
  xout[off] = tout[off] + m + xin[off];
}

extern "C" void kernel_launch(void* const* d_in, const int* in_sizes, int n_in,
                              void* d_out, int out_size, void* d_ws, size_t ws_size,
                              hipStream_t stream) {
  const float* x0  = (const float*)d_in[0];
  const float* tw1 = (const float*)d_in[1];
  const float* tb1 = (const float*)d_in[2];
  const float* tw2 = (const float*)d_in[3];
  const float* tb2 = (const float*)d_in[4];
  const float* dw1 = (const float*)d_in[5];
  const float* db1 = (const float*)d_in[6];
  const float* dw2 = (const float*)d_in[7];
  const float* db2 = (const float*)d_in[8];
  float* out = (float*)d_out;

  float* ws = (float*)d_ws;
  const size_t NCT = (size_t)Bq * Cc * Tt;      // 2M elements
  float* x1   = ws;                 // layer-1 output           [B,C,T]
  float* hbuf = x1 + NCT;           // h, then ctr              [B,C,T]
  float* tbuf = hbuf + NCT;         // tout                     [B,C,T]
  float* xT   = tbuf + NCT;         // xT; later nbr            [B,T,C]/[B,C,T]
  float* g1   = xT + NCT;           // graph activ [B][C][K][T] (58.7MB region)
  // xh/xl/S alias the g1 region (dead until g1_gather)
  unsigned short* xh = (unsigned short*)g1;             // [B,T,C] bf16 hi
  unsigned short* xl = xh + NCT;                        // [B,T,C] bf16 lo
  float* S    = g1 + NCT;           // per-batch scores [T,T] (16MB)
  float* xx   = g1 + NCT * Kk;      // squared norms            [B,T]
  int* idxb   = (int*)(xx + (size_t)Bq * Tt);           // top-7  [B,T,K]
  int* idx10  = idxb + (size_t)Bq * Tt * Kk;            // top-10 [B,T,NTOP]
  float* nbr  = xT;                 // neighbor conv out, overwrites xT after rescore

  for (int i = 0; i < Ll; ++i) {
    const float* xin = (i == 0) ? x0 : x1;
    float* xout = (i == Ll - 1) ? out : x1;

    transpose_x<<<dim3(Tt/32, Cc/32, Bq), dim3(32, 8), 0, stream>>>(xin, xT);
    cvt_split<<<dim3(NCT/1024), 256, 0, stream>>>(xT, xh, xl);
    pw_conv16<<<dim3(Tt/256, Cc/16, Bq), 256, 0, stream>>>(
        xin, tw1 + (size_t)i * Cc * Cc, Cc, 0, tb1 + (size_t)i * Cc, hbuf, 1);
    gconv1d<<<dim3(Tt/256, Cc, Bq), 256, 0, stream>>>(
        hbuf, tw2 + (size_t)i * Cc * CG * 5, tb2 + (size_t)i * Cc, tbuf);
    sqnorm<<<dim3(Tt/256, Bq), 256, 0, stream>>>(xin, xx);
    for (int b = 0; b < Bq; ++b) {
      score_gemm<<<dim3(16, 16), 256, 0, stream>>>(
          xh + (size_t)b * Tt * Cc, xl + (size_t)b * Tt * Cc,
          xx + (size_t)b * Tt, S);
      topk_scan<<<dim3(Tt/8), 512, 0, stream>>>(S, idx10 + (size_t)b * Tt * NTOP);
    }
    knn_rescore<<<dim3(Tt, Bq), 64, 0, stream>>>(xT, idx10, idxb);
    // center half of dw1 (input channels 256..511) with bias -> ctr
    pw_conv16<<<dim3(Tt/256, Cc/16, Bq), 256, 0, stream>>>(
        xin, dw1 + (size_t)i * Cc * 2 * Cc, 2 * Cc, Cc, db1 + (size_t)i * Cc, hbuf, 0);
    // neighbor half of dw1 (input channels 0..255), no bias -> nbr (overwrites xT)
    pw_conv16<<<dim3(Tt/256, Cc/16, Bq), 256, 0, stream>>>(
        xin, dw1 + (size_t)i * Cc * 2 * Cc, 2 * Cc, 0, nullptr, nbr, 0);
    g1_gather<<<dim3(Tt/256, Cc, Bq), 256, 0, stream>>>(hbuf, nbr, idxb, g1);
    gconv2d_max<<<dim3(Tt/256, Cc, Bq), 256, 0, stream>>>(
        g1, dw2 + (size_t)i * Cc * CG * 25, db2 + (size_t)i * Cc, tbuf, xin, xout);
  }
}

// Round 5
// 1010.221 us; speedup vs baseline: 2.1622x; 1.1095x over previous
//
#include <hip/hip_runtime.h>
#include <math.h>

#define Bq 4
#define Cc 256
#define Tt 2048
#define Kk 7
#define NTOP 10
#define CG 8
#define Ll 2

typedef __attribute__((ext_vector_type(8))) short short8;
typedef __attribute__((ext_vector_type(4))) float floatx4;
typedef __attribute__((ext_vector_type(2))) float floatx2;

__device__ __forceinline__ float gelu_f(float v) {
  return 0.5f * v * (1.0f + erff(v * 0.70710678118654752440f));
}

__device__ __forceinline__ unsigned short bf16_rne(float v) {
  unsigned int u = __float_as_uint(v);
  return (unsigned short)((u + 0x7fffu + ((u >> 16) & 1u)) >> 16);
}

// xT[b][t][c] = x[b][c][t]
__global__ void transpose_x(const float* __restrict__ x, float* __restrict__ xT) {
  __shared__ float tile[32][33];
  int b = blockIdx.z;
  int t0 = blockIdx.x * 32, c0 = blockIdx.y * 32;
  int tx = threadIdx.x, ty = threadIdx.y;
  const float* xb = x + (size_t)b * Cc * Tt;
  for (int r = ty; r < 32; r += 8)
    tile[r][tx] = xb[(size_t)(c0 + r) * Tt + t0 + tx];
  __syncthreads();
  float* xo = xT + (size_t)b * Tt * Cc;
  for (int r = ty; r < 32; r += 8)
    xo[(size_t)(t0 + r) * Cc + c0 + tx] = tile[tx][r];
}

// split xT into bf16 hi/lo pair (x ~= hi + lo)
__global__ __launch_bounds__(256) void cvt_split(
    const float* __restrict__ xT, unsigned short* __restrict__ xh,
    unsigned short* __restrict__ xl) {
  int i = (blockIdx.x * 256 + threadIdx.x) * 4;
  float4 v = *(const float4*)(xT + i);
  ushort4 h, l;
  float f;
  h.x = bf16_rne(v.x); f = v.x - __uint_as_float((unsigned int)h.x << 16); l.x = bf16_rne(f);
  h.y = bf16_rne(v.y); f = v.y - __uint_as_float((unsigned int)h.y << 16); l.y = bf16_rne(f);
  h.z = bf16_rne(v.z); f = v.z - __uint_as_float((unsigned int)h.z << 16); l.z = bf16_rne(f);
  h.w = bf16_rne(v.w); f = v.w - __uint_as_float((unsigned int)h.w << 16); l.w = bf16_rne(f);
  *(ushort4*)(xh + i) = h;
  *(ushort4*)(xl + i) = l;
}

// y[b,o,t] = act((bias? bias[o]:0) + sum_c W[o*wstride + woff + c] * x[b,c,t])
__global__ __launch_bounds__(256) void pw_conv16(
    const float* __restrict__ x, const float* __restrict__ W, int wstride, int woff,
    const float* __restrict__ bias, float* __restrict__ y, int do_gelu) {
  int t = blockIdx.x * 256 + threadIdx.x;
  int o0 = blockIdx.y * 16;
  int b = blockIdx.z;
  const float* xp = x + (size_t)b * Cc * Tt + t;
  const float* wp = W + (size_t)o0 * wstride + woff;
  float acc[16];
#pragma unroll
  for (int j = 0; j < 16; ++j) acc[j] = bias ? bias[o0 + j] : 0.f;
  for (int c = 0; c < Cc; ++c) {
    float xv = xp[(size_t)c * Tt];
#pragma unroll
    for (int j = 0; j < 16; ++j)
      acc[j] = fmaf(wp[(size_t)j * wstride + c], xv, acc[j]);
  }
#pragma unroll
  for (int j = 0; j < 16; ++j) {
    float v = acc[j];
    if (do_gelu) v = gelu_f(v);
    y[((size_t)b * Cc + o0 + j) * Tt + t] = v;
  }
}

// grouped conv1d k=5 pad=2
__global__ __launch_bounds__(256) void gconv1d(
    const float* __restrict__ h, const float* __restrict__ W, // [C][8][5]
    const float* __restrict__ bias, float* __restrict__ tout) {
  int t = blockIdx.x * 256 + threadIdx.x;
  int o = blockIdx.y, b = blockIdx.z;
  int g = o >> 3;
  const float* hp = h + ((size_t)b * Cc + g * CG) * Tt;
  const float* wp = W + (size_t)o * CG * 5;
  float acc = bias[o];
#pragma unroll
  for (int ci = 0; ci < CG; ++ci) {
#pragma unroll
    for (int dt = 0; dt < 5; ++dt) {
      int tt = t + dt - 2;
      if (tt >= 0 && tt < Tt)
        acc = fmaf(wp[ci * 5 + dt], hp[(size_t)ci * Tt + tt], acc);
    }
  }
  tout[((size_t)b * Cc + o) * Tt + t] = acc;
}

__global__ void sqnorm(const float* __restrict__ x, float* __restrict__ xx) {
  int t = blockIdx.x * 256 + threadIdx.x;
  int b = blockIdx.y;
  const float* xp = x + (size_t)b * Cc * Tt + t;
  float acc = 0.f;
  for (int c = 0; c < Cc; ++c) { float v = xp[(size_t)c * Tt]; acc = fmaf(v, v, acc); }
  xx[(size_t)b * Tt + t] = acc;
}

// one-batch score GEMM: S[m][n] = 2*dot(x_m,x_n) - xx[n], split-bf16 (hh+hl+lh).
__global__ __launch_bounds__(256) void score_gemm(
    const unsigned short* __restrict__ xh, const unsigned short* __restrict__ xl,
    const float* __restrict__ xx, float* __restrict__ S) {
  __shared__ __align__(16) unsigned short Ah[128][40], Al[128][40];
  __shared__ __align__(16) unsigned short Bh[128][40], Bl[128][40];
  int m0 = blockIdx.y * 128, n0 = blockIdx.x * 128;
  int tid = threadIdx.x;
  int w = tid >> 6, lane = tid & 63, quad = lane >> 4, l15 = lane & 15;
  int wm = (w >> 1) * 64, wn = (w & 1) * 64;
  floatx4 acc[4][4];
#pragma unroll
  for (int i = 0; i < 4; ++i)
#pragma unroll
    for (int j = 0; j < 4; ++j) acc[i][j] = (floatx4){0.f, 0.f, 0.f, 0.f};

  int sr = tid >> 1;                 // staging row 0..127
  int sq = (tid & 1) * 2;            // uint4 index 0/2
  for (int kc = 0; kc < Cc; kc += 32) {
    __syncthreads();
    {
      const unsigned short* am = xh + (size_t)(m0 + sr) * Cc + kc + sq * 8;
      *(uint4*)&Ah[sr][sq * 8] = *(const uint4*)am;
      *(uint4*)&Ah[sr][sq * 8 + 8] = *(const uint4*)(am + 8);
      const unsigned short* al = xl + (size_t)(m0 + sr) * Cc + kc + sq * 8;
      *(uint4*)&Al[sr][sq * 8] = *(const uint4*)al;
      *(uint4*)&Al[sr][sq * 8 + 8] = *(const uint4*)(al + 8);
      const unsigned short* bm = xh + (size_t)(n0 + sr) * Cc + kc + sq * 8;
      *(uint4*)&Bh[sr][sq * 8] = *(const uint4*)bm;
      *(uint4*)&Bh[sr][sq * 8 + 8] = *(const uint4*)(bm + 8);
      const unsigned short* bl = xl + (size_t)(n0 + sr) * Cc + kc + sq * 8;
      *(uint4*)&Bl[sr][sq * 8] = *(const uint4*)bl;
      *(uint4*)&Bl[sr][sq * 8 + 8] = *(const uint4*)(bl + 8);
    }
    __syncthreads();
    int ka = quad * 8;
    short8 a_h[4], a_l[4], b_h[4], b_l[4];
#pragma unroll
    for (int f = 0; f < 4; ++f) {
      a_h[f] = *(const short8*)&Ah[wm + f * 16 + l15][ka];
      a_l[f] = *(const short8*)&Al[wm + f * 16 + l15][ka];
      b_h[f] = *(const short8*)&Bh[wn + f * 16 + l15][ka];
      b_l[f] = *(const short8*)&Bl[wn + f * 16 + l15][ka];
    }
#pragma unroll
    for (int fm = 0; fm < 4; ++fm)
#pragma unroll
      for (int fn = 0; fn < 4; ++fn) {
        acc[fm][fn] = __builtin_amdgcn_mfma_f32_16x16x32_bf16(a_h[fm], b_h[fn], acc[fm][fn], 0, 0, 0);
        acc[fm][fn] = __builtin_amdgcn_mfma_f32_16x16x32_bf16(a_h[fm], b_l[fn], acc[fm][fn], 0, 0, 0);
        acc[fm][fn] = __builtin_amdgcn_mfma_f32_16x16x32_bf16(a_l[fm], b_h[fn], acc[fm][fn], 0, 0, 0);
      }
  }
#pragma unroll
  for (int fn = 0; fn < 4; ++fn) {
    int n = n0 + wn + fn * 16 + l15;
    float xv = xx[n];
#pragma unroll
    for (int fm = 0; fm < 4; ++fm) {
      int m = m0 + wm + fm * 16 + quad * 4;
#pragma unroll
      for (int r = 0; r < 4; ++r)
        S[(size_t)(m + r) * Tt + n] = fmaf(2.f, acc[fm][fn][r], -xv);
    }
  }
}

// top-10 scan over one batch's S rows; wave per row, 8 rows per block
__global__ __launch_bounds__(512) void topk_scan(
    const float* __restrict__ S, int* __restrict__ idx10) {
  int m = blockIdx.x * 8 + (threadIdx.x >> 6);
  int lane = threadIdx.x & 63;
  const float* row = S + (size_t)m * Tt;
  float s[NTOP]; int idl[NTOP];
#pragma unroll
  for (int j = 0; j < NTOP; ++j) { s[j] = -INFINITY; idl[j] = 0x7fffffff; }
  for (int c0 = lane * 4; c0 < Tt; c0 += 256) {
    float4 v = *(const float4*)(row + c0);
    float cand[4] = {v.x, v.y, v.z, v.w};
#pragma unroll
    for (int e = 0; e < 4; ++e) {
      float sc = cand[e];
      if (sc > s[NTOP - 1]) {
        s[NTOP - 1] = sc; idl[NTOP - 1] = c0 + e;
#pragma unroll
        for (int j = NTOP - 1; j > 0; --j) {
          if (s[j] > s[j - 1]) {
            float ts = s[j]; s[j] = s[j - 1]; s[j - 1] = ts;
            int ti = idl[j]; idl[j] = idl[j - 1]; idl[j - 1] = ti;
          }
        }
      }
    }
  }
  int ptr = 0;
  for (int r = 0; r < NTOP; ++r) {
    float cs = (ptr < NTOP) ? s[ptr] : -INFINITY;
    int cid = (ptr < NTOP) ? idl[ptr] : 0x7fffffff;
    float bs = cs; int bi = cid;
#pragma unroll
    for (int off = 1; off < 64; off <<= 1) {
      float os = __shfl_xor(bs, off);
      int oi = __shfl_xor(bi, off);
      if (os > bs || (os == bs && oi < bi)) { bs = os; bi = oi; }
    }
    if (cid == bi) ptr++;
    if (lane == 0) idx10[(size_t)m * NTOP + r] = bi;
  }
}

// fp64 rescore of the NTOP shortlist, emit exact top-7 (score desc, idx asc)
__global__ __launch_bounds__(64) void knn_rescore(
    const float* __restrict__ xT, const int* __restrict__ idx10,
    int* __restrict__ idxout) {
  int t = blockIdx.x;
  int b = blockIdx.y;
  int lane = threadIdx.x;
  const float* xTb = xT + (size_t)b * Tt * Cc;
  const float* xm = xTb + (size_t)t * Cc;
  double sc = -1e300;
  int cid = 0x7fffffff;
  if (lane < NTOP) {
    int j = idx10[((size_t)b * Tt + t) * NTOP + lane];
    const float* xn = xTb + (size_t)j * Cc;
    double dot = 0.0, nn = 0.0;
    for (int c = 0; c < Cc; c += 4) {
      float4 a = *(const float4*)(xm + c);
      float4 v = *(const float4*)(xn + c);
      dot += (double)a.x * v.x + (double)a.y * v.y + (double)a.z * v.z + (double)a.w * v.w;
      nn  += (double)v.x * v.x + (double)v.y * v.y + (double)v.z * v.z + (double)v.w * v.w;
    }
    sc = 2.0 * dot - nn;
    cid = j;
  }
  for (int r = 0; r < Kk; ++r) {
    double bs = sc; int bi = cid;
#pragma unroll
    for (int off = 1; off < 64; off <<= 1) {
      double os = __shfl_xor(bs, off);
      int oi = __shfl_xor(bi, off);
      if (os > bs || (os == bs && oi < bi)) { bs = os; bi = oi; }
    }
    if (cid == bi) { sc = -1e300; cid = 0x7fffffff; }
    if (lane == 0) idxout[((size_t)b * Tt + t) * Kk + r] = bi;
  }
}

// Fused graph tail: g1 = gelu(ctr + nbr[idx]) staged in LDS (never hits HBM),
// grouped 5x5 conv over (K,T) + bias, max over k, + tout + identity.
// Block = (t-tile 128, group, batch); 256 threads.
__global__ __launch_bounds__(256) void graph_tail(
    const float* __restrict__ ctr, const float* __restrict__ nbr,
    const int* __restrict__ idx, const float* __restrict__ W, // [C][8][5][5]
    const float* __restrict__ bias, const float* __restrict__ tout,
    const float* __restrict__ xin, float* __restrict__ xout) {
  __shared__ __align__(16) float gt[CG][Kk][132];  // [ci][k][t0-2+tl], 29.6 KB
  __shared__ int jt[132][Kk];                      // idx tile (halo incl.)
  int t0 = blockIdx.x * 128;
  int g = blockIdx.y;
  int b = blockIdx.z;
  int tid = threadIdx.x;
  const float* ctrg = ctr + ((size_t)b * Cc + g * CG) * Tt;
  const float* nbrg = nbr + ((size_t)b * Cc + g * CG) * Tt;

  // stage idx tile (coalesced flat read)
  {
    const int* ib = idx + ((size_t)b * Tt + t0 - 2) * Kk;
    for (int e = tid; e < 132 * Kk; e += 256) {
      int tg = t0 - 2 + e / Kk;
      jt[e / Kk][e % Kk] = (tg >= 0 && tg < Tt) ? ib[e] : 0;
    }
  }
  __syncthreads();
  // stage g1 tile: gelu(ctr + nbr[idx]); zeros at sequence edges
  for (int e = tid; e < CG * Kk * 132; e += 256) {
    int ci = e / (Kk * 132), rem = e % (Kk * 132), k = rem / 132, tl = rem % 132;
    int tg = t0 - 2 + tl;
    float v = 0.f;
    if (tg >= 0 && tg < Tt) {
      int j = jt[tl][k];
      v = gelu_f(ctrg[(size_t)ci * Tt + tg] + nbrg[(size_t)ci * Tt + j]);
    }
    gt[ci][k][tl] = v;
  }
  __syncthreads();

  // conv phase: thread = (o_local = tid>>5, 4 t at tw=(tid&31)*4)
  int ol = tid >> 5, tw = (tid & 31) * 4;
  int o = g * CG + ol;
  const float* wp = W + (size_t)o * CG * 25;
  float bv = bias[o];
  floatx2 acc[Kk][2];
#pragma unroll
  for (int k = 0; k < Kk; ++k) { acc[k][0] = (floatx2){bv, bv}; acc[k][1] = (floatx2){bv, bv}; }

  for (int ci = 0; ci < CG; ++ci) {
    float w[25];
#pragma unroll
    for (int i = 0; i < 25; ++i) w[i] = wp[ci * 25 + i];
#pragma unroll
    for (int kin = 0; kin < Kk; ++kin) {
      float4 ra = *(const float4*)&gt[ci][kin][tw];
      float4 rb = *(const float4*)&gt[ci][kin][tw + 4];
      float r8[8] = {ra.x, ra.y, ra.z, ra.w, rb.x, rb.y, rb.z, rb.w};
      floatx2 rlo[5], rhi[5];
#pragma unroll
      for (int dt = 0; dt < 5; ++dt) {
        rlo[dt] = (floatx2){r8[dt], r8[dt + 1]};
        rhi[dt] = (floatx2){r8[dt + 2], r8[dt + 3]};
      }
#pragma unroll
      for (int dk = 0; dk < 5; ++dk) {
        int k = kin + 2 - dk;          // output k such that input kin = k+dk-2
        if (k < 0 || k >= Kk) continue;  // compile-time pruned
#pragma unroll
        for (int dt = 0; dt < 5; ++dt) {
          float wv = w[dt * 5 + dk];
          floatx2 wv2 = {wv, wv};
          acc[k][0] = __builtin_elementwise_fma(wv2, rlo[dt], acc[k][0]);
          acc[k][1] = __builtin_elementwise_fma(wv2, rhi[dt], acc[k][1]);
        }
      }
    }
  }
  // max over k, + tout + identity
  floatx2 m0 = acc[0][0], m1 = acc[0][1];
#pragma unroll
  for (int k = 1; k < Kk; ++k) {
    m0 = __builtin_elementwise_max(m0, acc[k][0]);
    m1 = __builtin_elementwise_max(m1, acc[k][1]);
  }
  size_t off = ((size_t)b * Cc + o) * Tt + t0 + tw;
  float4 tv = *(const float4*)&tout[off];
  float4 xv = *(const float4*)&xin[off];
  float4 r;
  r.x = tv.x + m0.x + xv.x;
  r.y = tv.y + m0.y + xv.y;
  r.z = tv.z + m1.x + xv.z;
  r.w = tv.w + m1.y + xv.w;
  *(float4*)&xout[off] = r;
}

extern "C" void kernel_launch(void* const* d_in, const int* in_sizes, int n_in,
                              void* d_out, int out_size, void* d_ws, size_t ws_size,
                              hipStream_t stream) {
  const float* x0  = (const float*)d_in[0];
  const float* tw1 = (const float*)d_in[1];
  const float* tb1 = (const float*)d_in[2];
  const float* tw2 = (const float*)d_in[3];
  const float* tb2 = (const float*)d_in[4];
  const float* dw1 = (const float*)d_in[5];
  const float* db1 = (const float*)d_in[6];
  const float* dw2 = (const float*)d_in[7];
  const float* db2 = (const float*)d_in[8];
  float* out = (float*)d_out;

  float* ws = (float*)d_ws;
  const size_t NCT = (size_t)Bq * Cc * Tt;      // 2M elements
  float* x1   = ws;                 // layer-1 output           [B,C,T]
  float* hbuf = x1 + NCT;           // h, then ctr              [B,C,T]
  float* tbuf = hbuf + NCT;         // tout                     [B,C,T]
  float* xT   = tbuf + NCT;         // xT; later nbr            [B,T,C]/[B,C,T]
  float* big  = xT + NCT;           // scratch region (was g1)
  unsigned short* xh = (unsigned short*)big;            // [B,T,C] bf16 hi
  unsigned short* xl = xh + NCT;                        // [B,T,C] bf16 lo
  float* S    = big + NCT;          // per-batch scores [T,T] (16MB)
  float* xx   = big + NCT * Kk;     // squared norms            [B,T]
  int* idxb   = (int*)(xx + (size_t)Bq * Tt);           // top-7  [B,T,K]
  int* idx10  = idxb + (size_t)Bq * Tt * Kk;            // top-10 [B,T,NTOP]
  float* nbr  = xT;                 // neighbor conv out, overwrites xT after rescore

  for (int i = 0; i < Ll; ++i) {
    const float* xin = (i == 0) ? x0 : x1;
    float* xout = (i == Ll - 1) ? out : x1;

    transpose_x<<<dim3(Tt/32, Cc/32, Bq), dim3(32, 8), 0, stream>>>(xin, xT);
    cvt_split<<<dim3(NCT/1024), 256, 0, stream>>>(xT, xh, xl);
    pw_conv16<<<dim3(Tt/256, Cc/16, Bq), 256, 0, stream>>>(
        xin, tw1 + (size_t)i * Cc * Cc, Cc, 0, tb1 + (size_t)i * Cc, hbuf, 1);
    gconv1d<<<dim3(Tt/256, Cc, Bq), 256, 0, stream>>>(
        hbuf, tw2 + (size_t)i * Cc * CG * 5, tb2 + (size_t)i * Cc, tbuf);
    sqnorm<<<dim3(Tt/256, Bq), 256, 0, stream>>>(xin, xx);
    for (int b = 0; b < Bq; ++b) {
      score_gemm<<<dim3(16, 16), 256, 0, stream>>>(
          xh + (size_t)b * Tt * Cc, xl + (size_t)b * Tt * Cc,
          xx + (size_t)b * Tt, S);
      topk_scan<<<dim3(Tt/8), 512, 0, stream>>>(S, idx10 + (size_t)b * Tt * NTOP);
    }
    knn_rescore<<<dim3(Tt, Bq), 64, 0, stream>>>(xT, idx10, idxb);
    // center half of dw1 (input channels 256..511) with bias -> ctr
    pw_conv16<<<dim3(Tt/256, Cc/16, Bq), 256, 0, stream>>>(
        xin, dw1 + (size_t)i * Cc * 2 * Cc, 2 * Cc, Cc, db1 + (size_t)i * Cc, hbuf, 0);
    // neighbor half of dw1 (input channels 0..255), no bias -> nbr (overwrites xT)
    pw_conv16<<<dim3(Tt/256, Cc/16, Bq), 256, 0, stream>>>(
        xin, dw1 + (size_t)i * Cc * 2 * Cc, 2 * Cc, 0, nullptr, nbr, 0);
    graph_tail<<<dim3(Tt/128, Cc/CG, Bq), 256, 0, stream>>>(
        hbuf, nbr, idxb, dw2 + (size_t)i * Cc * CG * 25, db2 + (size_t)i * Cc,
        tbuf, xin, xout);
  }
}

// Round 8
// 860.430 us; speedup vs baseline: 2.5386x; 1.1741x over previous
//
#include <hip/hip_runtime.h>
#include <math.h>

#define Bq 4
#define Cc 256
#define Tt 2048
#define Kk 7
#define NTOP 10
#define CG 8
#define Ll 2
#define NO 768   // fused pointwise outputs: 256 h | 256 ctr | 256 nbr

typedef __attribute__((ext_vector_type(8))) short short8;
typedef __attribute__((ext_vector_type(4))) float floatx4;
typedef __attribute__((ext_vector_type(2))) float floatx2;

__device__ __forceinline__ float gelu_f(float v) {
  return 0.5f * v * (1.0f + erff(v * 0.70710678118654752440f));
}

__device__ __forceinline__ unsigned short bf16_rne(float v) {
  unsigned int u = __float_as_uint(v);
  return (unsigned short)((u + 0x7fffu + ((u >> 16) & 1u)) >> 16);
}

// xT[b][t][c] = x[b][c][t]   (R5 verbatim)
__global__ void transpose_x(const float* __restrict__ x, float* __restrict__ xT) {
  __shared__ float tile[32][33];
  int b = blockIdx.z;
  int t0 = blockIdx.x * 32, c0 = blockIdx.y * 32;
  int tx = threadIdx.x, ty = threadIdx.y;
  const float* xb = x + (size_t)b * Cc * Tt;
  for (int r = ty; r < 32; r += 8)
    tile[r][tx] = xb[(size_t)(c0 + r) * Tt + t0 + tx];
  __syncthreads();
  float* xo = xT + (size_t)b * Tt * Cc;
  for (int r = ty; r < 32; r += 8)
    xo[(size_t)(t0 + r) * Cc + c0 + tx] = tile[tx][r];
}

// split xT into bf16 hi/lo pair (x ~= hi + lo)   (R5 verbatim)
__global__ __launch_bounds__(256) void cvt_split(
    const float* __restrict__ xT, unsigned short* __restrict__ xh,
    unsigned short* __restrict__ xl) {
  int i = (blockIdx.x * 256 + threadIdx.x) * 4;
  float4 v = *(const float4*)(xT + i);
  ushort4 h, l;
  float f;
  h.x = bf16_rne(v.x); f = v.x - __uint_as_float((unsigned int)h.x << 16); l.x = bf16_rne(f);
  h.y = bf16_rne(v.y); f = v.y - __uint_as_float((unsigned int)h.y << 16); l.y = bf16_rne(f);
  h.z = bf16_rne(v.z); f = v.z - __uint_as_float((unsigned int)h.z << 16); l.z = bf16_rne(f);
  h.w = bf16_rne(v.w); f = v.w - __uint_as_float((unsigned int)h.w << 16); l.w = bf16_rne(f);
  *(ushort4*)(xh + i) = h;
  *(ushort4*)(xl + i) = l;
}

// squared norms from x [B,C,T]   (R5 verbatim)
__global__ void sqnorm(const float* __restrict__ x, float* __restrict__ xx) {
  int t = blockIdx.x * 256 + threadIdx.x;
  int b = blockIdx.y;
  const float* xp = x + (size_t)b * Cc * Tt + t;
  float acc = 0.f;
  for (int c = 0; c < Cc; ++c) { float v = xp[(size_t)c * Tt]; acc = fmaf(v, v, acc); }
  xx[(size_t)b * Tt + t] = acc;
}

// fp32 pointwise conv (layer-1 exact path; feeds layer-2 KNN so must match ref fp32)
__global__ __launch_bounds__(256) void pw_conv16(
    const float* __restrict__ x, const float* __restrict__ W, int wstride, int woff,
    const float* __restrict__ bias, float* __restrict__ y, int do_gelu) {
  int t = blockIdx.x * 256 + threadIdx.x;
  int o0 = blockIdx.y * 16;
  int b = blockIdx.z;
  const float* xp = x + (size_t)b * Cc * Tt + t;
  const float* wp = W + (size_t)o0 * wstride + woff;
  float acc[16];
#pragma unroll
  for (int j = 0; j < 16; ++j) acc[j] = bias ? bias[o0 + j] : 0.f;
  for (int c = 0; c < Cc; ++c) {
    float xv = xp[(size_t)c * Tt];
#pragma unroll
    for (int j = 0; j < 16; ++j)
      acc[j] = fmaf(wp[(size_t)j * wstride + c], xv, acc[j]);
  }
#pragma unroll
  for (int j = 0; j < 16; ++j) {
    float v = acc[j];
    if (do_gelu) v = gelu_f(v);
    y[((size_t)b * Cc + o0 + j) * Tt + t] = v;
  }
}

// concat weights [768][256] -> bf16 hi/lo. rows: 0..255 tw1 | 256..511 dw1 center | 512..767 dw1 nbr
__global__ __launch_bounds__(256) void wsplit(
    const float* __restrict__ tw1, const float* __restrict__ dw1,
    unsigned short* __restrict__ wh, unsigned short* __restrict__ wl) {
  int o = blockIdx.x;
  int c = threadIdx.x;
  float v;
  if (o < 256) v = tw1[(size_t)o * Cc + c];
  else if (o < 512) v = dw1[(size_t)(o - 256) * (2 * Cc) + Cc + c];
  else v = dw1[(size_t)(o - 512) * (2 * Cc) + c];
  unsigned short h = bf16_rne(v);
  float f = v - __uint_as_float((unsigned int)h << 16);
  wh[(size_t)o * Cc + c] = h;
  wl[(size_t)o * Cc + c] = bf16_rne(f);
}

// fused pointwise GEMM (layer-2 only): y[o][t] = act(bias + sum_c W[o][c]*x[t][c])
__global__ __launch_bounds__(256) void pw_gemm(
    const unsigned short* __restrict__ wh, const unsigned short* __restrict__ wl,
    const unsigned short* __restrict__ xh, const unsigned short* __restrict__ xl,
    const float* __restrict__ tb1, const float* __restrict__ db1,
    float* __restrict__ hb, float* __restrict__ cb, float* __restrict__ nb) {
  __shared__ __align__(16) unsigned short Ah[128][40], Al[128][40];
  __shared__ __align__(16) unsigned short Bh[128][40], Bl[128][40];
  int mt = blockIdx.x;                  // token tile: b = mt/16, t0 = (mt%16)*128
  int b = mt >> 4;
  int t0 = (mt & 15) * 128;
  int o0 = blockIdx.y * 128;            // output tile
  int tid = threadIdx.x;
  int w = tid >> 6, lane = tid & 63, quad = lane >> 4, l15 = lane & 15;
  int wm = (w >> 1) * 64, wn = (w & 1) * 64;
  floatx4 acc[4][4];
#pragma unroll
  for (int i = 0; i < 4; ++i)
#pragma unroll
    for (int j = 0; j < 4; ++j) acc[i][j] = (floatx4){0.f, 0.f, 0.f, 0.f};

  const unsigned short* xhb = xh + ((size_t)b * Tt + t0) * Cc;
  const unsigned short* xlb = xl + ((size_t)b * Tt + t0) * Cc;
  int sr = tid >> 1;
  int sq = (tid & 1) * 2;
  for (int kc = 0; kc < Cc; kc += 32) {
    __syncthreads();
    {
      const unsigned short* am = wh + (size_t)(o0 + sr) * Cc + kc + sq * 8;
      *(uint4*)&Ah[sr][sq * 8] = *(const uint4*)am;
      *(uint4*)&Ah[sr][sq * 8 + 8] = *(const uint4*)(am + 8);
      const unsigned short* al = wl + (size_t)(o0 + sr) * Cc + kc + sq * 8;
      *(uint4*)&Al[sr][sq * 8] = *(const uint4*)al;
      *(uint4*)&Al[sr][sq * 8 + 8] = *(const uint4*)(al + 8);
      const unsigned short* bm = xhb + (size_t)sr * Cc + kc + sq * 8;
      *(uint4*)&Bh[sr][sq * 8] = *(const uint4*)bm;
      *(uint4*)&Bh[sr][sq * 8 + 8] = *(const uint4*)(bm + 8);
      const unsigned short* bl = xlb + (size_t)sr * Cc + kc + sq * 8;
      *(uint4*)&Bl[sr][sq * 8] = *(const uint4*)bl;
      *(uint4*)&Bl[sr][sq * 8 + 8] = *(const uint4*)(bl + 8);
    }
    __syncthreads();
    int ka = quad * 8;
    short8 a_h[4], a_l[4], b_h[4], b_l[4];
#pragma unroll
    for (int f = 0; f < 4; ++f) {
      a_h[f] = *(const short8*)&Ah[wm + f * 16 + l15][ka];
      a_l[f] = *(const short8*)&Al[wm + f * 16 + l15][ka];
      b_h[f] = *(const short8*)&Bh[wn + f * 16 + l15][ka];
      b_l[f] = *(const short8*)&Bl[wn + f * 16 + l15][ka];
    }
#pragma unroll
    for (int fm = 0; fm < 4; ++fm)
#pragma unroll
      for (int fn = 0; fn < 4; ++fn) {
        acc[fm][fn] = __builtin_amdgcn_mfma_f32_16x16x32_bf16(a_h[fm], b_h[fn], acc[fm][fn], 0, 0, 0);
        acc[fm][fn] = __builtin_amdgcn_mfma_f32_16x16x32_bf16(a_h[fm], b_l[fn], acc[fm][fn], 0, 0, 0);
        acc[fm][fn] = __builtin_amdgcn_mfma_f32_16x16x32_bf16(a_l[fm], b_h[fn], acc[fm][fn], 0, 0, 0);
      }
  }
  // epilogue: range select by o0
  int range = o0 >> 8;                 // 0: h(gelu,tb1)  1: ctr(db1)  2: nbr
  float* dst = (range == 0) ? hb : (range == 1) ? cb : nb;
  const float* bias = (range == 0) ? tb1 : (range == 1) ? db1 : nullptr;
  int ol0 = o0 & 255;
#pragma unroll
  for (int fm = 0; fm < 4; ++fm) {
    int o = ol0 + wm + fm * 16 + quad * 4;
#pragma unroll
    for (int r = 0; r < 4; ++r) {
      float bv = bias ? bias[o + r] : 0.f;
      size_t rowoff = ((size_t)b * Cc + o + r) * Tt + t0;
#pragma unroll
      for (int fn = 0; fn < 4; ++fn) {
        int t = wn + fn * 16 + l15;
        float v = acc[fm][fn][r] + bv;
        if (range == 0) v = gelu_f(v);
        dst[rowoff + t] = v;
      }
    }
  }
}

// grouped conv1d k=5 pad=2   (R5 verbatim)
__global__ __launch_bounds__(256) void gconv1d(
    const float* __restrict__ h, const float* __restrict__ W, // [C][8][5]
    const float* __restrict__ bias, float* __restrict__ tout) {
  int t = blockIdx.x * 256 + threadIdx.x;
  int o = blockIdx.y, b = blockIdx.z;
  int g = o >> 3;
  const float* hp = h + ((size_t)b * Cc + g * CG) * Tt;
  const float* wp = W + (size_t)o * CG * 5;
  float acc = bias[o];
#pragma unroll
  for (int ci = 0; ci < CG; ++ci) {
#pragma unroll
    for (int dt = 0; dt < 5; ++dt) {
      int tt = t + dt - 2;
      if (tt >= 0 && tt < Tt)
        acc = fmaf(wp[ci * 5 + dt], hp[(size_t)ci * Tt + tt], acc);
    }
  }
  tout[((size_t)b * Cc + o) * Tt + t] = acc;
}

// one-batch score GEMM: S[m][n] = 2*dot(x_m,x_n) - xx[n]   (R5 verbatim)
__global__ __launch_bounds__(256) void score_gemm(
    const unsigned short* __restrict__ xh, const unsigned short* __restrict__ xl,
    const float* __restrict__ xx, float* __restrict__ S) {
  __shared__ __align__(16) unsigned short Ah[128][40], Al[128][40];
  __shared__ __align__(16) unsigned short Bh[128][40], Bl[128][40];
  int m0 = blockIdx.y * 128, n0 = blockIdx.x * 128;
  int tid = threadIdx.x;
  int w = tid >> 6, lane = tid & 63, quad = lane >> 4, l15 = lane & 15;
  int wm = (w >> 1) * 64, wn = (w & 1) * 64;
  floatx4 acc[4][4];
#pragma unroll
  for (int i = 0; i < 4; ++i)
#pragma unroll
    for (int j = 0; j < 4; ++j) acc[i][j] = (floatx4){0.f, 0.f, 0.f, 0.f};

  int sr = tid >> 1;
  int sq = (tid & 1) * 2;
  for (int kc = 0; kc < Cc; kc += 32) {
    __syncthreads();
    {
      const unsigned short* am = xh + (size_t)(m0 + sr) * Cc + kc + sq * 8;
      *(uint4*)&Ah[sr][sq * 8] = *(const uint4*)am;
      *(uint4*)&Ah[sr][sq * 8 + 8] = *(const uint4*)(am + 8);
      const unsigned short* al = xl + (size_t)(m0 + sr) * Cc + kc + sq * 8;
      *(uint4*)&Al[sr][sq * 8] = *(const uint4*)al;
      *(uint4*)&Al[sr][sq * 8 + 8] = *(const uint4*)(al + 8);
      const unsigned short* bm = xh + (size_t)(n0 + sr) * Cc + kc + sq * 8;
      *(uint4*)&Bh[sr][sq * 8] = *(const uint4*)bm;
      *(uint4*)&Bh[sr][sq * 8 + 8] = *(const uint4*)(bm + 8);
      const unsigned short* bl = xl + (size_t)(n0 + sr) * Cc + kc + sq * 8;
      *(uint4*)&Bl[sr][sq * 8] = *(const uint4*)bl;
      *(uint4*)&Bl[sr][sq * 8 + 8] = *(const uint4*)(bl + 8);
    }
    __syncthreads();
    int ka = quad * 8;
    short8 a_h[4], a_l[4], b_h[4], b_l[4];
#pragma unroll
    for (int f = 0; f < 4; ++f) {
      a_h[f] = *(const short8*)&Ah[wm + f * 16 + l15][ka];
      a_l[f] = *(const short8*)&Al[wm + f * 16 + l15][ka];
      b_h[f] = *(const short8*)&Bh[wn + f * 16 + l15][ka];
      b_l[f] = *(const short8*)&Bl[wn + f * 16 + l15][ka];
    }
#pragma unroll
    for (int fm = 0; fm < 4; ++fm)
#pragma unroll
      for (int fn = 0; fn < 4; ++fn) {
        acc[fm][fn] = __builtin_amdgcn_mfma_f32_16x16x32_bf16(a_h[fm], b_h[fn], acc[fm][fn], 0, 0, 0);
        acc[fm][fn] = __builtin_amdgcn_mfma_f32_16x16x32_bf16(a_h[fm], b_l[fn], acc[fm][fn], 0, 0, 0);
        acc[fm][fn] = __builtin_amdgcn_mfma_f32_16x16x32_bf16(a_l[fm], b_h[fn], acc[fm][fn], 0, 0, 0);
      }
  }
#pragma unroll
  for (int fn = 0; fn < 4; ++fn) {
    int n = n0 + wn + fn * 16 + l15;
    float xv = xx[n];
#pragma unroll
    for (int fm = 0; fm < 4; ++fm) {
      int m = m0 + wm + fm * 16 + quad * 4;
#pragma unroll
      for (int r = 0; r < 4; ++r)
        S[(size_t)(m + r) * Tt + n] = fmaf(2.f, acc[fm][fn][r], -xv);
    }
  }
}

// top-10 scan over one batch's S rows; wave per row, 8 rows per block (R5 verbatim)
__global__ __launch_bounds__(512) void topk_scan(
    const float* __restrict__ S, int* __restrict__ idx10) {
  int m = blockIdx.x * 8 + (threadIdx.x >> 6);
  int lane = threadIdx.x & 63;
  const float* row = S + (size_t)m * Tt;
  float s[NTOP]; int idl[NTOP];
#pragma unroll
  for (int j = 0; j < NTOP; ++j) { s[j] = -INFINITY; idl[j] = 0x7fffffff; }
  for (int c0 = lane * 4; c0 < Tt; c0 += 256) {
    float4 v = *(const float4*)(row + c0);
    float cand[4] = {v.x, v.y, v.z, v.w};
#pragma unroll
    for (int e = 0; e < 4; ++e) {
      float sc = cand[e];
      if (sc > s[NTOP - 1]) {
        s[NTOP - 1] = sc; idl[NTOP - 1] = c0 + e;
#pragma unroll
        for (int j = NTOP - 1; j > 0; --j) {
          if (s[j] > s[j - 1]) {
            float ts = s[j]; s[j] = s[j - 1]; s[j - 1] = ts;
            int ti = idl[j]; idl[j] = idl[j - 1]; idl[j - 1] = ti;
          }
        }
      }
    }
  }
  int ptr = 0;
  for (int r = 0; r < NTOP; ++r) {
    float cs = (ptr < NTOP) ? s[ptr] : -INFINITY;
    int cid = (ptr < NTOP) ? idl[ptr] : 0x7fffffff;
    float bs = cs; int bi = cid;
#pragma unroll
    for (int off = 1; off < 64; off <<= 1) {
      float os = __shfl_xor(bs, off);
      int oi = __shfl_xor(bi, off);
      if (os > bs || (os == bs && oi < bi)) { bs = os; bi = oi; }
    }
    if (cid == bi) ptr++;
    if (lane == 0) idx10[(size_t)m * NTOP + r] = bi;
  }
}

// fp64 rescore of the NTOP shortlist, emit exact top-7 (R5 verbatim)
__global__ __launch_bounds__(64) void knn_rescore(
    const float* __restrict__ xT, const int* __restrict__ idx10,
    int* __restrict__ idxout) {
  int t = blockIdx.x;
  int b = blockIdx.y;
  int lane = threadIdx.x;
  const float* xTb = xT + (size_t)b * Tt * Cc;
  const float* xm = xTb + (size_t)t * Cc;
  double sc = -1e300;
  int cid = 0x7fffffff;
  if (lane < NTOP) {
    int j = idx10[((size_t)b * Tt + t) * NTOP + lane];
    const float* xn = xTb + (size_t)j * Cc;
    double dot = 0.0, nn = 0.0;
    for (int c = 0; c < Cc; c += 4) {
      float4 a = *(const float4*)(xm + c);
      float4 v = *(const float4*)(xn + c);
      dot += (double)a.x * v.x + (double)a.y * v.y + (double)a.z * v.z + (double)a.w * v.w;
      nn  += (double)v.x * v.x + (double)v.y * v.y + (double)v.z * v.z + (double)v.w * v.w;
    }
    sc = 2.0 * dot - nn;
    cid = j;
  }
  for (int r = 0; r < Kk; ++r) {
    double bs = sc; int bi = cid;
#pragma unroll
    for (int off = 1; off < 64; off <<= 1) {
      double os = __shfl_xor(bs, off);
      int oi = __shfl_xor(bi, off);
      if (os > bs || (os == bs && oi < bi)) { bs = os; bi = oi; }
    }
    if (cid == bi) { sc = -1e300; cid = 0x7fffffff; }
    if (lane == 0) idxout[((size_t)b * Tt + t) * Kk + r] = bi;
  }
}

// Fused graph tail (R5 verbatim)
__global__ __launch_bounds__(256) void graph_tail(
    const float* __restrict__ ctr, const float* __restrict__ nbr,
    const int* __restrict__ idx, const float* __restrict__ W, // [C][8][5][5]
    const float* __restrict__ bias, const float* __restrict__ tout,
    const float* __restrict__ xin, float* __restrict__ xout) {
  __shared__ __align__(16) float gt[CG][Kk][132];
  __shared__ int jt[132][Kk];
  int t0 = blockIdx.x * 128;
  int g = blockIdx.y;
  int b = blockIdx.z;
  int tid = threadIdx.x;
  const float* ctrg = ctr + ((size_t)b * Cc + g * CG) * Tt;
  const float* nbrg = nbr + ((size_t)b * Cc + g * CG) * Tt;

  {
    const int* ib = idx + ((size_t)b * Tt + t0 - 2) * Kk;
    for (int e = tid; e < 132 * Kk; e += 256) {
      int tg = t0 - 2 + e / Kk;
      jt[e / Kk][e % Kk] = (tg >= 0 && tg < Tt) ? ib[e] : 0;
    }
  }
  __syncthreads();
  for (int e = tid; e < CG * Kk * 132; e += 256) {
    int ci = e / (Kk * 132), rem = e % (Kk * 132), k = rem / 132, tl = rem % 132;
    int tg = t0 - 2 + tl;
    float v = 0.f;
    if (tg >= 0 && tg < Tt) {
      int j = jt[tl][k];
      v = gelu_f(ctrg[(size_t)ci * Tt + tg] + nbrg[(size_t)ci * Tt + j]);
    }
    gt[ci][k][tl] = v;
  }
  __syncthreads();

  int ol = tid >> 5, tw = (tid & 31) * 4;
  int o = g * CG + ol;
  const float* wp = W + (size_t)o * CG * 25;
  float bv = bias[o];
  floatx2 acc[Kk][2];
#pragma unroll
  for (int k = 0; k < Kk; ++k) { acc[k][0] = (floatx2){bv, bv}; acc[k][1] = (floatx2){bv, bv}; }

  for (int ci = 0; ci < CG; ++ci) {
    float w[25];
#pragma unroll
    for (int i = 0; i < 25; ++i) w[i] = wp[ci * 25 + i];
#pragma unroll
    for (int kin = 0; kin < Kk; ++kin) {
      float4 ra = *(const float4*)&gt[ci][kin][tw];
      float4 rb = *(const float4*)&gt[ci][kin][tw + 4];
      float r8[8] = {ra.x, ra.y, ra.z, ra.w, rb.x, rb.y, rb.z, rb.w};
      floatx2 rlo[5], rhi[5];
#pragma unroll
      for (int dt = 0; dt < 5; ++dt) {
        rlo[dt] = (floatx2){r8[dt], r8[dt + 1]};
        rhi[dt] = (floatx2){r8[dt + 2], r8[dt + 3]};
      }
#pragma unroll
      for (int dk = 0; dk < 5; ++dk) {
        int k = kin + 2 - dk;
        if (k < 0 || k >= Kk) continue;
#pragma unroll
        for (int dt = 0; dt < 5; ++dt) {
          float wv = w[dt * 5 + dk];
          floatx2 wv2 = {wv, wv};
          acc[k][0] = __builtin_elementwise_fma(wv2, rlo[dt], acc[k][0]);
          acc[k][1] = __builtin_elementwise_fma(wv2, rhi[dt], acc[k][1]);
        }
      }
    }
  }
  floatx2 m0 = acc[0][0], m1 = acc[0][1];
#pragma unroll
  for (int k = 1; k < Kk; ++k) {
    m0 = __builtin_elementwise_max(m0, acc[k][0]);
    m1 = __builtin_elementwise_max(m1, acc[k][1]);
  }
  size_t off = ((size_t)b * Cc + o) * Tt + t0 + tw;
  float4 tv = *(const float4*)&tout[off];
  float4 xv = *(const float4*)&xin[off];
  float4 r;
  r.x = tv.x + m0.x + xv.x;
  r.y = tv.y + m0.y + xv.y;
  r.z = tv.z + m1.x + xv.z;
  r.w = tv.w + m1.y + xv.w;
  *(float4*)&xout[off] = r;
}

extern "C" void kernel_launch(void* const* d_in, const int* in_sizes, int n_in,
                              void* d_out, int out_size, void* d_ws, size_t ws_size,
                              hipStream_t stream) {
  const float* x0  = (const float*)d_in[0];
  const float* tw1 = (const float*)d_in[1];
  const float* tb1 = (const float*)d_in[2];
  const float* tw2 = (const float*)d_in[3];
  const float* tb2 = (const float*)d_in[4];
  const float* dw1 = (const float*)d_in[5];
  const float* db1 = (const float*)d_in[6];
  const float* dw2 = (const float*)d_in[7];
  const float* db2 = (const float*)d_in[8];
  float* out = (float*)d_out;

  float* ws = (float*)d_ws;
  const size_t NCT = (size_t)Bq * Cc * Tt;      // 2M elements
  float* x1   = ws;                             // layer-1 output   [B,C,T]
  float* hbuf = x1 + NCT;                       // h                [B,C,T]
  float* cbuf = hbuf + NCT;                     // ctr              [B,C,T]
  float* tbuf = cbuf + NCT;                     // tout             [B,C,T]
  float* xT   = tbuf + NCT;                     // xT, then nbr     [B,T,C]
  unsigned short* xh = (unsigned short*)(xT + NCT);   // [B,T,C] bf16 hi
  unsigned short* xl = xh + NCT;                      // bf16 lo
  unsigned short* wh = xl + NCT;                      // weights hi [768][256]
  unsigned short* wl = wh + (size_t)NO * Cc;
  float* S    = (float*)(wl + (size_t)NO * Cc); // per-batch scores [T,T] 16MB
  float* xx   = S + (size_t)Tt * Tt;            // squared norms    [B,T]
  int* idxb   = (int*)(xx + (size_t)Bq * Tt);   // top-7            [B,T,K]
  int* idx10  = idxb + (size_t)Bq * Tt * Kk;    // top-10           [B,T,NTOP]
  float* nbr  = xT;                             // nbr overwrites xT after rescore

  for (int i = 0; i < Ll; ++i) {
    const float* xin = (i == 0) ? x0 : x1;
    float* xout = (i == Ll - 1) ? out : x1;

    transpose_x<<<dim3(Tt/32, Cc/32, Bq), dim3(32, 8), 0, stream>>>(xin, xT);
    cvt_split<<<dim3(NCT/1024), 256, 0, stream>>>(xT, xh, xl);
    sqnorm<<<dim3(Tt/256, Bq), 256, 0, stream>>>(xin, xx);
    for (int b = 0; b < Bq; ++b) {
      score_gemm<<<dim3(16, 16), 256, 0, stream>>>(
          xh + (size_t)b * Tt * Cc, xl + (size_t)b * Tt * Cc,
          xx + (size_t)b * Tt, S);
      topk_scan<<<dim3(Tt/8), 512, 0, stream>>>(S, idx10 + (size_t)b * Tt * NTOP);
    }
    knn_rescore<<<dim3(Tt, Bq), 64, 0, stream>>>(xT, idx10, idxb);

    if (i == 0) {
      // Layer 1: exact fp32 pointwise convs — x1 feeds layer-2 KNN (discrete
      // top-k selection amplifies any x1 perturbation into neighbor flips).
      pw_conv16<<<dim3(Tt/256, Cc/16, Bq), 256, 0, stream>>>(
          xin, tw1 + (size_t)i * Cc * Cc, Cc, 0, tb1 + (size_t)i * Cc, hbuf, 1);
      pw_conv16<<<dim3(Tt/256, Cc/16, Bq), 256, 0, stream>>>(
          xin, dw1 + (size_t)i * Cc * 2 * Cc, 2 * Cc, Cc, db1 + (size_t)i * Cc, cbuf, 0);
      pw_conv16<<<dim3(Tt/256, Cc/16, Bq), 256, 0, stream>>>(
          xin, dw1 + (size_t)i * Cc * 2 * Cc, 2 * Cc, 0, nullptr, nbr, 0);
    } else {
      // Layer 2: split-bf16 MFMA GEMM — output feeds only the final result
      // (no downstream selection), ~1e-3 error vs 0.144 threshold.
      wsplit<<<dim3(NO), 256, 0, stream>>>(
          tw1 + (size_t)i * Cc * Cc, dw1 + (size_t)i * Cc * 2 * Cc, wh, wl);
      pw_gemm<<<dim3(64, NO/128), 256, 0, stream>>>(
          wh, wl, xh, xl, tb1 + (size_t)i * Cc, db1 + (size_t)i * Cc,
          hbuf, cbuf, nbr);
    }
    gconv1d<<<dim3(Tt/256, Cc, Bq), 256, 0, stream>>>(
        hbuf, tw2 + (size_t)i * Cc * CG * 5, tb2 + (size_t)i * Cc, tbuf);
    graph_tail<<<dim3(Tt/128, Cc/CG, Bq), 256, 0, stream>>>(
        cbuf, nbr, idxb, dw2 + (size_t)i * Cc * CG * 25, db2 + (size_t)i * Cc,
        tbuf, xin, xout);
  }
}

// Round 9
// 658.148 us; speedup vs baseline: 3.3189x; 1.3073x over previous
//
#include <hip/hip_runtime.h>
#include <math.h>

#define Bq 4
#define Cc 256
#define Tt 2048
#define Kk 7
#define NTOP 10
#define CG 8
#define Ll 2
#define NO 768   // fused pointwise outputs: 256 h | 256 ctr | 256 nbr

typedef __attribute__((ext_vector_type(8))) short short8;
typedef __attribute__((ext_vector_type(4))) float floatx4;
typedef __attribute__((ext_vector_type(2))) float floatx2;

__device__ __forceinline__ float gelu_f(float v) {
  return 0.5f * v * (1.0f + erff(v * 0.70710678118654752440f));
}

__device__ __forceinline__ unsigned short bf16_rne(float v) {
  unsigned int u = __float_as_uint(v);
  return (unsigned short)((u + 0x7fffu + ((u >> 16) & 1u)) >> 16);
}

// xT[b][t][c] = x[b][c][t]; also emits bf16 hi/lo split (validated by R6/R7 equality)
__global__ void transpose_x(const float* __restrict__ x, float* __restrict__ xT,
                            unsigned short* __restrict__ xh,
                            unsigned short* __restrict__ xl) {
  __shared__ float tile[32][33];
  int b = blockIdx.z;
  int t0 = blockIdx.x * 32, c0 = blockIdx.y * 32;
  int tx = threadIdx.x, ty = threadIdx.y;
  const float* xb = x + (size_t)b * Cc * Tt;
  for (int r = ty; r < 32; r += 8)
    tile[r][tx] = xb[(size_t)(c0 + r) * Tt + t0 + tx];
  __syncthreads();
  size_t base = (size_t)b * Tt * Cc;
  for (int r = ty; r < 32; r += 8) {
    float v = tile[tx][r];
    size_t o = base + (size_t)(t0 + r) * Cc + c0 + tx;
    xT[o] = v;
    unsigned short h = bf16_rne(v);
    float f = v - __uint_as_float((unsigned int)h << 16);
    xh[o] = h;
    xl[o] = bf16_rne(f);
  }
}

// squared norms from xT; wave per row t, 8 rows per block (validated by R6/R7 equality)
__global__ __launch_bounds__(512) void sqnorm_xt(
    const float* __restrict__ xT, float* __restrict__ xx) {
  int b = blockIdx.y;
  int t = blockIdx.x * 8 + (threadIdx.x >> 6);
  int lane = threadIdx.x & 63;
  const float* row = xT + ((size_t)b * Tt + t) * Cc;
  float4 v = *(const float4*)(row + lane * 4);
  float acc = v.x * v.x + v.y * v.y + v.z * v.z + v.w * v.w;
#pragma unroll
  for (int off = 1; off < 64; off <<= 1) acc += __shfl_xor(acc, off);
  if (lane == 0) xx[(size_t)b * Tt + t] = acc;
}

// fp32 pointwise conv (layer-1 exact path). 8 outputs/thread, c-unroll x4,
// 4 loads in flight. Accumulation order per output unchanged -> bit-identical.
__global__ __launch_bounds__(256) void pw_conv8(
    const float* __restrict__ x, const float* __restrict__ W, int wstride, int woff,
    const float* __restrict__ bias, float* __restrict__ y, int do_gelu) {
  int t = blockIdx.x * 256 + threadIdx.x;
  int o0 = blockIdx.y * 8;
  int b = blockIdx.z;
  const float* xp = x + (size_t)b * Cc * Tt + t;
  const float* wp = W + (size_t)o0 * wstride + woff;
  float acc[8];
#pragma unroll
  for (int j = 0; j < 8; ++j) acc[j] = bias ? bias[o0 + j] : 0.f;
  for (int c = 0; c < Cc; c += 4) {
    float xv0 = xp[(size_t)c * Tt];
    float xv1 = xp[(size_t)(c + 1) * Tt];
    float xv2 = xp[(size_t)(c + 2) * Tt];
    float xv3 = xp[(size_t)(c + 3) * Tt];
#pragma unroll
    for (int j = 0; j < 8; ++j) {
      const float* wr = wp + (size_t)j * wstride + c;
      float a = acc[j];
      a = fmaf(wr[0], xv0, a);
      a = fmaf(wr[1], xv1, a);
      a = fmaf(wr[2], xv2, a);
      a = fmaf(wr[3], xv3, a);
      acc[j] = a;
    }
  }
#pragma unroll
  for (int j = 0; j < 8; ++j) {
    float v = acc[j];
    if (do_gelu) v = gelu_f(v);
    y[((size_t)b * Cc + o0 + j) * Tt + t] = v;
  }
}

// concat weights [768][256] -> bf16 hi/lo (layer-2 only)
__global__ __launch_bounds__(256) void wsplit(
    const float* __restrict__ tw1, const float* __restrict__ dw1,
    unsigned short* __restrict__ wh, unsigned short* __restrict__ wl) {
  int o = blockIdx.x;
  int c = threadIdx.x;
  float v;
  if (o < 256) v = tw1[(size_t)o * Cc + c];
  else if (o < 512) v = dw1[(size_t)(o - 256) * (2 * Cc) + Cc + c];
  else v = dw1[(size_t)(o - 512) * (2 * Cc) + c];
  unsigned short h = bf16_rne(v);
  float f = v - __uint_as_float((unsigned int)h << 16);
  wh[(size_t)o * Cc + c] = h;
  wl[(size_t)o * Cc + c] = bf16_rne(f);
}

// fused pointwise GEMM (layer-2 only): y[o][t] = act(bias + sum_c W[o][c]*x[t][c])
__global__ __launch_bounds__(256) void pw_gemm(
    const unsigned short* __restrict__ wh, const unsigned short* __restrict__ wl,
    const unsigned short* __restrict__ xh, const unsigned short* __restrict__ xl,
    const float* __restrict__ tb1, const float* __restrict__ db1,
    float* __restrict__ hb, float* __restrict__ cb, float* __restrict__ nb) {
  __shared__ __align__(16) unsigned short Ah[128][40], Al[128][40];
  __shared__ __align__(16) unsigned short Bh[128][40], Bl[128][40];
  int mt = blockIdx.x;                  // token tile: b = mt/16, t0 = (mt%16)*128
  int b = mt >> 4;
  int t0 = (mt & 15) * 128;
  int o0 = blockIdx.y * 128;            // output tile
  int tid = threadIdx.x;
  int w = tid >> 6, lane = tid & 63, quad = lane >> 4, l15 = lane & 15;
  int wm = (w >> 1) * 64, wn = (w & 1) * 64;
  floatx4 acc[4][4];
#pragma unroll
  for (int i = 0; i < 4; ++i)
#pragma unroll
    for (int j = 0; j < 4; ++j) acc[i][j] = (floatx4){0.f, 0.f, 0.f, 0.f};

  const unsigned short* xhb = xh + ((size_t)b * Tt + t0) * Cc;
  const unsigned short* xlb = xl + ((size_t)b * Tt + t0) * Cc;
  int sr = tid >> 1;
  int sq = (tid & 1) * 2;
  for (int kc = 0; kc < Cc; kc += 32) {
    __syncthreads();
    {
      const unsigned short* am = wh + (size_t)(o0 + sr) * Cc + kc + sq * 8;
      *(uint4*)&Ah[sr][sq * 8] = *(const uint4*)am;
      *(uint4*)&Ah[sr][sq * 8 + 8] = *(const uint4*)(am + 8);
      const unsigned short* al = wl + (size_t)(o0 + sr) * Cc + kc + sq * 8;
      *(uint4*)&Al[sr][sq * 8] = *(const uint4*)al;
      *(uint4*)&Al[sr][sq * 8 + 8] = *(const uint4*)(al + 8);
      const unsigned short* bm = xhb + (size_t)sr * Cc + kc + sq * 8;
      *(uint4*)&Bh[sr][sq * 8] = *(const uint4*)bm;
      *(uint4*)&Bh[sr][sq * 8 + 8] = *(const uint4*)(bm + 8);
      const unsigned short* bl = xlb + (size_t)sr * Cc + kc + sq * 8;
      *(uint4*)&Bl[sr][sq * 8] = *(const uint4*)bl;
      *(uint4*)&Bl[sr][sq * 8 + 8] = *(const uint4*)(bl + 8);
    }
    __syncthreads();
    int ka = quad * 8;
    short8 a_h[4], a_l[4], b_h[4], b_l[4];
#pragma unroll
    for (int f = 0; f < 4; ++f) {
      a_h[f] = *(const short8*)&Ah[wm + f * 16 + l15][ka];
      a_l[f] = *(const short8*)&Al[wm + f * 16 + l15][ka];
      b_h[f] = *(const short8*)&Bh[wn + f * 16 + l15][ka];
      b_l[f] = *(const short8*)&Bl[wn + f * 16 + l15][ka];
    }
#pragma unroll
    for (int fm = 0; fm < 4; ++fm)
#pragma unroll
      for (int fn = 0; fn < 4; ++fn) {
        acc[fm][fn] = __builtin_amdgcn_mfma_f32_16x16x32_bf16(a_h[fm], b_h[fn], acc[fm][fn], 0, 0, 0);
        acc[fm][fn] = __builtin_amdgcn_mfma_f32_16x16x32_bf16(a_h[fm], b_l[fn], acc[fm][fn], 0, 0, 0);
        acc[fm][fn] = __builtin_amdgcn_mfma_f32_16x16x32_bf16(a_l[fm], b_h[fn], acc[fm][fn], 0, 0, 0);
      }
  }
  int range = o0 >> 8;                 // 0: h(gelu,tb1)  1: ctr(db1)  2: nbr
  float* dst = (range == 0) ? hb : (range == 1) ? cb : nb;
  const float* bias = (range == 0) ? tb1 : (range == 1) ? db1 : nullptr;
  int ol0 = o0 & 255;
#pragma unroll
  for (int fm = 0; fm < 4; ++fm) {
    int o = ol0 + wm + fm * 16 + quad * 4;
#pragma unroll
    for (int r = 0; r < 4; ++r) {
      float bv = bias ? bias[o + r] : 0.f;
      size_t rowoff = ((size_t)b * Cc + o + r) * Tt + t0;
#pragma unroll
      for (int fn = 0; fn < 4; ++fn) {
        int t = wn + fn * 16 + l15;
        float v = acc[fm][fn][r] + bv;
        if (range == 0) v = gelu_f(v);
        dst[rowoff + t] = v;
      }
    }
  }
}

// grouped conv1d k=5 pad=2   (R5 verbatim)
__global__ __launch_bounds__(256) void gconv1d(
    const float* __restrict__ h, const float* __restrict__ W, // [C][8][5]
    const float* __restrict__ bias, float* __restrict__ tout) {
  int t = blockIdx.x * 256 + threadIdx.x;
  int o = blockIdx.y, b = blockIdx.z;
  int g = o >> 3;
  const float* hp = h + ((size_t)b * Cc + g * CG) * Tt;
  const float* wp = W + (size_t)o * CG * 5;
  float acc = bias[o];
#pragma unroll
  for (int ci = 0; ci < CG; ++ci) {
#pragma unroll
    for (int dt = 0; dt < 5; ++dt) {
      int tt = t + dt - 2;
      if (tt >= 0 && tt < Tt)
        acc = fmaf(wp[ci * 5 + dt], hp[(size_t)ci * Tt + tt], acc);
    }
  }
  tout[((size_t)b * Cc + o) * Tt + t] = acc;
}

// score GEMM, 2 batches per dispatch via z (validated by R6/R7 equality)
__global__ __launch_bounds__(256) void score_gemm(
    const unsigned short* __restrict__ xh, const unsigned short* __restrict__ xl,
    const float* __restrict__ xx, float* __restrict__ S, int bbase) {
  __shared__ __align__(16) unsigned short Ah[128][40], Al[128][40];
  __shared__ __align__(16) unsigned short Bh[128][40], Bl[128][40];
  int lb = blockIdx.z;
  int b = bbase + lb;
  int m0 = blockIdx.y * 128, n0 = blockIdx.x * 128;
  int tid = threadIdx.x;
  int w = tid >> 6, lane = tid & 63, quad = lane >> 4, l15 = lane & 15;
  int wm = (w >> 1) * 64, wn = (w & 1) * 64;
  const unsigned short* xhb = xh + (size_t)b * Tt * Cc;
  const unsigned short* xlb = xl + (size_t)b * Tt * Cc;
  const float* xxb = xx + (size_t)b * Tt;
  float* Sb = S + (size_t)lb * Tt * Tt;
  floatx4 acc[4][4];
#pragma unroll
  for (int i = 0; i < 4; ++i)
#pragma unroll
    for (int j = 0; j < 4; ++j) acc[i][j] = (floatx4){0.f, 0.f, 0.f, 0.f};

  int sr = tid >> 1;
  int sq = (tid & 1) * 2;
  for (int kc = 0; kc < Cc; kc += 32) {
    __syncthreads();
    {
      const unsigned short* am = xhb + (size_t)(m0 + sr) * Cc + kc + sq * 8;
      *(uint4*)&Ah[sr][sq * 8] = *(const uint4*)am;
      *(uint4*)&Ah[sr][sq * 8 + 8] = *(const uint4*)(am + 8);
      const unsigned short* al = xlb + (size_t)(m0 + sr) * Cc + kc + sq * 8;
      *(uint4*)&Al[sr][sq * 8] = *(const uint4*)al;
      *(uint4*)&Al[sr][sq * 8 + 8] = *(const uint4*)(al + 8);
      const unsigned short* bm = xhb + (size_t)(n0 + sr) * Cc + kc + sq * 8;
      *(uint4*)&Bh[sr][sq * 8] = *(const uint4*)bm;
      *(uint4*)&Bh[sr][sq * 8 + 8] = *(const uint4*)(bm + 8);
      const unsigned short* bl = xlb + (size_t)(n0 + sr) * Cc + kc + sq * 8;
      *(uint4*)&Bl[sr][sq * 8] = *(const uint4*)bl;
      *(uint4*)&Bl[sr][sq * 8 + 8] = *(const uint4*)(bl + 8);
    }
    __syncthreads();
    int ka = quad * 8;
    short8 a_h[4], a_l[4], b_h[4], b_l[4];
#pragma unroll
    for (int f = 0; f < 4; ++f) {
      a_h[f] = *(const short8*)&Ah[wm + f * 16 + l15][ka];
      a_l[f] = *(const short8*)&Al[wm + f * 16 + l15][ka];
      b_h[f] = *(const short8*)&Bh[wn + f * 16 + l15][ka];
      b_l[f] = *(const short8*)&Bl[wn + f * 16 + l15][ka];
    }
#pragma unroll
    for (int fm = 0; fm < 4; ++fm)
#pragma unroll
      for (int fn = 0; fn < 4; ++fn) {
        acc[fm][fn] = __builtin_amdgcn_mfma_f32_16x16x32_bf16(a_h[fm], b_h[fn], acc[fm][fn], 0, 0, 0);
        acc[fm][fn] = __builtin_amdgcn_mfma_f32_16x16x32_bf16(a_h[fm], b_l[fn], acc[fm][fn], 0, 0, 0);
        acc[fm][fn] = __builtin_amdgcn_mfma_f32_16x16x32_bf16(a_l[fm], b_h[fn], acc[fm][fn], 0, 0, 0);
      }
  }
#pragma unroll
  for (int fn = 0; fn < 4; ++fn) {
    int n = n0 + wn + fn * 16 + l15;
    float xv = xxb[n];
#pragma unroll
    for (int fm = 0; fm < 4; ++fm) {
      int m = m0 + wm + fm * 16 + quad * 4;
#pragma unroll
      for (int r = 0; r < 4; ++r)
        Sb[(size_t)(m + r) * Tt + n] = fmaf(2.f, acc[fm][fn][r], -xv);
    }
  }
}

// top-10 scan, 2 batches via z; wave per row, 8 rows per block
__global__ __launch_bounds__(512) void topk_scan(
    const float* __restrict__ S, int* __restrict__ idx10, int bbase) {
  int lb = blockIdx.z;
  int m = blockIdx.x * 8 + (threadIdx.x >> 6);
  int lane = threadIdx.x & 63;
  const float* row = S + ((size_t)lb * Tt + m) * Tt;
  float s[NTOP]; int idl[NTOP];
#pragma unroll
  for (int j = 0; j < NTOP; ++j) { s[j] = -INFINITY; idl[j] = 0x7fffffff; }
  for (int c0 = lane * 4; c0 < Tt; c0 += 256) {
    float4 v = *(const float4*)(row + c0);
    float cand[4] = {v.x, v.y, v.z, v.w};
#pragma unroll
    for (int e = 0; e < 4; ++e) {
      float sc = cand[e];
      if (sc > s[NTOP - 1]) {
        s[NTOP - 1] = sc; idl[NTOP - 1] = c0 + e;
#pragma unroll
        for (int j = NTOP - 1; j > 0; --j) {
          if (s[j] > s[j - 1]) {
            float ts = s[j]; s[j] = s[j - 1]; s[j - 1] = ts;
            int ti = idl[j]; idl[j] = idl[j - 1]; idl[j - 1] = ti;
          }
        }
      }
    }
  }
  int ptr = 0;
  for (int r = 0; r < NTOP; ++r) {
    float cs = (ptr < NTOP) ? s[ptr] : -INFINITY;
    int cid = (ptr < NTOP) ? idl[ptr] : 0x7fffffff;
    float bs = cs; int bi = cid;
#pragma unroll
    for (int off = 1; off < 64; off <<= 1) {
      float os = __shfl_xor(bs, off);
      int oi = __shfl_xor(bi, off);
      if (os > bs || (os == bs && oi < bi)) { bs = os; bi = oi; }
    }
    if (cid == bi) ptr++;
    if (lane == 0) idx10[((size_t)(bbase + lb) * Tt + m) * NTOP + r] = bi;
  }
}

// fp64 rescore of the NTOP shortlist, emit exact top-7 (R5 verbatim)
__global__ __launch_bounds__(64) void knn_rescore(
    const float* __restrict__ xT, const int* __restrict__ idx10,
    int* __restrict__ idxout) {
  int t = blockIdx.x;
  int b = blockIdx.y;
  int lane = threadIdx.x;
  const float* xTb = xT + (size_t)b * Tt * Cc;
  const float* xm = xTb + (size_t)t * Cc;
  double sc = -1e300;
  int cid = 0x7fffffff;
  if (lane < NTOP) {
    int j = idx10[((size_t)b * Tt + t) * NTOP + lane];
    const float* xn = xTb + (size_t)j * Cc;
    double dot = 0.0, nn = 0.0;
    for (int c = 0; c < Cc; c += 4) {
      float4 a = *(const float4*)(xm + c);
      float4 v = *(const float4*)(xn + c);
      dot += (double)a.x * v.x + (double)a.y * v.y + (double)a.z * v.z + (double)a.w * v.w;
      nn  += (double)v.x * v.x + (double)v.y * v.y + (double)v.z * v.z + (double)v.w * v.w;
    }
    sc = 2.0 * dot - nn;
    cid = j;
  }
  for (int r = 0; r < Kk; ++r) {
    double bs = sc; int bi = cid;
#pragma unroll
    for (int off = 1; off < 64; off <<= 1) {
      double os = __shfl_xor(bs, off);
      int oi = __shfl_xor(bi, off);
      if (os > bs || (os == bs && oi < bi)) { bs = os; bi = oi; }
    }
    if (cid == bi) { sc = -1e300; cid = 0x7fffffff; }
    if (lane == 0) idxout[((size_t)b * Tt + t) * Kk + r] = bi;
  }
}

// Fused graph tail, 64-token tile (same arithmetic as R5's 128-tile; 17.2 KB LDS
// -> ~8 blocks/CU for gather-latency hiding). Thread = (o, 2 tokens).
__global__ __launch_bounds__(256) void graph_tail(
    const float* __restrict__ ctr, const float* __restrict__ nbr,
    const int* __restrict__ idx, const float* __restrict__ W, // [C][8][5][5]
    const float* __restrict__ bias, const float* __restrict__ tout,
    const float* __restrict__ xin, float* __restrict__ xout) {
  __shared__ __align__(16) float gt[CG][Kk][68];   // [ci][k][t0-2+tl], 14.9 KB
  __shared__ int jt[68][Kk];                       // 1.9 KB
  int t0 = blockIdx.x * 64;
  int g = blockIdx.y;
  int b = blockIdx.z;
  int tid = threadIdx.x;
  const float* ctrg = ctr + ((size_t)b * Cc + g * CG) * Tt;
  const float* nbrg = nbr + ((size_t)b * Cc + g * CG) * Tt;

  {
    const int* ib = idx + ((size_t)b * Tt + t0 - 2) * Kk;
    for (int e = tid; e < 68 * Kk; e += 256) {
      int tg = t0 - 2 + e / Kk;
      jt[e / Kk][e % Kk] = (tg >= 0 && tg < Tt) ? ib[e] : 0;
    }
  }
  __syncthreads();
  for (int e = tid; e < CG * Kk * 68; e += 256) {
    int ci = e / (Kk * 68), rem = e % (Kk * 68), k = rem / 68, tl = rem % 68;
    int tg = t0 - 2 + tl;
    float v = 0.f;
    if (tg >= 0 && tg < Tt) {
      int j = jt[tl][k];
      v = gelu_f(ctrg[(size_t)ci * Tt + tg] + nbrg[(size_t)ci * Tt + j]);
    }
    gt[ci][k][tl] = v;
  }
  __syncthreads();

  // conv phase: thread = (o_local = tid>>5, 2 tokens at tl2=(tid&31)*2)
  int ol = tid >> 5, tl2 = (tid & 31) * 2;
  int o = g * CG + ol;
  const float* wp = W + (size_t)o * CG * 25;
  float bv = bias[o];
  floatx2 acc[Kk];
#pragma unroll
  for (int k = 0; k < Kk; ++k) acc[k] = (floatx2){bv, bv};

  for (int ci = 0; ci < CG; ++ci) {
    float w[25];
#pragma unroll
    for (int i = 0; i < 25; ++i) w[i] = wp[ci * 25 + i];
#pragma unroll
    for (int kin = 0; kin < Kk; ++kin) {
      floatx2 p0 = *(const floatx2*)&gt[ci][kin][tl2];
      floatx2 p1 = *(const floatx2*)&gt[ci][kin][tl2 + 2];
      floatx2 p2 = *(const floatx2*)&gt[ci][kin][tl2 + 4];
      float r6[6] = {p0.x, p0.y, p1.x, p1.y, p2.x, p2.y};
      floatx2 rp[5];
#pragma unroll
      for (int dt = 0; dt < 5; ++dt) rp[dt] = (floatx2){r6[dt], r6[dt + 1]};
#pragma unroll
      for (int dk = 0; dk < 5; ++dk) {
        int k = kin + 2 - dk;            // output k with input kin = k+dk-2
        if (k < 0 || k >= Kk) continue;  // compile-time pruned
#pragma unroll
        for (int dt = 0; dt < 5; ++dt) {
          float wv = w[dt * 5 + dk];
          floatx2 wv2 = {wv, wv};
          acc[k] = __builtin_elementwise_fma(wv2, rp[dt], acc[k]);
        }
      }
    }
  }
  floatx2 m = acc[0];
#pragma unroll
  for (int k = 1; k < Kk; ++k) m = __builtin_elementwise_max(m, acc[k]);
  size_t off = ((size_t)b * Cc + o) * Tt + t0 + tl2;
  floatx2 tv = *(const floatx2*)&tout[off];
  floatx2 xv = *(const floatx2*)&xin[off];
  floatx2 r;
  r.x = tv.x + m.x + xv.x;
  r.y = tv.y + m.y + xv.y;
  *(floatx2*)&xout[off] = r;
}

extern "C" void kernel_launch(void* const* d_in, const int* in_sizes, int n_in,
                              void* d_out, int out_size, void* d_ws, size_t ws_size,
                              hipStream_t stream) {
  const float* x0  = (const float*)d_in[0];
  const float* tw1 = (const float*)d_in[1];
  const float* tb1 = (const float*)d_in[2];
  const float* tw2 = (const float*)d_in[3];
  const float* tb2 = (const float*)d_in[4];
  const float* dw1 = (const float*)d_in[5];
  const float* db1 = (const float*)d_in[6];
  const float* dw2 = (const float*)d_in[7];
  const float* db2 = (const float*)d_in[8];
  float* out = (float*)d_out;

  float* ws = (float*)d_ws;
  const size_t NCT = (size_t)Bq * Cc * Tt;      // 2M elements
  float* x1   = ws;                             // layer-1 output   [B,C,T]
  float* hbuf = x1 + NCT;                       // h                [B,C,T]
  float* cbuf = hbuf + NCT;                     // ctr              [B,C,T]
  float* tbuf = cbuf + NCT;                     // tout             [B,C,T]
  float* xT   = tbuf + NCT;                     // xT, then nbr     [B,T,C]
  unsigned short* xh = (unsigned short*)(xT + NCT);   // [B,T,C] bf16 hi
  unsigned short* xl = xh + NCT;                      // bf16 lo
  unsigned short* wh = xl + NCT;                      // weights hi [768][256]
  unsigned short* wl = wh + (size_t)NO * Cc;
  float* S    = (float*)(wl + (size_t)NO * Cc); // scores, 2 batches [2,T,T] 32MB
  float* xx   = S + 2 * (size_t)Tt * Tt;        // squared norms    [B,T]
  int* idxb   = (int*)(xx + (size_t)Bq * Tt);   // top-7            [B,T,K]
  int* idx10  = idxb + (size_t)Bq * Tt * Kk;    // top-10           [B,T,NTOP]
  float* nbr  = xT;                             // nbr overwrites xT after rescore

  for (int i = 0; i < Ll; ++i) {
    const float* xin = (i == 0) ? x0 : x1;
    float* xout = (i == Ll - 1) ? out : x1;

    transpose_x<<<dim3(Tt/32, Cc/32, Bq), dim3(32, 8), 0, stream>>>(xin, xT, xh, xl);
    sqnorm_xt<<<dim3(Tt/8, Bq), 512, 0, stream>>>(xT, xx);
    for (int bp = 0; bp < Bq; bp += 2) {
      score_gemm<<<dim3(16, 16, 2), 256, 0, stream>>>(xh, xl, xx, S, bp);
      topk_scan<<<dim3(Tt/8, 1, 2), 512, 0, stream>>>(S, idx10, bp);
    }
    knn_rescore<<<dim3(Tt, Bq), 64, 0, stream>>>(xT, idx10, idxb);

    if (i == 0) {
      // Layer 1: exact fp32 pointwise convs — x1 feeds layer-2 KNN (discrete
      // top-k amplifies perturbation into neighbor flips; proven R6/R7).
      pw_conv8<<<dim3(Tt/256, Cc/8, Bq), 256, 0, stream>>>(
          xin, tw1 + (size_t)i * Cc * Cc, Cc, 0, tb1 + (size_t)i * Cc, hbuf, 1);
      pw_conv8<<<dim3(Tt/256, Cc/8, Bq), 256, 0, stream>>>(
          xin, dw1 + (size_t)i * Cc * 2 * Cc, 2 * Cc, Cc, db1 + (size_t)i * Cc, cbuf, 0);
      pw_conv8<<<dim3(Tt/256, Cc/8, Bq), 256, 0, stream>>>(
          xin, dw1 + (size_t)i * Cc * 2 * Cc, 2 * Cc, 0, nullptr, nbr, 0);
    } else {
      // Layer 2: split-bf16 MFMA GEMM — output feeds only the final result.
      wsplit<<<dim3(NO), 256, 0, stream>>>(
          tw1 + (size_t)i * Cc * Cc, dw1 + (size_t)i * Cc * 2 * Cc, wh, wl);
      pw_gemm<<<dim3(64, NO/128), 256, 0, stream>>>(
          wh, wl, xh, xl, tb1 + (size_t)i * Cc, db1 + (size_t)i * Cc,
          hbuf, cbuf, nbr);
    }
    gconv1d<<<dim3(Tt/256, Cc, Bq), 256, 0, stream>>>(
        hbuf, tw2 + (size_t)i * Cc * CG * 5, tb2 + (size_t)i * Cc, tbuf);
    graph_tail<<<dim3(Tt/64, Cc/CG, Bq), 256, 0, stream>>>(
        cbuf, nbr, idxb, dw2 + (size_t)i * Cc * CG * 25, db2 + (size_t)i * Cc,
        tbuf, xin, xout);
  }
}

// Round 11
// 595.205 us; speedup vs baseline: 3.6699x; 1.1058x over previous
//
#include <hip/hip_runtime.h>
#include <math.h>

#define Bq 4
#define Cc 256
#define Tt 2048
#define Kk 7
#define NTOP 10
#define CG 8
#define Ll 2
#define NO 768   // fused pointwise outputs: 256 h | 256 ctr | 256 nbr

typedef __attribute__((ext_vector_type(8))) short short8;
typedef __attribute__((ext_vector_type(4))) float floatx4;
typedef __attribute__((ext_vector_type(2))) float floatx2;

__device__ __forceinline__ float gelu_f(float v) {
  return 0.5f * v * (1.0f + erff(v * 0.70710678118654752440f));
}

// A&S 7.1.26 rational erf (~5e-7 abs err in fp32). SAFE ONLY on paths that do
// not feed a later top-k: R10 proved a ~1e-6 x1 perturbation flips layer-2 KNN.
__device__ __forceinline__ float erf_fast(float x) {
  float ax = fabsf(x);
  float t = __builtin_amdgcn_rcpf(fmaf(0.3275911f, ax, 1.0f));
  float y = t * (0.254829592f + t * (-0.284496736f + t * (1.421413741f +
            t * (-1.453152027f + t * 1.061405429f))));
  float r = 1.0f - y * __expf(-ax * ax);
  return copysignf(r, x);
}
__device__ __forceinline__ float gelu_fast(float v) {
  return 0.5f * v * (1.0f + erf_fast(v * 0.70710678118654752440f));
}

// xT[b][t][c] = x[b][c][t]; also emits bf16 hi/lo split
__global__ void transpose_x(const float* __restrict__ x, float* __restrict__ xT,
                            unsigned short* __restrict__ xh,
                            unsigned short* __restrict__ xl) {
  __shared__ float tile[32][33];
  int b = blockIdx.z;
  int t0 = blockIdx.x * 32, c0 = blockIdx.y * 32;
  int tx = threadIdx.x, ty = threadIdx.y;
  const float* xb = x + (size_t)b * Cc * Tt;
  for (int r = ty; r < 32; r += 8)
    tile[r][tx] = xb[(size_t)(c0 + r) * Tt + t0 + tx];
  __syncthreads();
  size_t base = (size_t)b * Tt * Cc;
  for (int r = ty; r < 32; r += 8) {
    float v = tile[tx][r];
    size_t o = base + (size_t)(t0 + r) * Cc + c0 + tx;
    xT[o] = v;
    unsigned int u = __float_as_uint(v);
    unsigned short h = (unsigned short)((u + 0x7fffu + ((u >> 16) & 1u)) >> 16);
    float f = v - __uint_as_float((unsigned int)h << 16);
    unsigned int ul = __float_as_uint(f);
    xh[o] = h;
    xl[o] = (unsigned short)((ul + 0x7fffu + ((ul >> 16) & 1u)) >> 16);
  }
}

// squared norms from xT; wave per row t, 8 rows per block
__global__ __launch_bounds__(512) void sqnorm_xt(
    const float* __restrict__ xT, float* __restrict__ xx) {
  int b = blockIdx.y;
  int t = blockIdx.x * 8 + (threadIdx.x >> 6);
  int lane = threadIdx.x & 63;
  const float* row = xT + ((size_t)b * Tt + t) * Cc;
  float4 v = *(const float4*)(row + lane * 4);
  float acc = v.x * v.x + v.y * v.y + v.z * v.z + v.w * v.w;
#pragma unroll
  for (int off = 1; off < 64; off <<= 1) acc += __shfl_xor(acc, off);
  if (lane == 0) xx[(size_t)b * Tt + t] = acc;
}

// fp32 pointwise convs, all 3 ranges in one launch (layer-1 exact path).
__global__ __launch_bounds__(256) void pw_conv8_all(
    const float* __restrict__ x, const float* __restrict__ tw1,
    const float* __restrict__ tb1, const float* __restrict__ dw1,
    const float* __restrict__ db1, float* __restrict__ hb,
    float* __restrict__ cb, float* __restrict__ nb) {
  int t = blockIdx.x * 256 + threadIdx.x;
  int oy = blockIdx.y;
  int b = blockIdx.z;
  int range = oy >> 5;            // 0: h  1: ctr  2: nbr
  int o0 = (oy & 31) * 8;
  const float* W; int wstride, woff; const float* bias; float* dst; int dg;
  if (range == 0)      { W = tw1; wstride = Cc;     woff = 0;  bias = tb1;     dst = hb; dg = 1; }
  else if (range == 1) { W = dw1; wstride = 2 * Cc; woff = Cc; bias = db1;     dst = cb; dg = 0; }
  else                 { W = dw1; wstride = 2 * Cc; woff = 0;  bias = nullptr; dst = nb; dg = 0; }
  const float* xp = x + (size_t)b * Cc * Tt + t;
  const float* wp = W + (size_t)o0 * wstride + woff;
  float acc[8];
#pragma unroll
  for (int j = 0; j < 8; ++j) acc[j] = bias ? bias[o0 + j] : 0.f;
  for (int c = 0; c < Cc; c += 4) {
    float xv0 = xp[(size_t)c * Tt];
    float xv1 = xp[(size_t)(c + 1) * Tt];
    float xv2 = xp[(size_t)(c + 2) * Tt];
    float xv3 = xp[(size_t)(c + 3) * Tt];
#pragma unroll
    for (int j = 0; j < 8; ++j) {
      const float* wr = wp + (size_t)j * wstride + c;
      float a = acc[j];
      a = fmaf(wr[0], xv0, a);
      a = fmaf(wr[1], xv1, a);
      a = fmaf(wr[2], xv2, a);
      a = fmaf(wr[3], xv3, a);
      acc[j] = a;
    }
  }
#pragma unroll
  for (int j = 0; j < 8; ++j) {
    float v = acc[j];
    if (dg) v = gelu_f(v);
    dst[((size_t)b * Cc + o0 + j) * Tt + t] = v;
  }
}

// concat weights [768][256] -> bf16 hi/lo (layer-2 only)
__global__ __launch_bounds__(256) void wsplit(
    const float* __restrict__ tw1, const float* __restrict__ dw1,
    unsigned short* __restrict__ wh, unsigned short* __restrict__ wl) {
  int o = blockIdx.x;
  int c = threadIdx.x;
  float v;
  if (o < 256) v = tw1[(size_t)o * Cc + c];
  else if (o < 512) v = dw1[(size_t)(o - 256) * (2 * Cc) + Cc + c];
  else v = dw1[(size_t)(o - 512) * (2 * Cc) + c];
  unsigned int u = __float_as_uint(v);
  unsigned short h = (unsigned short)((u + 0x7fffu + ((u >> 16) & 1u)) >> 16);
  float f = v - __uint_as_float((unsigned int)h << 16);
  unsigned int ul = __float_as_uint(f);
  wh[(size_t)o * Cc + c] = h;
  wl[(size_t)o * Cc + c] = (unsigned short)((ul + 0x7fffu + ((ul >> 16) & 1u)) >> 16);
}

// fused pointwise GEMM (layer-2 only)
__global__ __launch_bounds__(256) void pw_gemm(
    const unsigned short* __restrict__ wh, const unsigned short* __restrict__ wl,
    const unsigned short* __restrict__ xh, const unsigned short* __restrict__ xl,
    const float* __restrict__ tb1, const float* __restrict__ db1,
    float* __restrict__ hb, float* __restrict__ cb, float* __restrict__ nb) {
  __shared__ __align__(16) unsigned short Ah[128][40], Al[128][40];
  __shared__ __align__(16) unsigned short Bh[128][40], Bl[128][40];
  int mt = blockIdx.x;
  int b = mt >> 4;
  int t0 = (mt & 15) * 128;
  int o0 = blockIdx.y * 128;
  int tid = threadIdx.x;
  int w = tid >> 6, lane = tid & 63, quad = lane >> 4, l15 = lane & 15;
  int wm = (w >> 1) * 64, wn = (w & 1) * 64;
  floatx4 acc[4][4];
#pragma unroll
  for (int i = 0; i < 4; ++i)
#pragma unroll
    for (int j = 0; j < 4; ++j) acc[i][j] = (floatx4){0.f, 0.f, 0.f, 0.f};

  const unsigned short* xhb = xh + ((size_t)b * Tt + t0) * Cc;
  const unsigned short* xlb = xl + ((size_t)b * Tt + t0) * Cc;
  int sr = tid >> 1;
  int sq = (tid & 1) * 2;
  for (int kc = 0; kc < Cc; kc += 32) {
    __syncthreads();
    {
      const unsigned short* am = wh + (size_t)(o0 + sr) * Cc + kc + sq * 8;
      *(uint4*)&Ah[sr][sq * 8] = *(const uint4*)am;
      *(uint4*)&Ah[sr][sq * 8 + 8] = *(const uint4*)(am + 8);
      const unsigned short* al = wl + (size_t)(o0 + sr) * Cc + kc + sq * 8;
      *(uint4*)&Al[sr][sq * 8] = *(const uint4*)al;
      *(uint4*)&Al[sr][sq * 8 + 8] = *(const uint4*)(al + 8);
      const unsigned short* bm = xhb + (size_t)sr * Cc + kc + sq * 8;
      *(uint4*)&Bh[sr][sq * 8] = *(const uint4*)bm;
      *(uint4*)&Bh[sr][sq * 8 + 8] = *(const uint4*)(bm + 8);
      const unsigned short* bl = xlb + (size_t)sr * Cc + kc + sq * 8;
      *(uint4*)&Bl[sr][sq * 8] = *(const uint4*)bl;
      *(uint4*)&Bl[sr][sq * 8 + 8] = *(const uint4*)(bl + 8);
    }
    __syncthreads();
    int ka = quad * 8;
    short8 a_h[4], a_l[4], b_h[4], b_l[4];
#pragma unroll
    for (int f = 0; f < 4; ++f) {
      a_h[f] = *(const short8*)&Ah[wm + f * 16 + l15][ka];
      a_l[f] = *(const short8*)&Al[wm + f * 16 + l15][ka];
      b_h[f] = *(const short8*)&Bh[wn + f * 16 + l15][ka];
      b_l[f] = *(const short8*)&Bl[wn + f * 16 + l15][ka];
    }
#pragma unroll
    for (int fm = 0; fm < 4; ++fm)
#pragma unroll
      for (int fn = 0; fn < 4; ++fn) {
        acc[fm][fn] = __builtin_amdgcn_mfma_f32_16x16x32_bf16(a_h[fm], b_h[fn], acc[fm][fn], 0, 0, 0);
        acc[fm][fn] = __builtin_amdgcn_mfma_f32_16x16x32_bf16(a_h[fm], b_l[fn], acc[fm][fn], 0, 0, 0);
        acc[fm][fn] = __builtin_amdgcn_mfma_f32_16x16x32_bf16(a_l[fm], b_h[fn], acc[fm][fn], 0, 0, 0);
      }
  }
  int range = o0 >> 8;                 // 0: h(gelu,tb1)  1: ctr(db1)  2: nbr
  float* dst = (range == 0) ? hb : (range == 1) ? cb : nb;
  const float* bias = (range == 0) ? tb1 : (range == 1) ? db1 : nullptr;
  int ol0 = o0 & 255;
#pragma unroll
  for (int fm = 0; fm < 4; ++fm) {
    int o = ol0 + wm + fm * 16 + quad * 4;
#pragma unroll
    for (int r = 0; r < 4; ++r) {
      float bv = bias ? bias[o + r] : 0.f;
      size_t rowoff = ((size_t)b * Cc + o + r) * Tt + t0;
#pragma unroll
      for (int fn = 0; fn < 4; ++fn) {
        int t = wn + fn * 16 + l15;
        float v = acc[fm][fn][r] + bv;
        if (range == 0) v = gelu_f(v);
        dst[rowoff + t] = v;
      }
    }
  }
}

// score GEMM, 2 batches per dispatch via z
__global__ __launch_bounds__(256) void score_gemm(
    const unsigned short* __restrict__ xh, const unsigned short* __restrict__ xl,
    const float* __restrict__ xx, float* __restrict__ S, int bbase) {
  __shared__ __align__(16) unsigned short Ah[128][40], Al[128][40];
  __shared__ __align__(16) unsigned short Bh[128][40], Bl[128][40];
  int lb = blockIdx.z;
  int b = bbase + lb;
  int m0 = blockIdx.y * 128, n0 = blockIdx.x * 128;
  int tid = threadIdx.x;
  int w = tid >> 6, lane = tid & 63, quad = lane >> 4, l15 = lane & 15;
  int wm = (w >> 1) * 64, wn = (w & 1) * 64;
  const unsigned short* xhb = xh + (size_t)b * Tt * Cc;
  const unsigned short* xlb = xl + (size_t)b * Tt * Cc;
  const float* xxb = xx + (size_t)b * Tt;
  float* Sb = S + (size_t)lb * Tt * Tt;
  floatx4 acc[4][4];
#pragma unroll
  for (int i = 0; i < 4; ++i)
#pragma unroll
    for (int j = 0; j < 4; ++j) acc[i][j] = (floatx4){0.f, 0.f, 0.f, 0.f};

  int sr = tid >> 1;
  int sq = (tid & 1) * 2;
  for (int kc = 0; kc < Cc; kc += 32) {
    __syncthreads();
    {
      const unsigned short* am = xhb + (size_t)(m0 + sr) * Cc + kc + sq * 8;
      *(uint4*)&Ah[sr][sq * 8] = *(const uint4*)am;
      *(uint4*)&Ah[sr][sq * 8 + 8] = *(const uint4*)(am + 8);
      const unsigned short* al = xlb + (size_t)(m0 + sr) * Cc + kc + sq * 8;
      *(uint4*)&Al[sr][sq * 8] = *(const uint4*)al;
      *(uint4*)&Al[sr][sq * 8 + 8] = *(const uint4*)(al + 8);
      const unsigned short* bm = xhb + (size_t)(n0 + sr) * Cc + kc + sq * 8;
      *(uint4*)&Bh[sr][sq * 8] = *(const uint4*)bm;
      *(uint4*)&Bh[sr][sq * 8 + 8] = *(const uint4*)(bm + 8);
      const unsigned short* bl = xlb + (size_t)(n0 + sr) * Cc + kc + sq * 8;
      *(uint4*)&Bl[sr][sq * 8] = *(const uint4*)bl;
      *(uint4*)&Bl[sr][sq * 8 + 8] = *(const uint4*)(bl + 8);
    }
    __syncthreads();
    int ka = quad * 8;
    short8 a_h[4], a_l[4], b_h[4], b_l[4];
#pragma unroll
    for (int f = 0; f < 4; ++f) {
      a_h[f] = *(const short8*)&Ah[wm + f * 16 + l15][ka];
      a_l[f] = *(const short8*)&Al[wm + f * 16 + l15][ka];
      b_h[f] = *(const short8*)&Bh[wn + f * 16 + l15][ka];
      b_l[f] = *(const short8*)&Bl[wn + f * 16 + l15][ka];
    }
#pragma unroll
    for (int fm = 0; fm < 4; ++fm)
#pragma unroll
      for (int fn = 0; fn < 4; ++fn) {
        acc[fm][fn] = __builtin_amdgcn_mfma_f32_16x16x32_bf16(a_h[fm], b_h[fn], acc[fm][fn], 0, 0, 0);
        acc[fm][fn] = __builtin_amdgcn_mfma_f32_16x16x32_bf16(a_h[fm], b_l[fn], acc[fm][fn], 0, 0, 0);
        acc[fm][fn] = __builtin_amdgcn_mfma_f32_16x16x32_bf16(a_l[fm], b_h[fn], acc[fm][fn], 0, 0, 0);
      }
  }
#pragma unroll
  for (int fn = 0; fn < 4; ++fn) {
    int n = n0 + wn + fn * 16 + l15;
    float xv = xxb[n];
#pragma unroll
    for (int fm = 0; fm < 4; ++fm) {
      int m = m0 + wm + fm * 16 + quad * 4;
#pragma unroll
      for (int r = 0; r < 4; ++r)
        Sb[(size_t)(m + r) * Tt + n] = fmaf(2.f, acc[fm][fn][r], -xv);
    }
  }
}

// top-10 scan, 2 batches via z; wave per row, 8 rows per block
__global__ __launch_bounds__(512) void topk_scan(
    const float* __restrict__ S, int* __restrict__ idx10, int bbase) {
  int lb = blockIdx.z;
  int m = blockIdx.x * 8 + (threadIdx.x >> 6);
  int lane = threadIdx.x & 63;
  const float* row = S + ((size_t)lb * Tt + m) * Tt;
  float s[NTOP]; int idl[NTOP];
#pragma unroll
  for (int j = 0; j < NTOP; ++j) { s[j] = -INFINITY; idl[j] = 0x7fffffff; }
  for (int c0 = lane * 4; c0 < Tt; c0 += 256) {
    float4 v = *(const float4*)(row + c0);
    float cand[4] = {v.x, v.y, v.z, v.w};
#pragma unroll
    for (int e = 0; e < 4; ++e) {
      float sc = cand[e];
      if (sc > s[NTOP - 1]) {
        s[NTOP - 1] = sc; idl[NTOP - 1] = c0 + e;
#pragma unroll
        for (int j = NTOP - 1; j > 0; --j) {
          if (s[j] > s[j - 1]) {
            float ts = s[j]; s[j] = s[j - 1]; s[j - 1] = ts;
            int ti = idl[j]; idl[j] = idl[j - 1]; idl[j - 1] = ti;
          }
        }
      }
    }
  }
  int ptr = 0;
  for (int r = 0; r < NTOP; ++r) {
    float cs = (ptr < NTOP) ? s[ptr] : -INFINITY;
    int cid = (ptr < NTOP) ? idl[ptr] : 0x7fffffff;
    float bs = cs; int bi = cid;
#pragma unroll
    for (int off = 1; off < 64; off <<= 1) {
      float os = __shfl_xor(bs, off);
      int oi = __shfl_xor(bi, off);
      if (os > bs || (os == bs && oi < bi)) { bs = os; bi = oi; }
    }
    if (cid == bi) ptr++;
    if (lane == 0) idx10[((size_t)(bbase + lb) * Tt + m) * NTOP + r] = bi;
  }
}

// fp64 rescore of the NTOP shortlist, emit exact top-7
__global__ __launch_bounds__(64) void knn_rescore(
    const float* __restrict__ xT, const int* __restrict__ idx10,
    int* __restrict__ idxout) {
  int t = blockIdx.x;
  int b = blockIdx.y;
  int lane = threadIdx.x;
  const float* xTb = xT + (size_t)b * Tt * Cc;
  const float* xm = xTb + (size_t)t * Cc;
  double sc = -1e300;
  int cid = 0x7fffffff;
  if (lane < NTOP) {
    int j = idx10[((size_t)b * Tt + t) * NTOP + lane];
    const float* xn = xTb + (size_t)j * Cc;
    double dot = 0.0, nn = 0.0;
    for (int c = 0; c < Cc; c += 4) {
      float4 a = *(const float4*)(xm + c);
      float4 v = *(const float4*)(xn + c);
      dot += (double)a.x * v.x + (double)a.y * v.y + (double)a.z * v.z + (double)a.w * v.w;
      nn  += (double)v.x * v.x + (double)v.y * v.y + (double)v.z * v.z + (double)v.w * v.w;
    }
    sc = 2.0 * dot - nn;
    cid = j;
  }
  for (int r = 0; r < Kk; ++r) {
    double bs = sc; int bi = cid;
#pragma unroll
    for (int off = 1; off < 64; off <<= 1) {
      double os = __shfl_xor(bs, off);
      int oi = __shfl_xor(bi, off);
      if (os > bs || (os == bs && oi < bi)) { bs = os; bi = oi; }
    }
    if (cid == bi) { sc = -1e300; cid = 0x7fffffff; }
    if (lane == 0) idxout[((size_t)b * Tt + t) * Kk + r] = bi;
  }
}

// Fused graph tail + temporal conv. FAST=0: exact erff (layer 1 — its output is
// x1 which feeds layer-2 KNN and must be bit-stable; R10 proved fast-erf flips it).
// FAST=1: rational erf (layer 2 — output only feeds the final result).
template <int FAST>
__global__ __launch_bounds__(256) void graph_tail(
    const float* __restrict__ h, const float* __restrict__ ctr,
    const float* __restrict__ nbr, const int* __restrict__ idx,
    const float* __restrict__ tw2, const float* __restrict__ tb2,
    const float* __restrict__ dw2, const float* __restrict__ db2,
    const float* __restrict__ xin, float* __restrict__ xout) {
  __shared__ __align__(16) float gt[CG][Kk][68];   // 14.9 KB
  __shared__ __align__(16) float ht[CG][68];       // 2.2 KB
  __shared__ int jt[68][Kk];                       // 1.9 KB
  int t0 = blockIdx.x * 64;
  int g = blockIdx.y;
  int b = blockIdx.z;
  int tid = threadIdx.x;
  const float* hg   = h   + ((size_t)b * Cc + g * CG) * Tt;
  const float* ctrg = ctr + ((size_t)b * Cc + g * CG) * Tt;
  const float* nbrg = nbr + ((size_t)b * Cc + g * CG) * Tt;

  {
    const int* ib = idx + ((size_t)b * Tt + t0 - 2) * Kk;
    for (int e = tid; e < 68 * Kk; e += 256) {
      int tg = t0 - 2 + e / Kk;
      jt[e / Kk][e % Kk] = (tg >= 0 && tg < Tt) ? ib[e] : 0;
    }
    for (int e = tid; e < CG * 68; e += 256) {
      int ci = e / 68, tl = e % 68;
      int tg = t0 - 2 + tl;
      ht[ci][tl] = (tg >= 0 && tg < Tt) ? hg[(size_t)ci * Tt + tg] : 0.f;
    }
  }
  __syncthreads();
  for (int e = tid; e < CG * Kk * 68; e += 256) {
    int ci = e / (Kk * 68), rem = e % (Kk * 68), k = rem / 68, tl = rem % 68;
    int tg = t0 - 2 + tl;
    float v = 0.f;
    if (tg >= 0 && tg < Tt) {
      int j = jt[tl][k];
      float pre = ctrg[(size_t)ci * Tt + tg] + nbrg[(size_t)ci * Tt + j];
      v = FAST ? gelu_fast(pre) : gelu_f(pre);
    }
    gt[ci][k][tl] = v;
  }
  __syncthreads();

  // conv phase: thread = (o_local = tid>>5, 2 tokens at tl2=(tid&31)*2)
  int ol = tid >> 5, tl2 = (tid & 31) * 2;
  int o = g * CG + ol;

  // temporal conv (former gconv1d): same op order, zero-padded taps -> bit-identical
  const float* w2 = tw2 + (size_t)o * CG * 5;
  float bt = tb2[o];
  floatx2 acct = {bt, bt};
  for (int ci = 0; ci < CG; ++ci) {
    floatx2 p0 = *(const floatx2*)&ht[ci][tl2];
    floatx2 p1 = *(const floatx2*)&ht[ci][tl2 + 2];
    floatx2 p2 = *(const floatx2*)&ht[ci][tl2 + 4];
    float r6[6] = {p0.x, p0.y, p1.x, p1.y, p2.x, p2.y};
#pragma unroll
    for (int dt = 0; dt < 5; ++dt) {
      float wv = w2[ci * 5 + dt];
      floatx2 wv2 = {wv, wv};
      floatx2 rp = {r6[dt], r6[dt + 1]};
      acct = __builtin_elementwise_fma(wv2, rp, acct);
    }
  }

  // graph 5x5 conv + max over k
  const float* wp = dw2 + (size_t)o * CG * 25;
  float bv = db2[o];
  floatx2 acc[Kk];
#pragma unroll
  for (int k = 0; k < Kk; ++k) acc[k] = (floatx2){bv, bv};

  for (int ci = 0; ci < CG; ++ci) {
    float w[25];
#pragma unroll
    for (int i = 0; i < 25; ++i) w[i] = wp[ci * 25 + i];
#pragma unroll
    for (int kin = 0; kin < Kk; ++kin) {
      floatx2 p0 = *(const floatx2*)&gt[ci][kin][tl2];
      floatx2 p1 = *(const floatx2*)&gt[ci][kin][tl2 + 2];
      floatx2 p2 = *(const floatx2*)&gt[ci][kin][tl2 + 4];
      float r6[6] = {p0.x, p0.y, p1.x, p1.y, p2.x, p2.y};
      floatx2 rp[5];
#pragma unroll
      for (int dt = 0; dt < 5; ++dt) rp[dt] = (floatx2){r6[dt], r6[dt + 1]};
#pragma unroll
      for (int dk = 0; dk < 5; ++dk) {
        int k = kin + 2 - dk;
        if (k < 0 || k >= Kk) continue;
#pragma unroll
        for (int dt = 0; dt < 5; ++dt) {
          float wv = w[dt * 5 + dk];
          floatx2 wv2 = {wv, wv};
          acc[k] = __builtin_elementwise_fma(wv2, rp[dt], acc[k]);
        }
      }
    }
  }
  floatx2 m = acc[0];
#pragma unroll
  for (int k = 1; k < Kk; ++k) m = __builtin_elementwise_max(m, acc[k]);
  size_t off = ((size_t)b * Cc + o) * Tt + t0 + tl2;
  floatx2 xv = *(const floatx2*)&xin[off];
  floatx2 r;
  r.x = acct.x + m.x + xv.x;
  r.y = acct.y + m.y + xv.y;
  *(floatx2*)&xout[off] = r;
}

extern "C" void kernel_launch(void* const* d_in, const int* in_sizes, int n_in,
                              void* d_out, int out_size, void* d_ws, size_t ws_size,
                              hipStream_t stream) {
  const float* x0  = (const float*)d_in[0];
  const float* tw1 = (const float*)d_in[1];
  const float* tb1 = (const float*)d_in[2];
  const float* tw2 = (const float*)d_in[3];
  const float* tb2 = (const float*)d_in[4];
  const float* dw1 = (const float*)d_in[5];
  const float* db1 = (const float*)d_in[6];
  const float* dw2 = (const float*)d_in[7];
  const float* db2 = (const float*)d_in[8];
  float* out = (float*)d_out;

  float* ws = (float*)d_ws;
  const size_t NCT = (size_t)Bq * Cc * Tt;      // 2M elements
  float* x1   = ws;                             // layer-1 output   [B,C,T]
  float* hbuf = x1 + NCT;                       // h                [B,C,T]
  float* cbuf = hbuf + NCT;                     // ctr              [B,C,T]
  float* xT   = cbuf + NCT;                     // xT, then nbr     [B,T,C]
  unsigned short* xh = (unsigned short*)(xT + NCT);   // [B,T,C] bf16 hi
  unsigned short* xl = xh + NCT;                      // bf16 lo
  unsigned short* wh = xl + NCT;                      // weights hi [768][256]
  unsigned short* wl = wh + (size_t)NO * Cc;
  float* S    = (float*)(wl + (size_t)NO * Cc); // scores, 2 batches [2,T,T] 32MB
  float* xx   = S + 2 * (size_t)Tt * Tt;        // squared norms    [B,T]
  int* idxb   = (int*)(xx + (size_t)Bq * Tt);   // top-7            [B,T,K]
  int* idx10  = idxb + (size_t)Bq * Tt * Kk;    // top-10           [B,T,NTOP]
  float* nbr  = xT;                             // nbr overwrites xT after rescore

  for (int i = 0; i < Ll; ++i) {
    const float* xin = (i == 0) ? x0 : x1;
    float* xout = (i == Ll - 1) ? out : x1;

    transpose_x<<<dim3(Tt/32, Cc/32, Bq), dim3(32, 8), 0, stream>>>(xin, xT, xh, xl);
    sqnorm_xt<<<dim3(Tt/8, Bq), 512, 0, stream>>>(xT, xx);
    for (int bp = 0; bp < Bq; bp += 2) {
      score_gemm<<<dim3(16, 16, 2), 256, 0, stream>>>(xh, xl, xx, S, bp);
      topk_scan<<<dim3(Tt/8, 1, 2), 512, 0, stream>>>(S, idx10, bp);
    }
    knn_rescore<<<dim3(Tt, Bq), 64, 0, stream>>>(xT, idx10, idxb);

    if (i == 0) {
      // Layer 1: exact fp32 pointwise convs (x1 feeds layer-2 KNN; R6/R7/R10 forensics)
      pw_conv8_all<<<dim3(Tt/256, 96, Bq), 256, 0, stream>>>(
          xin, tw1 + (size_t)i * Cc * Cc, tb1 + (size_t)i * Cc,
          dw1 + (size_t)i * Cc * 2 * Cc, db1 + (size_t)i * Cc,
          hbuf, cbuf, nbr);
      graph_tail<0><<<dim3(Tt/64, Cc/CG, Bq), 256, 0, stream>>>(
          hbuf, cbuf, nbr, idxb, tw2 + (size_t)i * Cc * CG * 5, tb2 + (size_t)i * Cc,
          dw2 + (size_t)i * Cc * CG * 25, db2 + (size_t)i * Cc, xin, xout);
    } else {
      // Layer 2: split-bf16 MFMA GEMM + fast-erf tail — feeds only the final output.
      wsplit<<<dim3(NO), 256, 0, stream>>>(
          tw1 + (size_t)i * Cc * Cc, dw1 + (size_t)i * Cc * 2 * Cc, wh, wl);
      pw_gemm<<<dim3(64, NO/128), 256, 0, stream>>>(
          wh, wl, xh, xl, tb1 + (size_t)i * Cc, db1 + (size_t)i * Cc,
          hbuf, cbuf, nbr);
      graph_tail<1><<<dim3(Tt/64, Cc/CG, Bq), 256, 0, stream>>>(
          hbuf, cbuf, nbr, idxb, tw2 + (size_t)i * Cc * CG * 5, tb2 + (size_t)i * Cc,
          dw2 + (size_t)i * Cc * CG * 25, db2 + (size_t)i * Cc, xin, xout);
    }
  }
}

// Round 12
// 590.807 us; speedup vs baseline: 3.6972x; 1.0074x over previous
//
#include <hip/hip_runtime.h>
#include <math.h>

#define Bq 4
#define Cc 256
#define Tt 2048
#define Kk 7
#define NTOP 10
#define CG 8
#define Ll 2
#define NO 768   // fused pointwise outputs: 256 h | 256 ctr | 256 nbr

typedef __attribute__((ext_vector_type(8))) short short8;
typedef __attribute__((ext_vector_type(4))) float floatx4;
typedef __attribute__((ext_vector_type(2))) float floatx2;

__device__ __forceinline__ float gelu_f(float v) {
  return 0.5f * v * (1.0f + erff(v * 0.70710678118654752440f));
}

// A&S 7.1.26 rational erf (~1e-6 eff err in fp32). SAFE ONLY on paths that do
// not feed a later top-k: R10 proved a ~1e-6 x1 perturbation flips layer-2 KNN.
__device__ __forceinline__ float erf_fast(float x) {
  float ax = fabsf(x);
  float t = __builtin_amdgcn_rcpf(fmaf(0.3275911f, ax, 1.0f));
  float y = t * (0.254829592f + t * (-0.284496736f + t * (1.421413741f +
            t * (-1.453152027f + t * 1.061405429f))));
  float r = 1.0f - y * __expf(-ax * ax);
  return copysignf(r, x);
}
__device__ __forceinline__ float gelu_fast(float v) {
  return 0.5f * v * (1.0f + erf_fast(v * 0.70710678118654752440f));
}

// xT[b][t][c] = x[b][c][t]; also emits bf16 hi/lo split
__global__ void transpose_x(const float* __restrict__ x, float* __restrict__ xT,
                            unsigned short* __restrict__ xh,
                            unsigned short* __restrict__ xl) {
  __shared__ float tile[32][33];
  int b = blockIdx.z;
  int t0 = blockIdx.x * 32, c0 = blockIdx.y * 32;
  int tx = threadIdx.x, ty = threadIdx.y;
  const float* xb = x + (size_t)b * Cc * Tt;
  for (int r = ty; r < 32; r += 8)
    tile[r][tx] = xb[(size_t)(c0 + r) * Tt + t0 + tx];
  __syncthreads();
  size_t base = (size_t)b * Tt * Cc;
  for (int r = ty; r < 32; r += 8) {
    float v = tile[tx][r];
    size_t o = base + (size_t)(t0 + r) * Cc + c0 + tx;
    xT[o] = v;
    unsigned int u = __float_as_uint(v);
    unsigned short h = (unsigned short)((u + 0x7fffu + ((u >> 16) & 1u)) >> 16);
    float f = v - __uint_as_float((unsigned int)h << 16);
    unsigned int ul = __float_as_uint(f);
    xh[o] = h;
    xl[o] = (unsigned short)((ul + 0x7fffu + ((ul >> 16) & 1u)) >> 16);
  }
}

// plain fp32 transpose: dst[b][t][c] = src[b][c][t]  (for nbr -> nbrT)
__global__ void transpose_f(const float* __restrict__ src, float* __restrict__ dst) {
  __shared__ float tile[32][33];
  int b = blockIdx.z;
  int t0 = blockIdx.x * 32, c0 = blockIdx.y * 32;
  int tx = threadIdx.x, ty = threadIdx.y;
  const float* sb = src + (size_t)b * Cc * Tt;
  for (int r = ty; r < 32; r += 8)
    tile[r][tx] = sb[(size_t)(c0 + r) * Tt + t0 + tx];
  __syncthreads();
  float* db = dst + (size_t)b * Tt * Cc;
  for (int r = ty; r < 32; r += 8)
    db[(size_t)(t0 + r) * Cc + c0 + tx] = tile[tx][r];
}

// squared norms from xT; wave per row t, 8 rows per block
__global__ __launch_bounds__(512) void sqnorm_xt(
    const float* __restrict__ xT, float* __restrict__ xx) {
  int b = blockIdx.y;
  int t = blockIdx.x * 8 + (threadIdx.x >> 6);
  int lane = threadIdx.x & 63;
  const float* row = xT + ((size_t)b * Tt + t) * Cc;
  float4 v = *(const float4*)(row + lane * 4);
  float acc = v.x * v.x + v.y * v.y + v.z * v.z + v.w * v.w;
#pragma unroll
  for (int off = 1; off < 64; off <<= 1) acc += __shfl_xor(acc, off);
  if (lane == 0) xx[(size_t)b * Tt + t] = acc;
}

// fp32 pointwise convs, all 3 ranges in one launch (layer-1 exact path).
__global__ __launch_bounds__(256) void pw_conv8_all(
    const float* __restrict__ x, const float* __restrict__ tw1,
    const float* __restrict__ tb1, const float* __restrict__ dw1,
    const float* __restrict__ db1, float* __restrict__ hb,
    float* __restrict__ cb, float* __restrict__ nb) {
  int t = blockIdx.x * 256 + threadIdx.x;
  int oy = blockIdx.y;
  int b = blockIdx.z;
  int range = oy >> 5;            // 0: h  1: ctr  2: nbr
  int o0 = (oy & 31) * 8;
  const float* W; int wstride, woff; const float* bias; float* dst; int dg;
  if (range == 0)      { W = tw1; wstride = Cc;     woff = 0;  bias = tb1;     dst = hb; dg = 1; }
  else if (range == 1) { W = dw1; wstride = 2 * Cc; woff = Cc; bias = db1;     dst = cb; dg = 0; }
  else                 { W = dw1; wstride = 2 * Cc; woff = 0;  bias = nullptr; dst = nb; dg = 0; }
  const float* xp = x + (size_t)b * Cc * Tt + t;
  const float* wp = W + (size_t)o0 * wstride + woff;
  float acc[8];
#pragma unroll
  for (int j = 0; j < 8; ++j) acc[j] = bias ? bias[o0 + j] : 0.f;
  for (int c = 0; c < Cc; c += 4) {
    float xv0 = xp[(size_t)c * Tt];
    float xv1 = xp[(size_t)(c + 1) * Tt];
    float xv2 = xp[(size_t)(c + 2) * Tt];
    float xv3 = xp[(size_t)(c + 3) * Tt];
#pragma unroll
    for (int j = 0; j < 8; ++j) {
      const float* wr = wp + (size_t)j * wstride + c;
      float a = acc[j];
      a = fmaf(wr[0], xv0, a);
      a = fmaf(wr[1], xv1, a);
      a = fmaf(wr[2], xv2, a);
      a = fmaf(wr[3], xv3, a);
      acc[j] = a;
    }
  }
#pragma unroll
  for (int j = 0; j < 8; ++j) {
    float v = acc[j];
    if (dg) v = gelu_f(v);
    dst[((size_t)b * Cc + o0 + j) * Tt + t] = v;
  }
}

// concat weights [768][256] -> bf16 hi/lo (layer-2 only)
__global__ __launch_bounds__(256) void wsplit(
    const float* __restrict__ tw1, const float* __restrict__ dw1,
    unsigned short* __restrict__ wh, unsigned short* __restrict__ wl) {
  int o = blockIdx.x;
  int c = threadIdx.x;
  float v;
  if (o < 256) v = tw1[(size_t)o * Cc + c];
  else if (o < 512) v = dw1[(size_t)(o - 256) * (2 * Cc) + Cc + c];
  else v = dw1[(size_t)(o - 512) * (2 * Cc) + c];
  unsigned int u = __float_as_uint(v);
  unsigned short h = (unsigned short)((u + 0x7fffu + ((u >> 16) & 1u)) >> 16);
  float f = v - __uint_as_float((unsigned int)h << 16);
  unsigned int ul = __float_as_uint(f);
  wh[(size_t)o * Cc + c] = h;
  wl[(size_t)o * Cc + c] = (unsigned short)((ul + 0x7fffu + ((ul >> 16) & 1u)) >> 16);
}

// fused pointwise GEMM (layer-2 only)
__global__ __launch_bounds__(256) void pw_gemm(
    const unsigned short* __restrict__ wh, const unsigned short* __restrict__ wl,
    const unsigned short* __restrict__ xh, const unsigned short* __restrict__ xl,
    const float* __restrict__ tb1, const float* __restrict__ db1,
    float* __restrict__ hb, float* __restrict__ cb, float* __restrict__ nb) {
  __shared__ __align__(16) unsigned short Ah[128][40], Al[128][40];
  __shared__ __align__(16) unsigned short Bh[128][40], Bl[128][40];
  int mt = blockIdx.x;
  int b = mt >> 4;
  int t0 = (mt & 15) * 128;
  int o0 = blockIdx.y * 128;
  int tid = threadIdx.x;
  int w = tid >> 6, lane = tid & 63, quad = lane >> 4, l15 = lane & 15;
  int wm = (w >> 1) * 64, wn = (w & 1) * 64;
  floatx4 acc[4][4];
#pragma unroll
  for (int i = 0; i < 4; ++i)
#pragma unroll
    for (int j = 0; j < 4; ++j) acc[i][j] = (floatx4){0.f, 0.f, 0.f, 0.f};

  const unsigned short* xhb = xh + ((size_t)b * Tt + t0) * Cc;
  const unsigned short* xlb = xl + ((size_t)b * Tt + t0) * Cc;
  int sr = tid >> 1;
  int sq = (tid & 1) * 2;
  for (int kc = 0; kc < Cc; kc += 32) {
    __syncthreads();
    {
      const unsigned short* am = wh + (size_t)(o0 + sr) * Cc + kc + sq * 8;
      *(uint4*)&Ah[sr][sq * 8] = *(const uint4*)am;
      *(uint4*)&Ah[sr][sq * 8 + 8] = *(const uint4*)(am + 8);
      const unsigned short* al = wl + (size_t)(o0 + sr) * Cc + kc + sq * 8;
      *(uint4*)&Al[sr][sq * 8] = *(const uint4*)al;
      *(uint4*)&Al[sr][sq * 8 + 8] = *(const uint4*)(al + 8);
      const unsigned short* bm = xhb + (size_t)sr * Cc + kc + sq * 8;
      *(uint4*)&Bh[sr][sq * 8] = *(const uint4*)bm;
      *(uint4*)&Bh[sr][sq * 8 + 8] = *(const uint4*)(bm + 8);
      const unsigned short* bl = xlb + (size_t)sr * Cc + kc + sq * 8;
      *(uint4*)&Bl[sr][sq * 8] = *(const uint4*)bl;
      *(uint4*)&Bl[sr][sq * 8 + 8] = *(const uint4*)(bl + 8);
    }
    __syncthreads();
    int ka = quad * 8;
    short8 a_h[4], a_l[4], b_h[4], b_l[4];
#pragma unroll
    for (int f = 0; f < 4; ++f) {
      a_h[f] = *(const short8*)&Ah[wm + f * 16 + l15][ka];
      a_l[f] = *(const short8*)&Al[wm + f * 16 + l15][ka];
      b_h[f] = *(const short8*)&Bh[wn + f * 16 + l15][ka];
      b_l[f] = *(const short8*)&Bl[wn + f * 16 + l15][ka];
    }
#pragma unroll
    for (int fm = 0; fm < 4; ++fm)
#pragma unroll
      for (int fn = 0; fn < 4; ++fn) {
        acc[fm][fn] = __builtin_amdgcn_mfma_f32_16x16x32_bf16(a_h[fm], b_h[fn], acc[fm][fn], 0, 0, 0);
        acc[fm][fn] = __builtin_amdgcn_mfma_f32_16x16x32_bf16(a_h[fm], b_l[fn], acc[fm][fn], 0, 0, 0);
        acc[fm][fn] = __builtin_amdgcn_mfma_f32_16x16x32_bf16(a_l[fm], b_h[fn], acc[fm][fn], 0, 0, 0);
      }
  }
  int range = o0 >> 8;                 // 0: h(gelu,tb1)  1: ctr(db1)  2: nbr
  float* dst = (range == 0) ? hb : (range == 1) ? cb : nb;
  const float* bias = (range == 0) ? tb1 : (range == 1) ? db1 : nullptr;
  int ol0 = o0 & 255;
#pragma unroll
  for (int fm = 0; fm < 4; ++fm) {
    int o = ol0 + wm + fm * 16 + quad * 4;
#pragma unroll
    for (int r = 0; r < 4; ++r) {
      float bv = bias ? bias[o + r] : 0.f;
      size_t rowoff = ((size_t)b * Cc + o + r) * Tt + t0;
#pragma unroll
      for (int fn = 0; fn < 4; ++fn) {
        int t = wn + fn * 16 + l15;
        float v = acc[fm][fn][r] + bv;
        if (range == 0) v = gelu_f(v);
        dst[rowoff + t] = v;
      }
    }
  }
}

// score GEMM, 2 batches per dispatch via z
__global__ __launch_bounds__(256) void score_gemm(
    const unsigned short* __restrict__ xh, const unsigned short* __restrict__ xl,
    const float* __restrict__ xx, float* __restrict__ S, int bbase) {
  __shared__ __align__(16) unsigned short Ah[128][40], Al[128][40];
  __shared__ __align__(16) unsigned short Bh[128][40], Bl[128][40];
  int lb = blockIdx.z;
  int b = bbase + lb;
  int m0 = blockIdx.y * 128, n0 = blockIdx.x * 128;
  int tid = threadIdx.x;
  int w = tid >> 6, lane = tid & 63, quad = lane >> 4, l15 = lane & 15;
  int wm = (w >> 1) * 64, wn = (w & 1) * 64;
  const unsigned short* xhb = xh + (size_t)b * Tt * Cc;
  const unsigned short* xlb = xl + (size_t)b * Tt * Cc;
  const float* xxb = xx + (size_t)b * Tt;
  float* Sb = S + (size_t)lb * Tt * Tt;
  floatx4 acc[4][4];
#pragma unroll
  for (int i = 0; i < 4; ++i)
#pragma unroll
    for (int j = 0; j < 4; ++j) acc[i][j] = (floatx4){0.f, 0.f, 0.f, 0.f};

  int sr = tid >> 1;
  int sq = (tid & 1) * 2;
  for (int kc = 0; kc < Cc; kc += 32) {
    __syncthreads();
    {
      const unsigned short* am = xhb + (size_t)(m0 + sr) * Cc + kc + sq * 8;
      *(uint4*)&Ah[sr][sq * 8] = *(const uint4*)am;
      *(uint4*)&Ah[sr][sq * 8 + 8] = *(const uint4*)(am + 8);
      const unsigned short* al = xlb + (size_t)(m0 + sr) * Cc + kc + sq * 8;
      *(uint4*)&Al[sr][sq * 8] = *(const uint4*)al;
      *(uint4*)&Al[sr][sq * 8 + 8] = *(const uint4*)(al + 8);
      const unsigned short* bm = xhb + (size_t)(n0 + sr) * Cc + kc + sq * 8;
      *(uint4*)&Bh[sr][sq * 8] = *(const uint4*)bm;
      *(uint4*)&Bh[sr][sq * 8 + 8] = *(const uint4*)(bm + 8);
      const unsigned short* bl = xlb + (size_t)(n0 + sr) * Cc + kc + sq * 8;
      *(uint4*)&Bl[sr][sq * 8] = *(const uint4*)bl;
      *(uint4*)&Bl[sr][sq * 8 + 8] = *(const uint4*)(bl + 8);
    }
    __syncthreads();
    int ka = quad * 8;
    short8 a_h[4], a_l[4], b_h[4], b_l[4];
#pragma unroll
    for (int f = 0; f < 4; ++f) {
      a_h[f] = *(const short8*)&Ah[wm + f * 16 + l15][ka];
      a_l[f] = *(const short8*)&Al[wm + f * 16 + l15][ka];
      b_h[f] = *(const short8*)&Bh[wn + f * 16 + l15][ka];
      b_l[f] = *(const short8*)&Bl[wn + f * 16 + l15][ka];
    }
#pragma unroll
    for (int fm = 0; fm < 4; ++fm)
#pragma unroll
      for (int fn = 0; fn < 4; ++fn) {
        acc[fm][fn] = __builtin_amdgcn_mfma_f32_16x16x32_bf16(a_h[fm], b_h[fn], acc[fm][fn], 0, 0, 0);
        acc[fm][fn] = __builtin_amdgcn_mfma_f32_16x16x32_bf16(a_h[fm], b_l[fn], acc[fm][fn], 0, 0, 0);
        acc[fm][fn] = __builtin_amdgcn_mfma_f32_16x16x32_bf16(a_l[fm], b_h[fn], acc[fm][fn], 0, 0, 0);
      }
  }
#pragma unroll
  for (int fn = 0; fn < 4; ++fn) {
    int n = n0 + wn + fn * 16 + l15;
    float xv = xxb[n];
#pragma unroll
    for (int fm = 0; fm < 4; ++fm) {
      int m = m0 + wm + fm * 16 + quad * 4;
#pragma unroll
      for (int r = 0; r < 4; ++r)
        Sb[(size_t)(m + r) * Tt + n] = fmaf(2.f, acc[fm][fn][r], -xv);
    }
  }
}

// top-10 scan, 2 batches via z; wave per row, 8 rows per block
__global__ __launch_bounds__(512) void topk_scan(
    const float* __restrict__ S, int* __restrict__ idx10, int bbase) {
  int lb = blockIdx.z;
  int m = blockIdx.x * 8 + (threadIdx.x >> 6);
  int lane = threadIdx.x & 63;
  const float* row = S + ((size_t)lb * Tt + m) * Tt;
  float s[NTOP]; int idl[NTOP];
#pragma unroll
  for (int j = 0; j < NTOP; ++j) { s[j] = -INFINITY; idl[j] = 0x7fffffff; }
  for (int c0 = lane * 4; c0 < Tt; c0 += 256) {
    float4 v = *(const float4*)(row + c0);
    float cand[4] = {v.x, v.y, v.z, v.w};
#pragma unroll
    for (int e = 0; e < 4; ++e) {
      float sc = cand[e];
      if (sc > s[NTOP - 1]) {
        s[NTOP - 1] = sc; idl[NTOP - 1] = c0 + e;
#pragma unroll
        for (int j = NTOP - 1; j > 0; --j) {
          if (s[j] > s[j - 1]) {
            float ts = s[j]; s[j] = s[j - 1]; s[j - 1] = ts;
            int ti = idl[j]; idl[j] = idl[j - 1]; idl[j - 1] = ti;
          }
        }
      }
    }
  }
  int ptr = 0;
  for (int r = 0; r < NTOP; ++r) {
    float cs = (ptr < NTOP) ? s[ptr] : -INFINITY;
    int cid = (ptr < NTOP) ? idl[ptr] : 0x7fffffff;
    float bs = cs; int bi = cid;
#pragma unroll
    for (int off = 1; off < 64; off <<= 1) {
      float os = __shfl_xor(bs, off);
      int oi = __shfl_xor(bi, off);
      if (os > bs || (os == bs && oi < bi)) { bs = os; bi = oi; }
    }
    if (cid == bi) ptr++;
    if (lane == 0) idx10[((size_t)(bbase + lb) * Tt + m) * NTOP + r] = bi;
  }
}

// fp64 rescore of the NTOP shortlist, emit exact top-7
__global__ __launch_bounds__(64) void knn_rescore(
    const float* __restrict__ xT, const int* __restrict__ idx10,
    int* __restrict__ idxout) {
  int t = blockIdx.x;
  int b = blockIdx.y;
  int lane = threadIdx.x;
  const float* xTb = xT + (size_t)b * Tt * Cc;
  const float* xm = xTb + (size_t)t * Cc;
  double sc = -1e300;
  int cid = 0x7fffffff;
  if (lane < NTOP) {
    int j = idx10[((size_t)b * Tt + t) * NTOP + lane];
    const float* xn = xTb + (size_t)j * Cc;
    double dot = 0.0, nn = 0.0;
    for (int c = 0; c < Cc; c += 4) {
      float4 a = *(const float4*)(xm + c);
      float4 v = *(const float4*)(xn + c);
      dot += (double)a.x * v.x + (double)a.y * v.y + (double)a.z * v.z + (double)a.w * v.w;
      nn  += (double)v.x * v.x + (double)v.y * v.y + (double)v.z * v.z + (double)v.w * v.w;
    }
    sc = 2.0 * dot - nn;
    cid = j;
  }
  for (int r = 0; r < Kk; ++r) {
    double bs = sc; int bi = cid;
#pragma unroll
    for (int off = 1; off < 64; off <<= 1) {
      double os = __shfl_xor(bs, off);
      int oi = __shfl_xor(bi, off);
      if (os > bs || (os == bs && oi < bi)) { bs = os; bi = oi; }
    }
    if (cid == bi) { sc = -1e300; cid = 0x7fffffff; }
    if (lane == 0) idxout[((size_t)b * Tt + t) * Kk + r] = bi;
  }
}

// Fused graph tail + temporal conv. nbr is consumed in [B,T,C] layout (nbrT) so
// each (t,k) gather reads the group's 8 channels as 2 contiguous float4s
// (8x fewer L1 transactions than the [B,C,T] per-channel dword gather).
// Values and fma order identical to R11 -> bit-identical output.
// FAST=0: exact erff (layer 1 -> x1 -> layer-2 KNN must be bit-stable).
// FAST=1: rational erf (layer 2 -> only final output).
template <int FAST>
__global__ __launch_bounds__(256) void graph_tail(
    const float* __restrict__ h, const float* __restrict__ ctr,
    const float* __restrict__ nbrT, const int* __restrict__ idx,
    const float* __restrict__ tw2, const float* __restrict__ tb2,
    const float* __restrict__ dw2, const float* __restrict__ db2,
    const float* __restrict__ xin, float* __restrict__ xout) {
  __shared__ __align__(16) float gt[CG][Kk][68];   // 14.9 KB
  __shared__ __align__(16) float ht[CG][68];       // 2.2 KB
  __shared__ __align__(16) float ct[CG][68];       // 2.2 KB
  __shared__ int jt[Kk * 68];                      // 1.9 KB, [k][tl]
  int t0 = blockIdx.x * 64;
  int g = blockIdx.y;
  int b = blockIdx.z;
  int tid = threadIdx.x;
  const float* hg   = h   + ((size_t)b * Cc + g * CG) * Tt;
  const float* ctrg = ctr + ((size_t)b * Cc + g * CG) * Tt;
  const float* nbT  = nbrT + (size_t)b * Tt * Cc + g * CG;

  // stage h and ctr tiles (coalesced) and the idx tile
  {
    const int* ib = idx + ((size_t)b * Tt + t0 - 2) * Kk;
    for (int p = tid; p < Kk * 68; p += 256) {
      int k = p / 68, tl = p - k * 68;
      int tg = t0 - 2 + tl;
      jt[p] = (tg >= 0 && tg < Tt) ? ib[tl * Kk + k] : 0;
    }
    for (int e = tid; e < CG * 68; e += 256) {
      int ci = e / 68, tl = e - ci * 68;
      int tg = t0 - 2 + tl;
      int valid = (tg >= 0 && tg < Tt);
      ht[ci][tl] = valid ? hg[(size_t)ci * Tt + tg] : 0.f;
      ct[ci][tl] = valid ? ctrg[(size_t)ci * Tt + tg] : 0.f;
    }
  }
  __syncthreads();
  // gather + gelu: one (k,tl) pair per thread-iteration, 8 channels via 2xfloat4
  for (int p = tid; p < Kk * 68; p += 256) {
    int k = p / 68, tl = p - k * 68;
    int tg = t0 - 2 + tl;
    int valid = (tg >= 0 && tg < Tt);
    int j = jt[p];
    const float* np = nbT + (size_t)j * Cc;
    float4 n0 = *(const float4*)np;
    float4 n1 = *(const float4*)(np + 4);
    float ch[8] = {n0.x, n0.y, n0.z, n0.w, n1.x, n1.y, n1.z, n1.w};
#pragma unroll
    for (int ci = 0; ci < CG; ++ci) {
      float pre = ct[ci][tl] + ch[ci];
      float v = FAST ? gelu_fast(pre) : gelu_f(pre);
      gt[ci][k][tl] = valid ? v : 0.f;
    }
  }
  __syncthreads();

  // conv phase: thread = (o_local = tid>>5, 2 tokens at tl2=(tid&31)*2)
  int ol = tid >> 5, tl2 = (tid & 31) * 2;
  int o = g * CG + ol;

  // temporal conv (former gconv1d): same op order, zero-padded taps -> bit-identical
  const float* w2 = tw2 + (size_t)o * CG * 5;
  float bt = tb2[o];
  floatx2 acct = {bt, bt};
  for (int ci = 0; ci < CG; ++ci) {
    floatx2 p0 = *(const floatx2*)&ht[ci][tl2];
    floatx2 p1 = *(const floatx2*)&ht[ci][tl2 + 2];
    floatx2 p2 = *(const floatx2*)&ht[ci][tl2 + 4];
    float r6[6] = {p0.x, p0.y, p1.x, p1.y, p2.x, p2.y};
#pragma unroll
    for (int dt = 0; dt < 5; ++dt) {
      float wv = w2[ci * 5 + dt];
      floatx2 wv2 = {wv, wv};
      floatx2 rp = {r6[dt], r6[dt + 1]};
      acct = __builtin_elementwise_fma(wv2, rp, acct);
    }
  }

  // graph 5x5 conv + max over k
  const float* wp = dw2 + (size_t)o * CG * 25;
  float bv = db2[o];
  floatx2 acc[Kk];
#pragma unroll
  for (int k = 0; k < Kk; ++k) acc[k] = (floatx2){bv, bv};

  for (int ci = 0; ci < CG; ++ci) {
    float w[25];
#pragma unroll
    for (int i = 0; i < 25; ++i) w[i] = wp[ci * 25 + i];
#pragma unroll
    for (int kin = 0; kin < Kk; ++kin) {
      floatx2 p0 = *(const floatx2*)&gt[ci][kin][tl2];
      floatx2 p1 = *(const floatx2*)&gt[ci][kin][tl2 + 2];
      floatx2 p2 = *(const floatx2*)&gt[ci][kin][tl2 + 4];
      float r6[6] = {p0.x, p0.y, p1.x, p1.y, p2.x, p2.y};
      floatx2 rp[5];
#pragma unroll
      for (int dt = 0; dt < 5; ++dt) rp[dt] = (floatx2){r6[dt], r6[dt + 1]};
#pragma unroll
      for (int dk = 0; dk < 5; ++dk) {
        int k = kin + 2 - dk;
        if (k < 0 || k >= Kk) continue;
#pragma unroll
        for (int dt = 0; dt < 5; ++dt) {
          float wv = w[dt * 5 + dk];
          floatx2 wv2 = {wv, wv};
          acc[k] = __builtin_elementwise_fma(wv2, rp[dt], acc[k]);
        }
      }
    }
  }
  floatx2 m = acc[0];
#pragma unroll
  for (int k = 1; k < Kk; ++k) m = __builtin_elementwise_max(m, acc[k]);
  size_t off = ((size_t)b * Cc + o) * Tt + t0 + tl2;
  floatx2 xv = *(const floatx2*)&xin[off];
  floatx2 r;
  r.x = acct.x + m.x + xv.x;
  r.y = acct.y + m.y + xv.y;
  *(floatx2*)&xout[off] = r;
}

extern "C" void kernel_launch(void* const* d_in, const int* in_sizes, int n_in,
                              void* d_out, int out_size, void* d_ws, size_t ws_size,
                              hipStream_t stream) {
  const float* x0  = (const float*)d_in[0];
  const float* tw1 = (const float*)d_in[1];
  const float* tb1 = (const float*)d_in[2];
  const float* tw2 = (const float*)d_in[3];
  const float* tb2 = (const float*)d_in[4];
  const float* dw1 = (const float*)d_in[5];
  const float* db1 = (const float*)d_in[6];
  const float* dw2 = (const float*)d_in[7];
  const float* db2 = (const float*)d_in[8];
  float* out = (float*)d_out;

  float* ws = (float*)d_ws;
  const size_t NCT = (size_t)Bq * Cc * Tt;      // 2M elements
  float* x1   = ws;                             // layer-1 output   [B,C,T]
  float* hbuf = x1 + NCT;                       // h                [B,C,T]
  float* cbuf = hbuf + NCT;                     // ctr              [B,C,T]
  float* xT   = cbuf + NCT;                     // xT, then nbr     [B,T,C]
  unsigned short* xh = (unsigned short*)(xT + NCT);   // [B,T,C] bf16 hi
  unsigned short* xl = xh + NCT;                      // bf16 lo
  unsigned short* wh = xl + NCT;                      // weights hi [768][256]
  unsigned short* wl = wh + (size_t)NO * Cc;
  float* S    = (float*)(wl + (size_t)NO * Cc); // scores, 2 batches [2,T,T] 32MB
  float* xx   = S + 2 * (size_t)Tt * Tt;        // squared norms    [B,T]
  int* idxb   = (int*)(xx + (size_t)Bq * Tt);   // top-7            [B,T,K]
  int* idx10  = idxb + (size_t)Bq * Tt * Kk;    // top-10           [B,T,NTOP]
  float* nbrT = (float*)(idx10 + (size_t)Bq * Tt * NTOP);  // nbr^T [B,T,C] 8MB
  float* nbr  = xT;                             // nbr overwrites xT after rescore

  for (int i = 0; i < Ll; ++i) {
    const float* xin = (i == 0) ? x0 : x1;
    float* xout = (i == Ll - 1) ? out : x1;

    transpose_x<<<dim3(Tt/32, Cc/32, Bq), dim3(32, 8), 0, stream>>>(xin, xT, xh, xl);
    sqnorm_xt<<<dim3(Tt/8, Bq), 512, 0, stream>>>(xT, xx);
    for (int bp = 0; bp < Bq; bp += 2) {
      score_gemm<<<dim3(16, 16, 2), 256, 0, stream>>>(xh, xl, xx, S, bp);
      topk_scan<<<dim3(Tt/8, 1, 2), 512, 0, stream>>>(S, idx10, bp);
    }
    knn_rescore<<<dim3(Tt, Bq), 64, 0, stream>>>(xT, idx10, idxb);

    if (i == 0) {
      // Layer 1: exact fp32 pointwise convs (x1 feeds layer-2 KNN; R6/R7/R10 forensics)
      pw_conv8_all<<<dim3(Tt/256, 96, Bq), 256, 0, stream>>>(
          xin, tw1 + (size_t)i * Cc * Cc, tb1 + (size_t)i * Cc,
          dw1 + (size_t)i * Cc * 2 * Cc, db1 + (size_t)i * Cc,
          hbuf, cbuf, nbr);
    } else {
      // Layer 2: split-bf16 MFMA GEMM — output feeds only the final result.
      wsplit<<<dim3(NO), 256, 0, stream>>>(
          tw1 + (size_t)i * Cc * Cc, dw1 + (size_t)i * Cc * 2 * Cc, wh, wl);
      pw_gemm<<<dim3(64, NO/128), 256, 0, stream>>>(
          wh, wl, xh, xl, tb1 + (size_t)i * Cc, db1 + (size_t)i * Cc,
          hbuf, cbuf, nbr);
    }
    // nbr -> nbrT [B,T,C] for transaction-efficient gathers in graph_tail
    transpose_f<<<dim3(Tt/32, Cc/32, Bq), dim3(32, 8), 0, stream>>>(nbr, nbrT);
    if (i == 0) {
      graph_tail<0><<<dim3(Tt/64, Cc/CG, Bq), 256, 0, stream>>>(
          hbuf, cbuf, nbrT, idxb, tw2 + (size_t)i * Cc * CG * 5, tb2 + (size_t)i * Cc,
          dw2 + (size_t)i * Cc * CG * 25, db2 + (size_t)i * Cc, xin, xout);
    } else {
      graph_tail<1><<<dim3(Tt/64, Cc/CG, Bq), 256, 0, stream>>>(
          hbuf, cbuf, nbrT, idxb, tw2 + (size_t)i * Cc * CG * 5, tb2 + (size_t)i * Cc,
          dw2 + (size_t)i * Cc * CG * 25, db2 + (size_t)i * Cc, xin, xout);
    }
  }
}

// Round 13
// 546.377 us; speedup vs baseline: 3.9978x; 1.0813x over previous
//
#include <hip/hip_runtime.h>
#include <math.h>

#define Bq 4
#define Cc 256
#define Tt 2048
#define Kk 7
#define NTOP 10
#define CG 8
#define Ll 2
#define NO 768   // fused pointwise outputs: 256 h | 256 ctr | 256 nbr

typedef __attribute__((ext_vector_type(8))) short short8;
typedef __attribute__((ext_vector_type(4))) float floatx4;
typedef __attribute__((ext_vector_type(2))) float floatx2;

__device__ __forceinline__ float gelu_f(float v) {
  return 0.5f * v * (1.0f + erff(v * 0.70710678118654752440f));
}

// A&S 7.1.26 rational erf (~1e-6 eff err in fp32). SAFE ONLY on paths that do
// not feed a later top-k: R10 proved a ~1e-6 x1 perturbation flips layer-2 KNN.
__device__ __forceinline__ float erf_fast(float x) {
  float ax = fabsf(x);
  float t = __builtin_amdgcn_rcpf(fmaf(0.3275911f, ax, 1.0f));
  float y = t * (0.254829592f + t * (-0.284496736f + t * (1.421413741f +
            t * (-1.453152027f + t * 1.061405429f))));
  float r = 1.0f - y * __expf(-ax * ax);
  return copysignf(r, x);
}
__device__ __forceinline__ float gelu_fast(float v) {
  return 0.5f * v * (1.0f + erf_fast(v * 0.70710678118654752440f));
}

// xT[b][t][c] = x[b][c][t]; also emits bf16 hi/lo split
__global__ void transpose_x(const float* __restrict__ x, float* __restrict__ xT,
                            unsigned short* __restrict__ xh,
                            unsigned short* __restrict__ xl) {
  __shared__ float tile[32][33];
  int b = blockIdx.z;
  int t0 = blockIdx.x * 32, c0 = blockIdx.y * 32;
  int tx = threadIdx.x, ty = threadIdx.y;
  const float* xb = x + (size_t)b * Cc * Tt;
  for (int r = ty; r < 32; r += 8)
    tile[r][tx] = xb[(size_t)(c0 + r) * Tt + t0 + tx];
  __syncthreads();
  size_t base = (size_t)b * Tt * Cc;
  for (int r = ty; r < 32; r += 8) {
    float v = tile[tx][r];
    size_t o = base + (size_t)(t0 + r) * Cc + c0 + tx;
    xT[o] = v;
    unsigned int u = __float_as_uint(v);
    unsigned short h = (unsigned short)((u + 0x7fffu + ((u >> 16) & 1u)) >> 16);
    float f = v - __uint_as_float((unsigned int)h << 16);
    unsigned int ul = __float_as_uint(f);
    xh[o] = h;
    xl[o] = (unsigned short)((ul + 0x7fffu + ((ul >> 16) & 1u)) >> 16);
  }
}

// plain fp32 transpose: dst[b][t][c] = src[b][c][t]  (for nbr -> nbrT)
__global__ void transpose_f(const float* __restrict__ src, float* __restrict__ dst) {
  __shared__ float tile[32][33];
  int b = blockIdx.z;
  int t0 = blockIdx.x * 32, c0 = blockIdx.y * 32;
  int tx = threadIdx.x, ty = threadIdx.y;
  const float* sb = src + (size_t)b * Cc * Tt;
  for (int r = ty; r < 32; r += 8)
    tile[r][tx] = sb[(size_t)(c0 + r) * Tt + t0 + tx];
  __syncthreads();
  float* db = dst + (size_t)b * Tt * Cc;
  for (int r = ty; r < 32; r += 8)
    db[(size_t)(t0 + r) * Cc + c0 + tx] = tile[tx][r];
}

// squared norms from xT; wave per row t, 8 rows per block
__global__ __launch_bounds__(512) void sqnorm_xt(
    const float* __restrict__ xT, float* __restrict__ xx) {
  int b = blockIdx.y;
  int t = blockIdx.x * 8 + (threadIdx.x >> 6);
  int lane = threadIdx.x & 63;
  const float* row = xT + ((size_t)b * Tt + t) * Cc;
  float4 v = *(const float4*)(row + lane * 4);
  float acc = v.x * v.x + v.y * v.y + v.z * v.z + v.w * v.w;
#pragma unroll
  for (int off = 1; off < 64; off <<= 1) acc += __shfl_xor(acc, off);
  if (lane == 0) xx[(size_t)b * Tt + t] = acc;
}

// fp32 pointwise convs, all 3 ranges in one launch (layer-1 exact path).
// Thread = 8 outputs x 4 tokens, float4 x-loads (32 FMA per load vs 8 before).
// Per-(o,t) fmaf chain remains bias -> ascending c  ==> bit-identical to R12.
__global__ __launch_bounds__(256) void pw_conv8_all(
    const float* __restrict__ x, const float* __restrict__ tw1,
    const float* __restrict__ tb1, const float* __restrict__ dw1,
    const float* __restrict__ db1, float* __restrict__ hb,
    float* __restrict__ cb, float* __restrict__ nb) {
  int tid = threadIdx.x;
  int wv = tid >> 6, lane = tid & 63;
  int t = blockIdx.x * 1024 + wv * 256 + lane * 4;   // 4 consecutive tokens
  int oy = blockIdx.y;
  int b = blockIdx.z;
  int range = oy >> 5;            // 0: h  1: ctr  2: nbr
  int o0 = (oy & 31) * 8;
  const float* W; int wstride, woff; const float* bias; float* dst; int dg;
  if (range == 0)      { W = tw1; wstride = Cc;     woff = 0;  bias = tb1;     dst = hb; dg = 1; }
  else if (range == 1) { W = dw1; wstride = 2 * Cc; woff = Cc; bias = db1;     dst = cb; dg = 0; }
  else                 { W = dw1; wstride = 2 * Cc; woff = 0;  bias = nullptr; dst = nb; dg = 0; }
  const float* xp = x + (size_t)b * Cc * Tt + t;
  const float* wp = W + (size_t)o0 * wstride + woff;
  float acc[8][4];
#pragma unroll
  for (int j = 0; j < 8; ++j) {
    float bv = bias ? bias[o0 + j] : 0.f;
#pragma unroll
    for (int e = 0; e < 4; ++e) acc[j][e] = bv;
  }
  for (int c = 0; c < Cc; c += 4) {
    float4 xv0 = *(const float4*)(xp + (size_t)c * Tt);
    float4 xv1 = *(const float4*)(xp + (size_t)(c + 1) * Tt);
    float4 xv2 = *(const float4*)(xp + (size_t)(c + 2) * Tt);
    float4 xv3 = *(const float4*)(xp + (size_t)(c + 3) * Tt);
    float x0[4] = {xv0.x, xv0.y, xv0.z, xv0.w};
    float x1[4] = {xv1.x, xv1.y, xv1.z, xv1.w};
    float x2[4] = {xv2.x, xv2.y, xv2.z, xv2.w};
    float x3[4] = {xv3.x, xv3.y, xv3.z, xv3.w};
#pragma unroll
    for (int j = 0; j < 8; ++j) {
      const float* wr = wp + (size_t)j * wstride + c;   // wave-uniform -> s_load
      float w0 = wr[0], w1 = wr[1], w2 = wr[2], w3 = wr[3];
#pragma unroll
      for (int e = 0; e < 4; ++e) {
        float a = acc[j][e];
        a = fmaf(w0, x0[e], a);
        a = fmaf(w1, x1[e], a);
        a = fmaf(w2, x2[e], a);
        a = fmaf(w3, x3[e], a);
        acc[j][e] = a;
      }
    }
  }
#pragma unroll
  for (int j = 0; j < 8; ++j) {
    float4 r;
    float* rp = (float*)&r;
#pragma unroll
    for (int e = 0; e < 4; ++e) {
      float v = acc[j][e];
      if (dg) v = gelu_f(v);
      rp[e] = v;
    }
    *(float4*)&dst[((size_t)b * Cc + o0 + j) * Tt + t] = r;
  }
}

// concat weights [768][256] -> bf16 hi/lo (layer-2 only)
__global__ __launch_bounds__(256) void wsplit(
    const float* __restrict__ tw1, const float* __restrict__ dw1,
    unsigned short* __restrict__ wh, unsigned short* __restrict__ wl) {
  int o = blockIdx.x;
  int c = threadIdx.x;
  float v;
  if (o < 256) v = tw1[(size_t)o * Cc + c];
  else if (o < 512) v = dw1[(size_t)(o - 256) * (2 * Cc) + Cc + c];
  else v = dw1[(size_t)(o - 512) * (2 * Cc) + c];
  unsigned int u = __float_as_uint(v);
  unsigned short h = (unsigned short)((u + 0x7fffu + ((u >> 16) & 1u)) >> 16);
  float f = v - __uint_as_float((unsigned int)h << 16);
  unsigned int ul = __float_as_uint(f);
  wh[(size_t)o * Cc + c] = h;
  wl[(size_t)o * Cc + c] = (unsigned short)((ul + 0x7fffu + ((ul >> 16) & 1u)) >> 16);
}

// fused pointwise GEMM (layer-2 only)
__global__ __launch_bounds__(256) void pw_gemm(
    const unsigned short* __restrict__ wh, const unsigned short* __restrict__ wl,
    const unsigned short* __restrict__ xh, const unsigned short* __restrict__ xl,
    const float* __restrict__ tb1, const float* __restrict__ db1,
    float* __restrict__ hb, float* __restrict__ cb, float* __restrict__ nb) {
  __shared__ __align__(16) unsigned short Ah[128][40], Al[128][40];
  __shared__ __align__(16) unsigned short Bh[128][40], Bl[128][40];
  int mt = blockIdx.x;
  int b = mt >> 4;
  int t0 = (mt & 15) * 128;
  int o0 = blockIdx.y * 128;
  int tid = threadIdx.x;
  int w = tid >> 6, lane = tid & 63, quad = lane >> 4, l15 = lane & 15;
  int wm = (w >> 1) * 64, wn = (w & 1) * 64;
  floatx4 acc[4][4];
#pragma unroll
  for (int i = 0; i < 4; ++i)
#pragma unroll
    for (int j = 0; j < 4; ++j) acc[i][j] = (floatx4){0.f, 0.f, 0.f, 0.f};

  const unsigned short* xhb = xh + ((size_t)b * Tt + t0) * Cc;
  const unsigned short* xlb = xl + ((size_t)b * Tt + t0) * Cc;
  int sr = tid >> 1;
  int sq = (tid & 1) * 2;
  for (int kc = 0; kc < Cc; kc += 32) {
    __syncthreads();
    {
      const unsigned short* am = wh + (size_t)(o0 + sr) * Cc + kc + sq * 8;
      *(uint4*)&Ah[sr][sq * 8] = *(const uint4*)am;
      *(uint4*)&Ah[sr][sq * 8 + 8] = *(const uint4*)(am + 8);
      const unsigned short* al = wl + (size_t)(o0 + sr) * Cc + kc + sq * 8;
      *(uint4*)&Al[sr][sq * 8] = *(const uint4*)al;
      *(uint4*)&Al[sr][sq * 8 + 8] = *(const uint4*)(al + 8);
      const unsigned short* bm = xhb + (size_t)sr * Cc + kc + sq * 8;
      *(uint4*)&Bh[sr][sq * 8] = *(const uint4*)bm;
      *(uint4*)&Bh[sr][sq * 8 + 8] = *(const uint4*)(bm + 8);
      const unsigned short* bl = xlb + (size_t)sr * Cc + kc + sq * 8;
      *(uint4*)&Bl[sr][sq * 8] = *(const uint4*)bl;
      *(uint4*)&Bl[sr][sq * 8 + 8] = *(const uint4*)(bl + 8);
    }
    __syncthreads();
    int ka = quad * 8;
    short8 a_h[4], a_l[4], b_h[4], b_l[4];
#pragma unroll
    for (int f = 0; f < 4; ++f) {
      a_h[f] = *(const short8*)&Ah[wm + f * 16 + l15][ka];
      a_l[f] = *(const short8*)&Al[wm + f * 16 + l15][ka];
      b_h[f] = *(const short8*)&Bh[wn + f * 16 + l15][ka];
      b_l[f] = *(const short8*)&Bl[wn + f * 16 + l15][ka];
    }
#pragma unroll
    for (int fm = 0; fm < 4; ++fm)
#pragma unroll
      for (int fn = 0; fn < 4; ++fn) {
        acc[fm][fn] = __builtin_amdgcn_mfma_f32_16x16x32_bf16(a_h[fm], b_h[fn], acc[fm][fn], 0, 0, 0);
        acc[fm][fn] = __builtin_amdgcn_mfma_f32_16x16x32_bf16(a_h[fm], b_l[fn], acc[fm][fn], 0, 0, 0);
        acc[fm][fn] = __builtin_amdgcn_mfma_f32_16x16x32_bf16(a_l[fm], b_h[fn], acc[fm][fn], 0, 0, 0);
      }
  }
  int range = o0 >> 8;                 // 0: h(gelu,tb1)  1: ctr(db1)  2: nbr
  float* dst = (range == 0) ? hb : (range == 1) ? cb : nb;
  const float* bias = (range == 0) ? tb1 : (range == 1) ? db1 : nullptr;
  int ol0 = o0 & 255;
#pragma unroll
  for (int fm = 0; fm < 4; ++fm) {
    int o = ol0 + wm + fm * 16 + quad * 4;
#pragma unroll
    for (int r = 0; r < 4; ++r) {
      float bv = bias ? bias[o + r] : 0.f;
      size_t rowoff = ((size_t)b * Cc + o + r) * Tt + t0;
#pragma unroll
      for (int fn = 0; fn < 4; ++fn) {
        int t = wn + fn * 16 + l15;
        float v = acc[fm][fn][r] + bv;
        if (range == 0) v = gelu_f(v);
        dst[rowoff + t] = v;
      }
    }
  }
}

// score GEMM, 2 batches per dispatch via z
__global__ __launch_bounds__(256) void score_gemm(
    const unsigned short* __restrict__ xh, const unsigned short* __restrict__ xl,
    const float* __restrict__ xx, float* __restrict__ S, int bbase) {
  __shared__ __align__(16) unsigned short Ah[128][40], Al[128][40];
  __shared__ __align__(16) unsigned short Bh[128][40], Bl[128][40];
  int lb = blockIdx.z;
  int b = bbase + lb;
  int m0 = blockIdx.y * 128, n0 = blockIdx.x * 128;
  int tid = threadIdx.x;
  int w = tid >> 6, lane = tid & 63, quad = lane >> 4, l15 = lane & 15;
  int wm = (w >> 1) * 64, wn = (w & 1) * 64;
  const unsigned short* xhb = xh + (size_t)b * Tt * Cc;
  const unsigned short* xlb = xl + (size_t)b * Tt * Cc;
  const float* xxb = xx + (size_t)b * Tt;
  float* Sb = S + (size_t)lb * Tt * Tt;
  floatx4 acc[4][4];
#pragma unroll
  for (int i = 0; i < 4; ++i)
#pragma unroll
    for (int j = 0; j < 4; ++j) acc[i][j] = (floatx4){0.f, 0.f, 0.f, 0.f};

  int sr = tid >> 1;
  int sq = (tid & 1) * 2;
  for (int kc = 0; kc < Cc; kc += 32) {
    __syncthreads();
    {
      const unsigned short* am = xhb + (size_t)(m0 + sr) * Cc + kc + sq * 8;
      *(uint4*)&Ah[sr][sq * 8] = *(const uint4*)am;
      *(uint4*)&Ah[sr][sq * 8 + 8] = *(const uint4*)(am + 8);
      const unsigned short* al = xlb + (size_t)(m0 + sr) * Cc + kc + sq * 8;
      *(uint4*)&Al[sr][sq * 8] = *(const uint4*)al;
      *(uint4*)&Al[sr][sq * 8 + 8] = *(const uint4*)(al + 8);
      const unsigned short* bm = xhb + (size_t)(n0 + sr) * Cc + kc + sq * 8;
      *(uint4*)&Bh[sr][sq * 8] = *(const uint4*)bm;
      *(uint4*)&Bh[sr][sq * 8 + 8] = *(const uint4*)(bm + 8);
      const unsigned short* bl = xlb + (size_t)(n0 + sr) * Cc + kc + sq * 8;
      *(uint4*)&Bl[sr][sq * 8] = *(const uint4*)bl;
      *(uint4*)&Bl[sr][sq * 8 + 8] = *(const uint4*)(bl + 8);
    }
    __syncthreads();
    int ka = quad * 8;
    short8 a_h[4], a_l[4], b_h[4], b_l[4];
#pragma unroll
    for (int f = 0; f < 4; ++f) {
      a_h[f] = *(const short8*)&Ah[wm + f * 16 + l15][ka];
      a_l[f] = *(const short8*)&Al[wm + f * 16 + l15][ka];
      b_h[f] = *(const short8*)&Bh[wn + f * 16 + l15][ka];
      b_l[f] = *(const short8*)&Bl[wn + f * 16 + l15][ka];
    }
#pragma unroll
    for (int fm = 0; fm < 4; ++fm)
#pragma unroll
      for (int fn = 0; fn < 4; ++fn) {
        acc[fm][fn] = __builtin_amdgcn_mfma_f32_16x16x32_bf16(a_h[fm], b_h[fn], acc[fm][fn], 0, 0, 0);
        acc[fm][fn] = __builtin_amdgcn_mfma_f32_16x16x32_bf16(a_h[fm], b_l[fn], acc[fm][fn], 0, 0, 0);
        acc[fm][fn] = __builtin_amdgcn_mfma_f32_16x16x32_bf16(a_l[fm], b_h[fn], acc[fm][fn], 0, 0, 0);
      }
  }
#pragma unroll
  for (int fn = 0; fn < 4; ++fn) {
    int n = n0 + wn + fn * 16 + l15;
    float xv = xxb[n];
#pragma unroll
    for (int fm = 0; fm < 4; ++fm) {
      int m = m0 + wm + fm * 16 + quad * 4;
#pragma unroll
      for (int r = 0; r < 4; ++r)
        Sb[(size_t)(m + r) * Tt + n] = fmaf(2.f, acc[fm][fn][r], -xv);
    }
  }
}

// top-10 scan, 2 batches via z; wave per row, 8 rows per block
__global__ __launch_bounds__(512) void topk_scan(
    const float* __restrict__ S, int* __restrict__ idx10, int bbase) {
  int lb = blockIdx.z;
  int m = blockIdx.x * 8 + (threadIdx.x >> 6);
  int lane = threadIdx.x & 63;
  const float* row = S + ((size_t)lb * Tt + m) * Tt;
  float s[NTOP]; int idl[NTOP];
#pragma unroll
  for (int j = 0; j < NTOP; ++j) { s[j] = -INFINITY; idl[j] = 0x7fffffff; }
  for (int c0 = lane * 4; c0 < Tt; c0 += 256) {
    float4 v = *(const float4*)(row + c0);
    float cand[4] = {v.x, v.y, v.z, v.w};
#pragma unroll
    for (int e = 0; e < 4; ++e) {
      float sc = cand[e];
      if (sc > s[NTOP - 1]) {
        s[NTOP - 1] = sc; idl[NTOP - 1] = c0 + e;
#pragma unroll
        for (int j = NTOP - 1; j > 0; --j) {
          if (s[j] > s[j - 1]) {
            float ts = s[j]; s[j] = s[j - 1]; s[j - 1] = ts;
            int ti = idl[j]; idl[j] = idl[j - 1]; idl[j - 1] = ti;
          }
        }
      }
    }
  }
  int ptr = 0;
  for (int r = 0; r < NTOP; ++r) {
    float cs = (ptr < NTOP) ? s[ptr] : -INFINITY;
    int cid = (ptr < NTOP) ? idl[ptr] : 0x7fffffff;
    float bs = cs; int bi = cid;
#pragma unroll
    for (int off = 1; off < 64; off <<= 1) {
      float os = __shfl_xor(bs, off);
      int oi = __shfl_xor(bi, off);
      if (os > bs || (os == bs && oi < bi)) { bs = os; bi = oi; }
    }
    if (cid == bi) ptr++;
    if (lane == 0) idx10[((size_t)(bbase + lb) * Tt + m) * NTOP + r] = bi;
  }
}

// fp64 rescore of the NTOP shortlist, emit exact top-7
__global__ __launch_bounds__(64) void knn_rescore(
    const float* __restrict__ xT, const int* __restrict__ idx10,
    int* __restrict__ idxout) {
  int t = blockIdx.x;
  int b = blockIdx.y;
  int lane = threadIdx.x;
  const float* xTb = xT + (size_t)b * Tt * Cc;
  const float* xm = xTb + (size_t)t * Cc;
  double sc = -1e300;
  int cid = 0x7fffffff;
  if (lane < NTOP) {
    int j = idx10[((size_t)b * Tt + t) * NTOP + lane];
    const float* xn = xTb + (size_t)j * Cc;
    double dot = 0.0, nn = 0.0;
    for (int c = 0; c < Cc; c += 4) {
      float4 a = *(const float4*)(xm + c);
      float4 v = *(const float4*)(xn + c);
      dot += (double)a.x * v.x + (double)a.y * v.y + (double)a.z * v.z + (double)a.w * v.w;
      nn  += (double)v.x * v.x + (double)v.y * v.y + (double)v.z * v.z + (double)v.w * v.w;
    }
    sc = 2.0 * dot - nn;
    cid = j;
  }
  for (int r = 0; r < Kk; ++r) {
    double bs = sc; int bi = cid;
#pragma unroll
    for (int off = 1; off < 64; off <<= 1) {
      double os = __shfl_xor(bs, off);
      int oi = __shfl_xor(bi, off);
      if (os > bs || (os == bs && oi < bi)) { bs = os; bi = oi; }
    }
    if (cid == bi) { sc = -1e300; cid = 0x7fffffff; }
    if (lane == 0) idxout[((size_t)b * Tt + t) * Kk + r] = bi;
  }
}

// Fused graph tail + temporal conv. nbr consumed in [B,T,C] layout (nbrT):
// each (t,k) gather reads 8 channels as 2 contiguous float4s.
// FAST=0: exact erff (layer 1 -> x1 -> layer-2 KNN must be bit-stable).
// FAST=1: rational erf (layer 2 -> only final output).
template <int FAST>
__global__ __launch_bounds__(256) void graph_tail(
    const float* __restrict__ h, const float* __restrict__ ctr,
    const float* __restrict__ nbrT, const int* __restrict__ idx,
    const float* __restrict__ tw2, const float* __restrict__ tb2,
    const float* __restrict__ dw2, const float* __restrict__ db2,
    const float* __restrict__ xin, float* __restrict__ xout) {
  __shared__ __align__(16) float gt[CG][Kk][68];   // 14.9 KB
  __shared__ __align__(16) float ht[CG][68];       // 2.2 KB
  __shared__ __align__(16) float ct[CG][68];       // 2.2 KB
  __shared__ int jt[Kk * 68];                      // 1.9 KB, [k][tl]
  int t0 = blockIdx.x * 64;
  int g = blockIdx.y;
  int b = blockIdx.z;
  int tid = threadIdx.x;
  const float* hg   = h   + ((size_t)b * Cc + g * CG) * Tt;
  const float* ctrg = ctr + ((size_t)b * Cc + g * CG) * Tt;
  const float* nbT  = nbrT + (size_t)b * Tt * Cc + g * CG;

  {
    const int* ib = idx + ((size_t)b * Tt + t0 - 2) * Kk;
    for (int p = tid; p < Kk * 68; p += 256) {
      int k = p / 68, tl = p - k * 68;
      int tg = t0 - 2 + tl;
      jt[p] = (tg >= 0 && tg < Tt) ? ib[tl * Kk + k] : 0;
    }
    for (int e = tid; e < CG * 68; e += 256) {
      int ci = e / 68, tl = e - ci * 68;
      int tg = t0 - 2 + tl;
      int valid = (tg >= 0 && tg < Tt);
      ht[ci][tl] = valid ? hg[(size_t)ci * Tt + tg] : 0.f;
      ct[ci][tl] = valid ? ctrg[(size_t)ci * Tt + tg] : 0.f;
    }
  }
  __syncthreads();
  for (int p = tid; p < Kk * 68; p += 256) {
    int k = p / 68, tl = p - k * 68;
    int tg = t0 - 2 + tl;
    int valid = (tg >= 0 && tg < Tt);
    int j = jt[p];
    const float* np = nbT + (size_t)j * Cc;
    float4 n0 = *(const float4*)np;
    float4 n1 = *(const float4*)(np + 4);
    float ch[8] = {n0.x, n0.y, n0.z, n0.w, n1.x, n1.y, n1.z, n1.w};
#pragma unroll
    for (int ci = 0; ci < CG; ++ci) {
      float pre = ct[ci][tl] + ch[ci];
      float v = FAST ? gelu_fast(pre) : gelu_f(pre);
      gt[ci][k][tl] = valid ? v : 0.f;
    }
  }
  __syncthreads();

  int ol = tid >> 5, tl2 = (tid & 31) * 2;
  int o = g * CG + ol;

  const float* w2 = tw2 + (size_t)o * CG * 5;
  float bt = tb2[o];
  floatx2 acct = {bt, bt};
  for (int ci = 0; ci < CG; ++ci) {
    floatx2 p0 = *(const floatx2*)&ht[ci][tl2];
    floatx2 p1 = *(const floatx2*)&ht[ci][tl2 + 2];
    floatx2 p2 = *(const floatx2*)&ht[ci][tl2 + 4];
    float r6[6] = {p0.x, p0.y, p1.x, p1.y, p2.x, p2.y};
#pragma unroll
    for (int dt = 0; dt < 5; ++dt) {
      float wv = w2[ci * 5 + dt];
      floatx2 wv2 = {wv, wv};
      floatx2 rp = {r6[dt], r6[dt + 1]};
      acct = __builtin_elementwise_fma(wv2, rp, acct);
    }
  }

  const float* wp = dw2 + (size_t)o * CG * 25;
  float bv = db2[o];
  floatx2 acc[Kk];
#pragma unroll
  for (int k = 0; k < Kk; ++k) acc[k] = (floatx2){bv, bv};

  for (int ci = 0; ci < CG; ++ci) {
    float w[25];
#pragma unroll
    for (int i = 0; i < 25; ++i) w[i] = wp[ci * 25 + i];
#pragma unroll
    for (int kin = 0; kin < Kk; ++kin) {
      floatx2 p0 = *(const floatx2*)&gt[ci][kin][tl2];
      floatx2 p1 = *(const floatx2*)&gt[ci][kin][tl2 + 2];
      floatx2 p2 = *(const floatx2*)&gt[ci][kin][tl2 + 4];
      float r6[6] = {p0.x, p0.y, p1.x, p1.y, p2.x, p2.y};
      floatx2 rp[5];
#pragma unroll
      for (int dt = 0; dt < 5; ++dt) rp[dt] = (floatx2){r6[dt], r6[dt + 1]};
#pragma unroll
      for (int dk = 0; dk < 5; ++dk) {
        int k = kin + 2 - dk;
        if (k < 0 || k >= Kk) continue;
#pragma unroll
        for (int dt = 0; dt < 5; ++dt) {
          float wv = w[dt * 5 + dk];
          floatx2 wv2 = {wv, wv};
          acc[k] = __builtin_elementwise_fma(wv2, rp[dt], acc[k]);
        }
      }
    }
  }
  floatx2 m = acc[0];
#pragma unroll
  for (int k = 1; k < Kk; ++k) m = __builtin_elementwise_max(m, acc[k]);
  size_t off = ((size_t)b * Cc + o) * Tt + t0 + tl2;
  floatx2 xv = *(const floatx2*)&xin[off];
  floatx2 r;
  r.x = acct.x + m.x + xv.x;
  r.y = acct.y + m.y + xv.y;
  *(floatx2*)&xout[off] = r;
}

extern "C" void kernel_launch(void* const* d_in, const int* in_sizes, int n_in,
                              void* d_out, int out_size, void* d_ws, size_t ws_size,
                              hipStream_t stream) {
  const float* x0  = (const float*)d_in[0];
  const float* tw1 = (const float*)d_in[1];
  const float* tb1 = (const float*)d_in[2];
  const float* tw2 = (const float*)d_in[3];
  const float* tb2 = (const float*)d_in[4];
  const float* dw1 = (const float*)d_in[5];
  const float* db1 = (const float*)d_in[6];
  const float* dw2 = (const float*)d_in[7];
  const float* db2 = (const float*)d_in[8];
  float* out = (float*)d_out;

  float* ws = (float*)d_ws;
  const size_t NCT = (size_t)Bq * Cc * Tt;      // 2M elements
  float* x1   = ws;                             // layer-1 output   [B,C,T]
  float* hbuf = x1 + NCT;                       // h                [B,C,T]
  float* cbuf = hbuf + NCT;                     // ctr              [B,C,T]
  float* xT   = cbuf + NCT;                     // xT, then nbr     [B,T,C]
  unsigned short* xh = (unsigned short*)(xT + NCT);   // [B,T,C] bf16 hi
  unsigned short* xl = xh + NCT;                      // bf16 lo
  unsigned short* wh = xl + NCT;                      // weights hi [768][256]
  unsigned short* wl = wh + (size_t)NO * Cc;
  float* S    = (float*)(wl + (size_t)NO * Cc); // scores, 2 batches [2,T,T] 32MB
  float* xx   = S + 2 * (size_t)Tt * Tt;        // squared norms    [B,T]
  int* idxb   = (int*)(xx + (size_t)Bq * Tt);   // top-7            [B,T,K]
  int* idx10  = idxb + (size_t)Bq * Tt * Kk;    // top-10           [B,T,NTOP]
  float* nbrT = (float*)(idx10 + (size_t)Bq * Tt * NTOP);  // nbr^T [B,T,C] 8MB
  float* nbr  = xT;                             // nbr overwrites xT after rescore

  for (int i = 0; i < Ll; ++i) {
    const float* xin = (i == 0) ? x0 : x1;
    float* xout = (i == Ll - 1) ? out : x1;

    transpose_x<<<dim3(Tt/32, Cc/32, Bq), dim3(32, 8), 0, stream>>>(xin, xT, xh, xl);
    sqnorm_xt<<<dim3(Tt/8, Bq), 512, 0, stream>>>(xT, xx);
    for (int bp = 0; bp < Bq; bp += 2) {
      score_gemm<<<dim3(16, 16, 2), 256, 0, stream>>>(xh, xl, xx, S, bp);
      topk_scan<<<dim3(Tt/8, 1, 2), 512, 0, stream>>>(S, idx10, bp);
    }
    knn_rescore<<<dim3(Tt, Bq), 64, 0, stream>>>(xT, idx10, idxb);

    if (i == 0) {
      // Layer 1: exact fp32 pointwise convs (x1 feeds layer-2 KNN; R6/R7/R10 forensics)
      pw_conv8_all<<<dim3(Tt/1024, 96, Bq), 256, 0, stream>>>(
          xin, tw1 + (size_t)i * Cc * Cc, tb1 + (size_t)i * Cc,
          dw1 + (size_t)i * Cc * 2 * Cc, db1 + (size_t)i * Cc,
          hbuf, cbuf, nbr);
    } else {
      // Layer 2: split-bf16 MFMA GEMM — output feeds only the final result.
      wsplit<<<dim3(NO), 256, 0, stream>>>(
          tw1 + (size_t)i * Cc * Cc, dw1 + (size_t)i * Cc * 2 * Cc, wh, wl);
      pw_gemm<<<dim3(64, NO/128), 256, 0, stream>>>(
          wh, wl, xh, xl, tb1 + (size_t)i * Cc, db1 + (size_t)i * Cc,
          hbuf, cbuf, nbr);
    }
    // nbr -> nbrT [B,T,C] for transaction-efficient gathers in graph_tail
    transpose_f<<<dim3(Tt/32, Cc/32, Bq), dim3(32, 8), 0, stream>>>(nbr, nbrT);
    if (i == 0) {
      graph_tail<0><<<dim3(Tt/64, Cc/CG, Bq), 256, 0, stream>>>(
          hbuf, cbuf, nbrT, idxb, tw2 + (size_t)i * Cc * CG * 5, tb2 + (size_t)i * Cc,
          dw2 + (size_t)i * Cc * CG * 25, db2 + (size_t)i * Cc, xin, xout);
    } else {
      graph_tail<1><<<dim3(Tt/64, Cc/CG, Bq), 256, 0, stream>>>(
          hbuf, cbuf, nbrT, idxb, tw2 + (size_t)i * Cc * CG * 5, tb2 + (size_t)i * Cc,
          dw2 + (size_t)i * Cc * CG * 25, db2 + (size_t)i * Cc, xin, xout);
    }
  }
}